// Round 3
// baseline (1270.001 us; speedup 1.0000x reference)
//
#include <hip/hip_runtime.h>
#include <math.h>

#define N_PTS 4096
#define BATCH 4
#define KNB 20

__device__ __forceinline__ float lrelu(float v){ return fmaxf(v, 0.2f*v); }
__device__ __forceinline__ unsigned fenc(float f){ unsigned u=__float_as_uint(f); return (u&0x80000000u)?~u:(u|0x80000000u); }
__device__ __forceinline__ float fdec(unsigned k){ return (k&0x80000000u)?__uint_as_float(k&0x7fffffffu):__uint_as_float(~k); }

// ---- prep: fold BN scale into weights ----
__global__ void k_scale_rows(const float* __restrict__ W, const float* __restrict__ bn,
                             float* __restrict__ Wf, float* __restrict__ bias, int O, int C){
  int i = blockIdx.x*256 + threadIdx.x;
  if (i >= O*C) return;
  int o = i / C;
  float s = bn[o] / sqrtf(bn[3*O+o] + 1e-5f);
  Wf[i] = W[i]*s;
  if (i % C == 0) bias[o] = bn[O+o] - s*bn[2*O+o];
}

// transposed float4-chunk layout: dst[(c/4)*256 + o*4 + c%4], O=64 fixed
__global__ void k_build_T4(const float* __restrict__ W, int ldw, const float* __restrict__ bn,
                           float* __restrict__ dst, float* __restrict__ bias,
                           int c0, int diffoff, int Csrc){
  int o = threadIdx.x, c = blockIdx.x;
  float s = bn[o] / sqrtf(bn[192+o] + 1e-5f);
  float val = 0.f;
  if (c < Csrc){
    val = W[o*ldw + c0 + c];
    if (diffoff) val = W[o*ldw + c0 + diffoff + c] - val;
    val *= s;
  }
  dst[(c>>2)*256 + o*4 + (c&3)] = val;
  if (bias != nullptr && c==0) bias[o] = bn[64+o] - s*bn[128+o];
}

// U1[b][k][o] = sum_{c<6} s_o*W1[o][c]*x[b][c][k]  (first-KNN neighbors are points 0..19)
__global__ void k_build_U1(const float* __restrict__ x, const float* __restrict__ W1,
                           const float* __restrict__ bn, float* __restrict__ U1){
  int o = threadIdx.x, k = blockIdx.x, b = blockIdx.y;
  float s = bn[o] / sqrtf(bn[192+o] + 1e-5f);
  float acc = 0.f;
  #pragma unroll
  for (int c=0;c<6;c++) acc += W1[o*12+c] * x[(b*6+c)*N_PTS + k];
  U1[(b*KNB+k)*64 + o] = acc*s;
}

__global__ void k_init_g(unsigned* g){ g[blockIdx.x*256+threadIdx.x] = fenc(-INFINITY); }

// ---- edge block 1 (trivial neighbors 0..19) : conv1 + conv2 + maxpool ----
__global__ __launch_bounds__(256) void k_edge1(const float* __restrict__ x, const float* __restrict__ U1,
                        const float* __restrict__ W1dT4, const float* __restrict__ bf1,
                        const float* __restrict__ W2T4, const float* __restrict__ bf2,
                        float* __restrict__ x1t, float* __restrict__ Xcat, float* __restrict__ xx1){
  __shared__ float hb[4][KNB][64];
  int wid = threadIdx.x>>6, lane = threadIdx.x&63;
  int pt = blockIdx.x*4 + wid, b = pt>>12, n = pt&4095;
  float xv[8];
  #pragma unroll
  for (int c=0;c<6;c++) xv[c] = x[(b*6+c)*N_PTS + n];
  xv[6]=0.f; xv[7]=0.f;
  float w = bf1[lane];
  #pragma unroll
  for (int cb=0;cb<2;cb++){
    float4 wv = ((const float4*)W1dT4)[cb*64+lane];
    w = fmaf(wv.x, xv[cb*4+0], w); w = fmaf(wv.y, xv[cb*4+1], w);
    w = fmaf(wv.z, xv[cb*4+2], w); w = fmaf(wv.w, xv[cb*4+3], w);
  }
  const float* Ub = U1 + b*KNB*64;
  #pragma unroll
  for (int k=0;k<KNB;k++) hb[wid][k][lane] = lrelu(Ub[k*64+lane] + w);
  __syncthreads();
  float acc[KNB];
  #pragma unroll
  for (int k=0;k<KNB;k++) acc[k] = bf2[lane];
  for (int cb=0;cb<16;cb++){
    float4 wv = ((const float4*)W2T4)[cb*64+lane];
    #pragma unroll
    for (int k=0;k<KNB;k++){
      float4 a = *(const float4*)&hb[wid][k][cb*4];
      acc[k]=fmaf(wv.x,a.x,acc[k]); acc[k]=fmaf(wv.y,a.y,acc[k]);
      acc[k]=fmaf(wv.z,a.z,acc[k]); acc[k]=fmaf(wv.w,a.w,acc[k]);
    }
  }
  float mx = -INFINITY;
  #pragma unroll
  for (int k=0;k<KNB;k++) mx = fmaxf(mx, lrelu(acc[k]));
  x1t[(size_t)pt*64 + lane] = mx;
  Xcat[((size_t)b*192 + 0 + lane)*N_PTS + n] = mx;
  float sq = mx*mx;
  #pragma unroll
  for (int off=32; off; off>>=1) sq += __shfl_xor(sq, off);
  if (lane==0) xx1[pt] = sq;
}

// ---- KNN pairwise kernel: pd[b][i][j] = fma(2,dot,-xx_n) - xx_m, 128x128 tile, K=64 ----
__global__ __launch_bounds__(256) void k_knn_gemm(const float* __restrict__ xt, const float* __restrict__ xx,
                          float* __restrict__ pd, int q0, int S){
  __shared__ float As[64][132];
  __shared__ float Bs[64][132];
  int tid = threadIdx.x;
  int bx = blockIdx.x, by = blockIdx.y, b = blockIdx.z;
  const float* xb = xt + (size_t)b*N_PTS*64;
  #pragma unroll
  for (int p=0;p<8;p++){
    int row = (tid>>4) + p*16, c4 = tid&15;
    float4 av = *(const float4*)&xb[(size_t)(q0 + by*128 + row)*64 + c4*4];
    As[c4*4+0][row]=av.x; As[c4*4+1][row]=av.y; As[c4*4+2][row]=av.z; As[c4*4+3][row]=av.w;
    float4 bv = *(const float4*)&xb[(size_t)(bx*128 + row)*64 + c4*4];
    Bs[c4*4+0][row]=bv.x; Bs[c4*4+1][row]=bv.y; Bs[c4*4+2][row]=bv.z; Bs[c4*4+3][row]=bv.w;
  }
  __syncthreads();
  int u = tid&15, v = tid>>4;
  float acc[8][8];
  #pragma unroll
  for (int i=0;i<8;i++)
    #pragma unroll
    for (int j=0;j<8;j++) acc[i][j]=0.f;
  #pragma unroll 4
  for (int k=0;k<64;k++){
    float4 a0 = *(const float4*)&As[k][u*4];
    float4 a1 = *(const float4*)&As[k][64+u*4];
    float4 b0 = *(const float4*)&Bs[k][v*4];
    float4 b1 = *(const float4*)&Bs[k][64+v*4];
    float a[8] = {a0.x,a0.y,a0.z,a0.w,a1.x,a1.y,a1.z,a1.w};
    float bb[8] = {b0.x,b0.y,b0.z,b0.w,b1.x,b1.y,b1.z,b1.w};
    #pragma unroll
    for (int i=0;i<8;i++)
      #pragma unroll
      for (int j=0;j<8;j++)
        acc[i][j] = fmaf(a[i], bb[j], acc[i][j]);
  }
  float xn[8], xm[8];
  #pragma unroll
  for (int i=0;i<8;i++){
    int ri = (i<4)? u*4+i : 64+u*4+(i-4);
    xn[i] = xx[b*N_PTS + q0 + by*128 + ri];
  }
  #pragma unroll
  for (int j=0;j<8;j++){
    int cj = (j<4)? v*4+j : 64+v*4+(j-4);
    xm[j] = xx[b*N_PTS + bx*128 + cj];
  }
  #pragma unroll
  for (int i=0;i<8;i++){
    int ri = (i<4)? u*4+i : 64+u*4+(i-4);
    float* dst = pd + ((size_t)(b*S + by*128 + ri))*N_PTS + bx*128;
    float4 s0, s1;
    s0.x = fmaf(2.f,acc[i][0],-xn[i]) - xm[0];
    s0.y = fmaf(2.f,acc[i][1],-xn[i]) - xm[1];
    s0.z = fmaf(2.f,acc[i][2],-xn[i]) - xm[2];
    s0.w = fmaf(2.f,acc[i][3],-xn[i]) - xm[3];
    s1.x = fmaf(2.f,acc[i][4],-xn[i]) - xm[4];
    s1.y = fmaf(2.f,acc[i][5],-xn[i]) - xm[5];
    s1.z = fmaf(2.f,acc[i][6],-xn[i]) - xm[6];
    s1.w = fmaf(2.f,acc[i][7],-xn[i]) - xm[7];
    *(float4*)&dst[v*4] = s0;
    *(float4*)&dst[64+v*4] = s1;
  }
}

// ---- top-20 via radix-select on encoded keys; exact jax set {key >= K20}, key=(val desc, idx asc) ----
// One wave per query. Output order within the 20 is arbitrary (downstream is max over k).
__global__ __launch_bounds__(256) void k_topk20(const float* __restrict__ pdbuf, int* __restrict__ idxout,
                                                int q0, int sshift){
  __shared__ unsigned hist[4][256];
  __shared__ unsigned long long cand[4][64];
  int wid = threadIdx.x>>6, lane = threadIdx.x&63;
  int gw = blockIdx.x*4 + wid;
  int S = 1 << sshift;
  int b = gw >> sshift, i = gw & (S-1);
  const float* row = pdbuf + ((size_t)b*S + i)*N_PTS;
  int lane4 = lane*4;
  // load + encode 64 values; m(t) = (t>>2)*256 + lane*4 + (t&3)
  unsigned ve[64];
  #pragma unroll
  for (int t4=0;t4<16;t4++){
    float4 f = *(const float4*)&row[t4*256 + lane4];
    unsigned u;
    u=__float_as_uint(f.x); ve[t4*4+0] = u ^ ((unsigned)(((int)u)>>31) | 0x80000000u);
    u=__float_as_uint(f.y); ve[t4*4+1] = u ^ ((unsigned)(((int)u)>>31) | 0x80000000u);
    u=__float_as_uint(f.z); ve[t4*4+2] = u ^ ((unsigned)(((int)u)>>31) | 0x80000000u);
    u=__float_as_uint(f.w); ve[t4*4+3] = u ^ ((unsigned)(((int)u)>>31) | 0x80000000u);
  }
  // radix descent: 8 bits/level, find bin containing rank `need` (from top)
  unsigned prefix = 0; int need = 20, pop = 0, s_shift = 0;
  for (int level=0; level<4; ++level){
    int s = 24 - 8*level;
    *(uint4*)&hist[wid][lane4] = make_uint4(0u,0u,0u,0u);
    #pragma unroll
    for (int t=0;t<64;t++){
      bool match = (level==0) || ((ve[t]>>(s+8)) == prefix);
      if (match) atomicAdd(&hist[wid][(ve[t]>>s)&255u], 1u);
    }
    uint4 hh = *(const uint4*)&hist[wid][(63-lane)*4];
    // descending-bin order within lane: d0 = bin 255-4l, ...
    unsigned d0=hh.w, d1=hh.z, d2=hh.y, d3=hh.x;
    unsigned s0=d0, s1=s0+d1, s2=s1+d2, s3=s2+d3;
    int T = (int)s3, incl = T;
    #pragma unroll
    for (int off=1; off<64; off<<=1){ int vv = __shfl_up(incl, off); if (lane>=off) incl += vv; }
    int excl = incl - T;
    int c0=excl+(int)s0, c1=excl+(int)s1, c2=excl+(int)s2, c3=excl+(int)s3;
    int a0=excl, a1=c0, a2=c1, a3=c2;         // count strictly above bin k
    int kk = -1;
    if      (a0<need && c0>=need) kk=0;
    else if (a1<need && c1>=need) kk=1;
    else if (a2<need && c2>=need) kk=2;
    else if (a3<need && c3>=need) kk=3;
    unsigned packed = 0u;
    if (kk>=0){
      int bstar = 255 - (lane4 + kk);
      int above = (kk==0)?a0:(kk==1)?a1:(kk==2)?a2:a3;
      unsigned dk = (kk==0)?d0:(kk==1)?d1:(kk==2)?d2:d3;
      packed = ((unsigned)bstar<<18) | (dk<<5) | (unsigned)above;
    }
    unsigned long long bal = __ballot(kk>=0);
    int src = __ffsll((unsigned long long)bal) - 1;
    packed = (unsigned)__shfl((int)packed, src);
    int bstar = (int)(packed>>18);
    pop = (int)((packed>>5)&0x1FFFu);
    int above = (int)(packed&31u);
    need -= above;
    prefix = (prefix<<8) | (unsigned)bstar;
    if (pop <= 64 || s == 0){ s_shift = s; break; }
  }
  unsigned vmask = (s_shift==0) ? 0u : ((1u<<s_shift)-1u);
  unsigned pfull = prefix << s_shift;
  // candidate membership mask (static ve indexing only)
  unsigned long long mask = 0ull;
  #pragma unroll
  for (int t=0;t<64;t++){
    if ((ve[t] & ~vmask) == pfull) mask |= (1ull<<t);
  }
  unsigned vrem20 = 0u; int lo20 = 0;
  if (pop <= 64){
    int c = __popcll(mask);
    int incl = c;
    #pragma unroll
    for (int off=1; off<64; off<<=1){ int vv = __shfl_up(incl, off); if (lane>=off) incl += vv; }
    int p = incl - c;
    #pragma unroll
    for (int t=0;t<64;t++){
      if ((mask>>t)&1ull){
        int m = ((t>>2)<<8) + lane4 + (t&3);
        cand[wid][p] = ((((unsigned long long)(ve[t]&vmask))<<12) | (unsigned)(4095-m)) + 1ull;
        p++;
      }
    }
    __threadfence_block();
    unsigned long long mykey = (lane < pop) ? cand[wid][lane] : 0ull;
    unsigned long long thr = 0ull;
    for (int q2=0; q2<need; ++q2){
      unsigned long long wmax = mykey;
      #pragma unroll
      for (int off=32; off; off>>=1){
        unsigned long long o = __shfl_xor(wmax, off);
        if (o > wmax) wmax = o;
      }
      thr = wmax;
      if (q2+1 < need && mykey == wmax) mykey = 0ull;
    }
    thr -= 1ull;
    vrem20 = (unsigned)(thr >> 12);
    lo20 = (int)(thr & 0xFFFull);
  } else {
    // degenerate: >64 values with exactly equal fp32 value at the boundary (s_shift==0).
    // need-th smallest index m among matches.
    int R = 0, m_star = 0; bool f2 = false;
    for (int t4=0; t4<16 && !f2; ++t4){
      unsigned jf = (unsigned)((mask >> (4*t4)) & 15ull);
      int c4 = __popc(jf);
      int inc2 = c4;
      #pragma unroll
      for (int off=1; off<64; off<<=1){ int vv = __shfl_up(inc2, off); if (lane>=off) inc2 += vv; }
      int Ctot = __shfl(inc2, 63);
      if (R + Ctot >= need){
        int excl2 = inc2 - c4;
        int need2 = need - R;
        bool own = (excl2 < need2) && (need2 <= excl2 + c4);
        int jr = need2 - excl2;
        int cnt2 = 0, jstar = 0;
        #pragma unroll
        for (int j=0;j<4;j++){ if ((jf>>j)&1u){ cnt2++; if (cnt2==jr) jstar=j; } }
        int mloc = t4*256 + lane4 + jstar;
        unsigned long long bal2 = __ballot(own);
        int src2 = __ffsll((unsigned long long)bal2) - 1;
        m_star = __shfl(mloc, src2);
        f2 = true;
      } else R += Ctot;
    }
    vrem20 = 0u; lo20 = 4095 - m_star;
  }
  unsigned V20 = pfull | vrem20;
  // emission: key >= K20  (exactly 20 across wave; order irrelevant)
  unsigned long long msel = 0ull;
  #pragma unroll
  for (int t=0;t<64;t++){
    int m = ((t>>2)<<8) + lane4 + (t&3);
    bool sel = (ve[t] > V20) || (ve[t]==V20 && (4095-m) >= lo20);
    if (sel) msel |= (1ull<<t);
  }
  int ce = __popcll(msel);
  int incl = ce;
  #pragma unroll
  for (int off=1; off<64; off<<=1){ int vv = __shfl_up(incl, off); if (lane>=off) incl += vv; }
  int p = incl - ce;
  int* dst = idxout + ((size_t)b*N_PTS + (q0+i))*KNB;
  #pragma unroll
  for (int t=0;t<64;t++){
    if ((msel>>t)&1ull){
      dst[p] = ((t>>2)<<8) + lane4 + (t&3);
      p++;
    }
  }
}

// ---- edge conv block (gather + 1 or 2 convs + maxpool) ----
template<int TWO>
__global__ __launch_bounds__(256) void k_edgeconv(const float* __restrict__ xt, const int* __restrict__ idx,
    const float* __restrict__ WLT4, const float* __restrict__ WRT4, const float* __restrict__ bfa,
    const float* __restrict__ W2T4, const float* __restrict__ bfb,
    float* __restrict__ xout, float* __restrict__ Xcat, int rowofs, float* __restrict__ xxout){
  __shared__ float A[4][KNB][64];
  __shared__ float H[4][TWO?KNB:1][64];
  __shared__ float Cs[4][64];
  int wid = threadIdx.x>>6, lane = threadIdx.x&63;
  int pt = blockIdx.x*4 + wid, b = pt>>12, n = pt&4095;
  const float* xb = xt + (size_t)b*N_PTS*64;
  float ctr = xb[(size_t)n*64 + lane];
  Cs[wid][lane] = ctr;
  const int* ip = idx + (size_t)pt*KNB;
  #pragma unroll
  for (int k=0;k<KNB;k++){
    int m = ip[k];
    A[wid][k][lane] = xb[(size_t)m*64 + lane] - ctr;
  }
  __syncthreads();
  float e = bfa[lane];
  #pragma unroll
  for (int cb=0;cb<16;cb++){
    float4 wv = ((const float4*)WRT4)[cb*64+lane];
    float4 cv = *(const float4*)&Cs[wid][cb*4];
    e=fmaf(wv.x,cv.x,e); e=fmaf(wv.y,cv.y,e); e=fmaf(wv.z,cv.z,e); e=fmaf(wv.w,cv.w,e);
  }
  float acc[KNB];
  #pragma unroll
  for (int k=0;k<KNB;k++) acc[k]=e;
  for (int cb=0;cb<16;cb++){
    float4 wv = ((const float4*)WLT4)[cb*64+lane];
    #pragma unroll
    for (int k=0;k<KNB;k++){
      float4 a = *(const float4*)&A[wid][k][cb*4];
      acc[k]=fmaf(wv.x,a.x,acc[k]); acc[k]=fmaf(wv.y,a.y,acc[k]);
      acc[k]=fmaf(wv.z,a.z,acc[k]); acc[k]=fmaf(wv.w,a.w,acc[k]);
    }
  }
  if (TWO){
    #pragma unroll
    for (int k=0;k<KNB;k++) H[wid][k][lane] = lrelu(acc[k]);
    __syncthreads();
    #pragma unroll
    for (int k=0;k<KNB;k++) acc[k] = bfb[lane];
    for (int cb=0;cb<16;cb++){
      float4 wv = ((const float4*)W2T4)[cb*64+lane];
      #pragma unroll
      for (int k=0;k<KNB;k++){
        float4 a = *(const float4*)&H[wid][k][cb*4];
        acc[k]=fmaf(wv.x,a.x,acc[k]); acc[k]=fmaf(wv.y,a.y,acc[k]);
        acc[k]=fmaf(wv.z,a.z,acc[k]); acc[k]=fmaf(wv.w,a.w,acc[k]);
      }
    }
  }
  float mx = -INFINITY;
  #pragma unroll
  for (int k=0;k<KNB;k++) mx = fmaxf(mx, lrelu(acc[k]));
  if (xout) xout[(size_t)pt*64 + lane] = mx;
  Xcat[((size_t)b*192 + rowofs + lane)*N_PTS + n] = mx;
  if (xxout){
    float sq = mx*mx;
    #pragma unroll
    for (int off=32;off;off>>=1) sq += __shfl_xor(sq,off);
    if (lane==0) xxout[pt] = sq;
  }
}

// ---- generic fp32 GEMM: C[b][o][n] = act(A(OxK) @ B[b](KxN) + bias), optional col-max atomic ----
// flags: 1=leakyrelu, 2=store C, 4=bias per batch
__global__ __launch_bounds__(256) void k_gemm(const float* __restrict__ A, int lda,
        const float* __restrict__ B, const float* __restrict__ bias,
        float* __restrict__ C, unsigned* __restrict__ gmax,
        int O, int K, int flags){
  __shared__ float As[64][132];
  __shared__ float Bs[64][132];
  int tid = threadIdx.x, bx = blockIdx.x, by = blockIdx.y, b = blockIdx.z;
  int u = tid&15, v = tid>>4;
  float acc[8][8];
  #pragma unroll
  for (int i=0;i<8;i++)
    #pragma unroll
    for (int j=0;j<8;j++) acc[i][j]=0.f;
  const float* Bb = B + (size_t)b*K*N_PTS;
  for (int kt=0; kt<K; kt+=64){
    #pragma unroll
    for (int p=0;p<8;p++){
      int row = (tid>>4) + p*16, c4 = tid&15;
      int ga = by*128 + row;
      float4 av = (ga < O) ? *(const float4*)&A[(size_t)ga*lda + kt + c4*4] : make_float4(0.f,0.f,0.f,0.f);
      As[c4*4+0][row]=av.x; As[c4*4+1][row]=av.y; As[c4*4+2][row]=av.z; As[c4*4+3][row]=av.w;
      int kk = p*8 + (tid>>5), n4 = tid&31;
      float4 bv = *(const float4*)&Bb[(size_t)(kt+kk)*N_PTS + bx*128 + n4*4];
      *(float4*)&Bs[kk][n4*4] = bv;
    }
    __syncthreads();
    #pragma unroll 4
    for (int k=0;k<64;k++){
      float4 a0 = *(const float4*)&As[k][u*4];
      float4 a1 = *(const float4*)&As[k][64+u*4];
      float4 b0 = *(const float4*)&Bs[k][v*4];
      float4 b1 = *(const float4*)&Bs[k][64+v*4];
      float a[8] = {a0.x,a0.y,a0.z,a0.w,a1.x,a1.y,a1.z,a1.w};
      float bb[8] = {b0.x,b0.y,b0.z,b0.w,b1.x,b1.y,b1.z,b1.w};
      #pragma unroll
      for (int i=0;i<8;i++)
        #pragma unroll
        for (int j=0;j<8;j++)
          acc[i][j] = fmaf(a[i], bb[j], acc[i][j]);
    }
    __syncthreads();
  }
  bool relu = flags&1, store = flags&2, pbb = flags&4;
  float rowm[8];
  #pragma unroll
  for (int i=0;i<8;i++){
    int rl = (i<4)? u*4+i : 64+u*4+(i-4);
    int ri = by*128 + rl;
    float bvv = (bias != nullptr && ri < O) ? (pbb ? bias[b*O+ri] : bias[ri]) : 0.f;
    float vals[8];
    #pragma unroll
    for (int j=0;j<8;j++){
      float y = acc[i][j] + bvv;
      if (relu) y = lrelu(y);
      vals[j]=y;
    }
    if (store && ri < O){
      float* dst = C + ((size_t)b*O+ri)*N_PTS + bx*128;
      *(float4*)&dst[v*4] = make_float4(vals[0],vals[1],vals[2],vals[3]);
      *(float4*)&dst[64+v*4] = make_float4(vals[4],vals[5],vals[6],vals[7]);
    }
    float m = vals[0];
    #pragma unroll
    for (int j=1;j<8;j++) m = fmaxf(m, vals[j]);
    rowm[i] = m;
  }
  if (gmax != nullptr){
    float* red = &Bs[0][0];   // reuse as [128][16]
    #pragma unroll
    for (int i=0;i<8;i++){
      int rl = (i<4)? u*4+i : 64+u*4+(i-4);
      red[rl*16 + v] = rowm[i];
    }
    __syncthreads();
    if (tid < 128){
      float m = red[tid*16];
      #pragma unroll
      for (int j=1;j<16;j++) m = fmaxf(m, red[tid*16+j]);
      atomicMax(&gmax[b*1024 + by*128 + tid], fenc(m));
    }
  }
}

// bias7[b][o] = sum_{c<1024} Wf7[o][c]*g[b][c] + bf7[o]
__global__ __launch_bounds__(256) void k_gemv7(const float* __restrict__ Wf7, const float* __restrict__ bf7,
                        const unsigned* __restrict__ g, float* __restrict__ bias7){
  int wid = threadIdx.x>>6, lane = threadIdx.x&63;
  int o = blockIdx.x*4 + wid, b = blockIdx.y;
  const float* wr = Wf7 + (size_t)o*1216;
  const unsigned* gb = g + b*1024;
  float acc = 0.f;
  for (int c = lane; c < 1024; c += 64)
    acc = fmaf(wr[c], fdec(gb[c]), acc);
  #pragma unroll
  for (int off=32; off; off>>=1) acc += __shfl_xor(acc, off);
  if (lane==0) bias7[b*512+o] = acc + bf7[o];
}

extern "C" void kernel_launch(void* const* d_in, const int* in_sizes, int n_in,
                              void* d_out, int out_size, void* d_ws, size_t ws_size,
                              hipStream_t stream){
  const float* x  = (const float*)d_in[0];
  const float* W1 = (const float*)d_in[1];
  const float* W2 = (const float*)d_in[2];
  const float* W3 = (const float*)d_in[3];
  const float* W4 = (const float*)d_in[4];
  const float* W5 = (const float*)d_in[5];
  const float* W6 = (const float*)d_in[6];
  const float* W7 = (const float*)d_in[7];
  const float* W8 = (const float*)d_in[8];
  const float* W9 = (const float*)d_in[9];
  const float* bn1 = (const float*)d_in[10];
  const float* bn2 = (const float*)d_in[11];
  const float* bn3 = (const float*)d_in[12];
  const float* bn4 = (const float*)d_in[13];
  const float* bn5 = (const float*)d_in[14];
  const float* bn6 = (const float*)d_in[15];
  const float* bn7 = (const float*)d_in[16];
  const float* bn8 = (const float*)d_in[17];

  float* ws = (float*)d_ws;
  size_t off = 0;
  auto alloc = [&](size_t nf){ float* p = ws + off; off += (nf + 63) & ~(size_t)63; return p; };
  float* Wf6 = alloc(1024*192);   float* bf6 = alloc(1024);
  float* Wf7 = alloc((size_t)512*1216); float* bf7 = alloc(512);
  float* Wf8 = alloc(256*512);    float* bf8 = alloc(256);
  float* W1dT4 = alloc(8*64);     float* bf1 = alloc(64);
  float* W2T4  = alloc(64*64);    float* bf2 = alloc(64);
  float* W3LT4 = alloc(64*64);    float* W3RT4 = alloc(64*64); float* bf3 = alloc(64);
  float* W4T4  = alloc(64*64);    float* bf4 = alloc(64);
  float* W5LT4 = alloc(64*64);    float* W5RT4 = alloc(64*64); float* bf5 = alloc(64);
  float* U1  = alloc(4*KNB*64);
  float* x1t = alloc((size_t)4*N_PTS*64);
  float* x2t = alloc((size_t)4*N_PTS*64);
  float* Xcat = alloc((size_t)4*192*N_PTS);
  float* xx1 = alloc(4*N_PTS);
  float* xx2 = alloc(4*N_PTS);
  int* idx1 = (int*)alloc((size_t)4*N_PTS*KNB);
  int* idx2 = (int*)alloc((size_t)4*N_PTS*KNB);
  unsigned* genc = (unsigned*)alloc(4*1024);
  float* bias7 = alloc(4*512);
  float* h8 = alloc((size_t)4*256*N_PTS);
  // pdbuf takes the remainder; pick largest power-of-two stripe S (<=4096, >=512) that fits
  size_t remaining = (ws_size / 4 > off) ? (ws_size / 4 - off) : 0;
  int S = 4096;
  while (S > 512 && (size_t)4*S*N_PTS + 1024 > remaining) S >>= 1;
  int sshift = 31 - __builtin_clz(S);
  float* pdbuf = alloc((size_t)4*S*N_PTS);   // also reused as h7 (needs 32 MB <= pdbuf)
  float* h7 = pdbuf;

  // prep (every call: deterministic)
  k_scale_rows<<<(1024*192+255)/256,256,0,stream>>>(W6, bn6, Wf6, bf6, 1024, 192);
  k_scale_rows<<<(512*1216+255)/256,256,0,stream>>>(W7, bn7, Wf7, bf7, 512, 1216);
  k_scale_rows<<<(256*512+255)/256,256,0,stream>>>(W8, bn8, Wf8, bf8, 256, 512);
  k_build_T4<<<8,64,0,stream>>>(W1, 12, bn1, W1dT4, bf1, 0, 6, 6);     // (W1R - W1L), pad to 8
  k_build_T4<<<64,64,0,stream>>>(W2, 64, bn2, W2T4, bf2, 0, 0, 64);
  k_build_T4<<<64,64,0,stream>>>(W3, 128, bn3, W3LT4, bf3, 0, 0, 64);
  k_build_T4<<<64,64,0,stream>>>(W3, 128, bn3, W3RT4, nullptr, 64, 0, 64);
  k_build_T4<<<64,64,0,stream>>>(W4, 64, bn4, W4T4, bf4, 0, 0, 64);
  k_build_T4<<<64,64,0,stream>>>(W5, 128, bn5, W5LT4, bf5, 0, 0, 64);
  k_build_T4<<<64,64,0,stream>>>(W5, 128, bn5, W5RT4, nullptr, 64, 0, 64);
  k_build_U1<<<dim3(KNB,4),64,0,stream>>>(x, W1, bn1, U1);
  k_init_g<<<16,256,0,stream>>>(genc);

  // edge block 1 (neighbors = points 0..19 since KNN input is empty slice)
  k_edge1<<<4096,256,0,stream>>>(x, U1, W1dT4, bf1, W2T4, bf2, x1t, Xcat, xx1);

  int nstripe = N_PTS / S;
  // KNN on x1
  for (int s=0;s<nstripe;s++){
    k_knn_gemm<<<dim3(32,S/128,4),256,0,stream>>>(x1t, xx1, pdbuf, s*S, S);
    k_topk20<<<S,256,0,stream>>>(pdbuf, idx1, s*S, sshift);
  }

  // edge block 2 (two convs)
  k_edgeconv<1><<<4096,256,0,stream>>>(x1t, idx1, W3LT4, W3RT4, bf3, W4T4, bf4, x2t, Xcat, 64, xx2);

  // KNN on x2
  for (int s=0;s<nstripe;s++){
    k_knn_gemm<<<dim3(32,S/128,4),256,0,stream>>>(x2t, xx2, pdbuf, s*S, S);
    k_topk20<<<S,256,0,stream>>>(pdbuf, idx2, s*S, sshift);
  }

  // edge block 3 (one conv)
  k_edgeconv<0><<<4096,256,0,stream>>>(x2t, idx2, W5LT4, W5RT4, bf5, nullptr, nullptr, nullptr, Xcat, 128, nullptr);

  // conv6 (1024x192) -> only column max g (atomic, no store)
  k_gemm<<<dim3(32,8,4),256,0,stream>>>(Wf6, 192, Xcat, bf6, nullptr, genc, 1024, 192, 1);
  // bias7[b][o] = W7[:, :1024] @ g + bf7
  k_gemv7<<<dim3(128,4),256,0,stream>>>(Wf7, bf7, genc, bias7);
  // conv7: W7[:, 1024:1216] @ Xcat + bias7 (per batch)
  k_gemm<<<dim3(32,4,4),256,0,stream>>>(Wf7+1024, 1216, Xcat, bias7, h7, nullptr, 512, 192, 1|2|4);
  // conv8: 256x512
  k_gemm<<<dim3(32,2,4),256,0,stream>>>(Wf8, 512, h7, bf8, h8, nullptr, 256, 512, 1|2);
  // conv9: 13x256, no bias/relu -> d_out
  k_gemm<<<dim3(32,1,4),256,0,stream>>>(W9, 256, h8, nullptr, (float*)d_out, nullptr, 13, 256, 2);
}

// Round 4
// 1088.854 us; speedup vs baseline: 1.1664x; 1.1664x over previous
//
#include <hip/hip_runtime.h>
#include <math.h>

#define N_PTS 4096
#define BATCH 4
#define KNB 20

__device__ __forceinline__ float lrelu(float v){ return fmaxf(v, 0.2f*v); }
__device__ __forceinline__ unsigned fenc(float f){ unsigned u=__float_as_uint(f); return (u&0x80000000u)?~u:(u|0x80000000u); }
__device__ __forceinline__ float fdec(unsigned k){ return (k&0x80000000u)?__uint_as_float(k&0x7fffffffu):__uint_as_float(~k); }

// ---- prep: fold BN scale into weights ----
__global__ void k_scale_rows(const float* __restrict__ W, const float* __restrict__ bn,
                             float* __restrict__ Wf, float* __restrict__ bias, int O, int C){
  int i = blockIdx.x*256 + threadIdx.x;
  if (i >= O*C) return;
  int o = i / C;
  float s = bn[o] / sqrtf(bn[3*O+o] + 1e-5f);
  Wf[i] = W[i]*s;
  if (i % C == 0) bias[o] = bn[O+o] - s*bn[2*O+o];
}

// transposed float4-chunk layout: dst[(c/4)*256 + o*4 + c%4], O=64 fixed
__global__ void k_build_T4(const float* __restrict__ W, int ldw, const float* __restrict__ bn,
                           float* __restrict__ dst, float* __restrict__ bias,
                           int c0, int diffoff, int Csrc){
  int o = threadIdx.x, c = blockIdx.x;
  float s = bn[o] / sqrtf(bn[192+o] + 1e-5f);
  float val = 0.f;
  if (c < Csrc){
    val = W[o*ldw + c0 + c];
    if (diffoff) val = W[o*ldw + c0 + diffoff + c] - val;
    val *= s;
  }
  dst[(c>>2)*256 + o*4 + (c&3)] = val;
  if (bias != nullptr && c==0) bias[o] = bn[64+o] - s*bn[128+o];
}

// U1[b][k][o] = sum_{c<6} s_o*W1[o][c]*x[b][c][k]  (first-KNN neighbors are points 0..19)
__global__ void k_build_U1(const float* __restrict__ x, const float* __restrict__ W1,
                           const float* __restrict__ bn, float* __restrict__ U1){
  int o = threadIdx.x, k = blockIdx.x, b = blockIdx.y;
  float s = bn[o] / sqrtf(bn[192+o] + 1e-5f);
  float acc = 0.f;
  #pragma unroll
  for (int c=0;c<6;c++) acc += W1[o*12+c] * x[(b*6+c)*N_PTS + k];
  U1[(b*KNB+k)*64 + o] = acc*s;
}

__global__ void k_init_g(unsigned* g){ g[blockIdx.x*256+threadIdx.x] = fenc(-INFINITY); }

// ---- edge block 1 (trivial neighbors 0..19) : conv1 + conv2 + maxpool ----
__global__ __launch_bounds__(256) void k_edge1(const float* __restrict__ x, const float* __restrict__ U1,
                        const float* __restrict__ W1dT4, const float* __restrict__ bf1,
                        const float* __restrict__ W2T4, const float* __restrict__ bf2,
                        float* __restrict__ x1t, float* __restrict__ Xcat, float* __restrict__ xx1){
  __shared__ float hb[4][KNB][64];
  int wid = threadIdx.x>>6, lane = threadIdx.x&63;
  int pt = blockIdx.x*4 + wid, b = pt>>12, n = pt&4095;
  float xv[8];
  #pragma unroll
  for (int c=0;c<6;c++) xv[c] = x[(b*6+c)*N_PTS + n];
  xv[6]=0.f; xv[7]=0.f;
  float w = bf1[lane];
  #pragma unroll
  for (int cb=0;cb<2;cb++){
    float4 wv = ((const float4*)W1dT4)[cb*64+lane];
    w = fmaf(wv.x, xv[cb*4+0], w); w = fmaf(wv.y, xv[cb*4+1], w);
    w = fmaf(wv.z, xv[cb*4+2], w); w = fmaf(wv.w, xv[cb*4+3], w);
  }
  const float* Ub = U1 + b*KNB*64;
  #pragma unroll
  for (int k=0;k<KNB;k++) hb[wid][k][lane] = lrelu(Ub[k*64+lane] + w);
  __syncthreads();
  float acc[KNB];
  #pragma unroll
  for (int k=0;k<KNB;k++) acc[k] = bf2[lane];
  for (int cb=0;cb<16;cb++){
    float4 wv = ((const float4*)W2T4)[cb*64+lane];
    #pragma unroll
    for (int k=0;k<KNB;k++){
      float4 a = *(const float4*)&hb[wid][k][cb*4];
      acc[k]=fmaf(wv.x,a.x,acc[k]); acc[k]=fmaf(wv.y,a.y,acc[k]);
      acc[k]=fmaf(wv.z,a.z,acc[k]); acc[k]=fmaf(wv.w,a.w,acc[k]);
    }
  }
  float mx = -INFINITY;
  #pragma unroll
  for (int k=0;k<KNB;k++) mx = fmaxf(mx, lrelu(acc[k]));
  x1t[(size_t)pt*64 + lane] = mx;
  Xcat[((size_t)b*192 + 0 + lane)*N_PTS + n] = mx;
  float sq = mx*mx;
  #pragma unroll
  for (int off=32; off; off>>=1) sq += __shfl_xor(sq, off);
  if (lane==0) xx1[pt] = sq;
}

// ---- KNN pairwise kernel: pd[b][i][j] = fma(2,dot,-xx_n) - xx_m, 128x128 tile, K=64 ----
__global__ __launch_bounds__(256) void k_knn_gemm(const float* __restrict__ xt, const float* __restrict__ xx,
                          float* __restrict__ pd, int q0, int S){
  __shared__ float As[64][132];
  __shared__ float Bs[64][132];
  int tid = threadIdx.x;
  int bx = blockIdx.x, by = blockIdx.y, b = blockIdx.z;
  const float* xb = xt + (size_t)b*N_PTS*64;
  #pragma unroll
  for (int p=0;p<8;p++){
    int row = (tid>>4) + p*16, c4 = tid&15;
    float4 av = *(const float4*)&xb[(size_t)(q0 + by*128 + row)*64 + c4*4];
    As[c4*4+0][row]=av.x; As[c4*4+1][row]=av.y; As[c4*4+2][row]=av.z; As[c4*4+3][row]=av.w;
    float4 bv = *(const float4*)&xb[(size_t)(bx*128 + row)*64 + c4*4];
    Bs[c4*4+0][row]=bv.x; Bs[c4*4+1][row]=bv.y; Bs[c4*4+2][row]=bv.z; Bs[c4*4+3][row]=bv.w;
  }
  __syncthreads();
  int u = tid&15, v = tid>>4;
  float acc[8][8];
  #pragma unroll
  for (int i=0;i<8;i++)
    #pragma unroll
    for (int j=0;j<8;j++) acc[i][j]=0.f;
  #pragma unroll 4
  for (int k=0;k<64;k++){
    float4 a0 = *(const float4*)&As[k][u*4];
    float4 a1 = *(const float4*)&As[k][64+u*4];
    float4 b0 = *(const float4*)&Bs[k][v*4];
    float4 b1 = *(const float4*)&Bs[k][64+v*4];
    float a[8] = {a0.x,a0.y,a0.z,a0.w,a1.x,a1.y,a1.z,a1.w};
    float bb[8] = {b0.x,b0.y,b0.z,b0.w,b1.x,b1.y,b1.z,b1.w};
    #pragma unroll
    for (int i=0;i<8;i++)
      #pragma unroll
      for (int j=0;j<8;j++)
        acc[i][j] = fmaf(a[i], bb[j], acc[i][j]);
  }
  float xn[8], xm[8];
  #pragma unroll
  for (int i=0;i<8;i++){
    int ri = (i<4)? u*4+i : 64+u*4+(i-4);
    xn[i] = xx[b*N_PTS + q0 + by*128 + ri];
  }
  #pragma unroll
  for (int j=0;j<8;j++){
    int cj = (j<4)? v*4+j : 64+v*4+(j-4);
    xm[j] = xx[b*N_PTS + bx*128 + cj];
  }
  #pragma unroll
  for (int i=0;i<8;i++){
    int ri = (i<4)? u*4+i : 64+u*4+(i-4);
    float* dst = pd + ((size_t)(b*S + by*128 + ri))*N_PTS + bx*128;
    float4 s0, s1;
    s0.x = fmaf(2.f,acc[i][0],-xn[i]) - xm[0];
    s0.y = fmaf(2.f,acc[i][1],-xn[i]) - xm[1];
    s0.z = fmaf(2.f,acc[i][2],-xn[i]) - xm[2];
    s0.w = fmaf(2.f,acc[i][3],-xn[i]) - xm[3];
    s1.x = fmaf(2.f,acc[i][4],-xn[i]) - xm[4];
    s1.y = fmaf(2.f,acc[i][5],-xn[i]) - xm[5];
    s1.z = fmaf(2.f,acc[i][6],-xn[i]) - xm[6];
    s1.w = fmaf(2.f,acc[i][7],-xn[i]) - xm[7];
    *(float4*)&dst[v*4] = s0;
    *(float4*)&dst[64+v*4] = s1;
  }
}

// ---- top-20 via ballot-bisection; exact jax set {key >= K20}, key=(val desc, idx asc) ----
// One wave per query; no LDS atomics, no histograms. Output order within the 20 arbitrary.
__global__ __launch_bounds__(256) void k_topk20(const float* __restrict__ pdbuf, int* __restrict__ idxout,
                                                int q0, int sshift){
  __shared__ unsigned long long cand[4][64];
  int wid = threadIdx.x>>6, lane = threadIdx.x&63;
  int gw = blockIdx.x*4 + wid;
  int S = 1 << sshift;
  int b = gw >> sshift, i = gw & (S-1);
  const float* row = pdbuf + ((size_t)b*S + i)*N_PTS;
  int lane4 = lane*4;
  // load + encode 64 values; value t lives at column m = (t>>2)*256 + lane*4 + (t&3)
  unsigned ve[64];
  #pragma unroll
  for (int t4=0;t4<16;t4++){
    float4 f = *(const float4*)&row[t4*256 + lane4];
    unsigned u;
    u=__float_as_uint(f.x); ve[t4*4+0] = u ^ ((unsigned)(((int)u)>>31) | 0x80000000u);
    u=__float_as_uint(f.y); ve[t4*4+1] = u ^ ((unsigned)(((int)u)>>31) | 0x80000000u);
    u=__float_as_uint(f.z); ve[t4*4+2] = u ^ ((unsigned)(((int)u)>>31) | 0x80000000u);
    u=__float_as_uint(f.w); ve[t4*4+3] = u ^ ((unsigned)(((int)u)>>31) | 0x80000000u);
  }
  // per-lane max (ILP tree)
  unsigned tm[32];
  #pragma unroll
  for (int t=0;t<32;t++) tm[t] = ve[t] > ve[t+32] ? ve[t] : ve[t+32];
  #pragma unroll
  for (int t=0;t<16;t++) tm[t] = tm[t] > tm[t+16] ? tm[t] : tm[t+16];
  #pragma unroll
  for (int t=0;t<8;t++)  tm[t] = tm[t] > tm[t+8]  ? tm[t] : tm[t+8];
  #pragma unroll
  for (int t=0;t<4;t++)  tm[t] = tm[t] > tm[t+4]  ? tm[t] : tm[t+4];
  tm[0] = tm[0] > tm[2] ? tm[0] : tm[2];
  tm[1] = tm[1] > tm[3] ? tm[1] : tm[3];
  unsigned lmax = tm[0] > tm[1] ? tm[0] : tm[1];
  // ballot-bisect: T = exact 20th-largest lane max  => count(all values >= T) >= 20
  unsigned T = 0u;
  #pragma unroll
  for (int bb=31; bb>=0; --bb){
    unsigned cnd = T | (1u<<bb);
    int c = __popcll(__ballot(lmax >= cnd));
    if (c >= KNB) T = cnd;
  }
  // candidate mask
  unsigned long long msk = 0ull;
  #pragma unroll
  for (int t=0;t<64;t++){
    if (ve[t] >= T) msk |= (1ull<<t);
  }
  int cnt = __popcll(msk);
  int incl = cnt;
  #pragma unroll
  for (int off=1; off<64; off<<=1){ int vv = __shfl_up(incl, off); if (lane>=off) incl += vv; }
  int base = incl - cnt;
  int C = __shfl(incl, 63);
  unsigned long long K = 0ull;
  if (C <= 64){
    // compact candidate keys (one per slot) and bisect 44-bit key across lanes
    int p = base;
    #pragma unroll
    for (int t=0;t<64;t++){
      if ((msk>>t)&1ull){
        int m = ((t>>2)<<8) + lane4 + (t&3);
        cand[wid][p] = (((unsigned long long)ve[t])<<12) | (unsigned)(4095-m);
        p++;
      }
    }
    __threadfence_block();
    unsigned long long mykey = cand[wid][lane];
    bool valid = lane < C;
    #pragma unroll
    for (int bb=43; bb>=0; --bb){
      unsigned long long cnd = K | (1ull<<bb);
      int c = __popcll(__ballot(valid && mykey >= cnd));
      if (c >= KNB) K = cnd;
    }
  } else {
    // degenerate (massive value ties): exact 44-bit bisect with per-lane masked counts
    for (int bb=43; bb>=0; --bb){
      unsigned long long cnd = K | (1ull<<bb);
      int lc = 0;
      #pragma unroll
      for (int t=0;t<64;t++){
        if ((msk>>t)&1ull){
          int m = ((t>>2)<<8) + lane4 + (t&3);
          unsigned long long key = (((unsigned long long)ve[t])<<12) | (unsigned)(4095-m);
          if (key >= cnd) lc++;
        }
      }
      #pragma unroll
      for (int off=32; off; off>>=1) lc += __shfl_xor(lc, off);
      if (lc >= KNB) K = cnd;
    }
  }
  // emission: the exactly-20 candidates with key >= K (keys unique)
  unsigned long long msel = 0ull;
  #pragma unroll
  for (int t=0;t<64;t++){
    if ((msk>>t)&1ull){
      int m = ((t>>2)<<8) + lane4 + (t&3);
      unsigned long long key = (((unsigned long long)ve[t])<<12) | (unsigned)(4095-m);
      if (key >= K) msel |= (1ull<<t);
    }
  }
  int ce = __popcll(msel);
  int incl2 = ce;
  #pragma unroll
  for (int off=1; off<64; off<<=1){ int vv = __shfl_up(incl2, off); if (lane>=off) incl2 += vv; }
  int p2 = incl2 - ce;
  int* dst = idxout + ((size_t)b*N_PTS + (q0+i))*KNB;
  #pragma unroll
  for (int t=0;t<64;t++){
    if ((msel>>t)&1ull){
      dst[p2] = ((t>>2)<<8) + lane4 + (t&3);
      p2++;
    }
  }
}

// ---- edge conv block (gather + 1 or 2 convs + maxpool) ----
template<int TWO>
__global__ __launch_bounds__(256) void k_edgeconv(const float* __restrict__ xt, const int* __restrict__ idx,
    const float* __restrict__ WLT4, const float* __restrict__ WRT4, const float* __restrict__ bfa,
    const float* __restrict__ W2T4, const float* __restrict__ bfb,
    float* __restrict__ xout, float* __restrict__ Xcat, int rowofs, float* __restrict__ xxout){
  __shared__ float A[4][KNB][64];
  __shared__ float H[4][TWO?KNB:1][64];
  __shared__ float Cs[4][64];
  int wid = threadIdx.x>>6, lane = threadIdx.x&63;
  int pt = blockIdx.x*4 + wid, b = pt>>12, n = pt&4095;
  const float* xb = xt + (size_t)b*N_PTS*64;
  float ctr = xb[(size_t)n*64 + lane];
  Cs[wid][lane] = ctr;
  const int* ip = idx + (size_t)pt*KNB;
  #pragma unroll
  for (int k=0;k<KNB;k++){
    int m = ip[k];
    A[wid][k][lane] = xb[(size_t)m*64 + lane] - ctr;
  }
  __syncthreads();
  float e = bfa[lane];
  #pragma unroll
  for (int cb=0;cb<16;cb++){
    float4 wv = ((const float4*)WRT4)[cb*64+lane];
    float4 cv = *(const float4*)&Cs[wid][cb*4];
    e=fmaf(wv.x,cv.x,e); e=fmaf(wv.y,cv.y,e); e=fmaf(wv.z,cv.z,e); e=fmaf(wv.w,cv.w,e);
  }
  float acc[KNB];
  #pragma unroll
  for (int k=0;k<KNB;k++) acc[k]=e;
  for (int cb=0;cb<16;cb++){
    float4 wv = ((const float4*)WLT4)[cb*64+lane];
    #pragma unroll
    for (int k=0;k<KNB;k++){
      float4 a = *(const float4*)&A[wid][k][cb*4];
      acc[k]=fmaf(wv.x,a.x,acc[k]); acc[k]=fmaf(wv.y,a.y,acc[k]);
      acc[k]=fmaf(wv.z,a.z,acc[k]); acc[k]=fmaf(wv.w,a.w,acc[k]);
    }
  }
  if (TWO){
    #pragma unroll
    for (int k=0;k<KNB;k++) H[wid][k][lane] = lrelu(acc[k]);
    __syncthreads();
    #pragma unroll
    for (int k=0;k<KNB;k++) acc[k] = bfb[lane];
    for (int cb=0;cb<16;cb++){
      float4 wv = ((const float4*)W2T4)[cb*64+lane];
      #pragma unroll
      for (int k=0;k<KNB;k++){
        float4 a = *(const float4*)&H[wid][k][cb*4];
        acc[k]=fmaf(wv.x,a.x,acc[k]); acc[k]=fmaf(wv.y,a.y,acc[k]);
        acc[k]=fmaf(wv.z,a.z,acc[k]); acc[k]=fmaf(wv.w,a.w,acc[k]);
      }
    }
  }
  float mx = -INFINITY;
  #pragma unroll
  for (int k=0;k<KNB;k++) mx = fmaxf(mx, lrelu(acc[k]));
  if (xout) xout[(size_t)pt*64 + lane] = mx;
  Xcat[((size_t)b*192 + rowofs + lane)*N_PTS + n] = mx;
  if (xxout){
    float sq = mx*mx;
    #pragma unroll
    for (int off=32;off;off>>=1) sq += __shfl_xor(sq,off);
    if (lane==0) xxout[pt] = sq;
  }
}

// ---- generic fp32 GEMM: C[b][o][n] = act(A(OxK) @ B[b](KxN) + bias), optional col-max atomic ----
// flags: 1=leakyrelu, 2=store C, 4=bias per batch
__global__ __launch_bounds__(256) void k_gemm(const float* __restrict__ A, int lda,
        const float* __restrict__ B, const float* __restrict__ bias,
        float* __restrict__ C, unsigned* __restrict__ gmax,
        int O, int K, int flags){
  __shared__ float As[64][132];
  __shared__ float Bs[64][132];
  int tid = threadIdx.x, bx = blockIdx.x, by = blockIdx.y, b = blockIdx.z;
  int u = tid&15, v = tid>>4;
  float acc[8][8];
  #pragma unroll
  for (int i=0;i<8;i++)
    #pragma unroll
    for (int j=0;j<8;j++) acc[i][j]=0.f;
  const float* Bb = B + (size_t)b*K*N_PTS;
  for (int kt=0; kt<K; kt+=64){
    #pragma unroll
    for (int p=0;p<8;p++){
      int row = (tid>>4) + p*16, c4 = tid&15;
      int ga = by*128 + row;
      float4 av = (ga < O) ? *(const float4*)&A[(size_t)ga*lda + kt + c4*4] : make_float4(0.f,0.f,0.f,0.f);
      As[c4*4+0][row]=av.x; As[c4*4+1][row]=av.y; As[c4*4+2][row]=av.z; As[c4*4+3][row]=av.w;
      int kk = p*8 + (tid>>5), n4 = tid&31;
      float4 bv = *(const float4*)&Bb[(size_t)(kt+kk)*N_PTS + bx*128 + n4*4];
      *(float4*)&Bs[kk][n4*4] = bv;
    }
    __syncthreads();
    #pragma unroll 4
    for (int k=0;k<64;k++){
      float4 a0 = *(const float4*)&As[k][u*4];
      float4 a1 = *(const float4*)&As[k][64+u*4];
      float4 b0 = *(const float4*)&Bs[k][v*4];
      float4 b1 = *(const float4*)&Bs[k][64+v*4];
      float a[8] = {a0.x,a0.y,a0.z,a0.w,a1.x,a1.y,a1.z,a1.w};
      float bb[8] = {b0.x,b0.y,b0.z,b0.w,b1.x,b1.y,b1.z,b1.w};
      #pragma unroll
      for (int i=0;i<8;i++)
        #pragma unroll
        for (int j=0;j<8;j++)
          acc[i][j] = fmaf(a[i], bb[j], acc[i][j]);
    }
    __syncthreads();
  }
  bool relu = flags&1, store = flags&2, pbb = flags&4;
  float rowm[8];
  #pragma unroll
  for (int i=0;i<8;i++){
    int rl = (i<4)? u*4+i : 64+u*4+(i-4);
    int ri = by*128 + rl;
    float bvv = (bias != nullptr && ri < O) ? (pbb ? bias[b*O+ri] : bias[ri]) : 0.f;
    float vals[8];
    #pragma unroll
    for (int j=0;j<8;j++){
      float y = acc[i][j] + bvv;
      if (relu) y = lrelu(y);
      vals[j]=y;
    }
    if (store && ri < O){
      float* dst = C + ((size_t)b*O+ri)*N_PTS + bx*128;
      *(float4*)&dst[v*4] = make_float4(vals[0],vals[1],vals[2],vals[3]);
      *(float4*)&dst[64+v*4] = make_float4(vals[4],vals[5],vals[6],vals[7]);
    }
    float m = vals[0];
    #pragma unroll
    for (int j=1;j<8;j++) m = fmaxf(m, vals[j]);
    rowm[i] = m;
  }
  if (gmax != nullptr){
    float* red = &Bs[0][0];   // reuse as [128][16]
    #pragma unroll
    for (int i=0;i<8;i++){
      int rl = (i<4)? u*4+i : 64+u*4+(i-4);
      red[rl*16 + v] = rowm[i];
    }
    __syncthreads();
    if (tid < 128){
      float m = red[tid*16];
      #pragma unroll
      for (int j=1;j<16;j++) m = fmaxf(m, red[tid*16+j]);
      atomicMax(&gmax[b*1024 + by*128 + tid], fenc(m));
    }
  }
}

// bias7[b][o] = sum_{c<1024} Wf7[o][c]*g[b][c] + bf7[o]
__global__ __launch_bounds__(256) void k_gemv7(const float* __restrict__ Wf7, const float* __restrict__ bf7,
                        const unsigned* __restrict__ g, float* __restrict__ bias7){
  int wid = threadIdx.x>>6, lane = threadIdx.x&63;
  int o = blockIdx.x*4 + wid, b = blockIdx.y;
  const float* wr = Wf7 + (size_t)o*1216;
  const unsigned* gb = g + b*1024;
  float acc = 0.f;
  for (int c = lane; c < 1024; c += 64)
    acc = fmaf(wr[c], fdec(gb[c]), acc);
  #pragma unroll
  for (int off=32; off; off>>=1) acc += __shfl_xor(acc, off);
  if (lane==0) bias7[b*512+o] = acc + bf7[o];
}

extern "C" void kernel_launch(void* const* d_in, const int* in_sizes, int n_in,
                              void* d_out, int out_size, void* d_ws, size_t ws_size,
                              hipStream_t stream){
  const float* x  = (const float*)d_in[0];
  const float* W1 = (const float*)d_in[1];
  const float* W2 = (const float*)d_in[2];
  const float* W3 = (const float*)d_in[3];
  const float* W4 = (const float*)d_in[4];
  const float* W5 = (const float*)d_in[5];
  const float* W6 = (const float*)d_in[6];
  const float* W7 = (const float*)d_in[7];
  const float* W8 = (const float*)d_in[8];
  const float* W9 = (const float*)d_in[9];
  const float* bn1 = (const float*)d_in[10];
  const float* bn2 = (const float*)d_in[11];
  const float* bn3 = (const float*)d_in[12];
  const float* bn4 = (const float*)d_in[13];
  const float* bn5 = (const float*)d_in[14];
  const float* bn6 = (const float*)d_in[15];
  const float* bn7 = (const float*)d_in[16];
  const float* bn8 = (const float*)d_in[17];

  float* ws = (float*)d_ws;
  size_t off = 0;
  auto alloc = [&](size_t nf){ float* p = ws + off; off += (nf + 63) & ~(size_t)63; return p; };
  float* Wf6 = alloc(1024*192);   float* bf6 = alloc(1024);
  float* Wf7 = alloc((size_t)512*1216); float* bf7 = alloc(512);
  float* Wf8 = alloc(256*512);    float* bf8 = alloc(256);
  float* W1dT4 = alloc(8*64);     float* bf1 = alloc(64);
  float* W2T4  = alloc(64*64);    float* bf2 = alloc(64);
  float* W3LT4 = alloc(64*64);    float* W3RT4 = alloc(64*64); float* bf3 = alloc(64);
  float* W4T4  = alloc(64*64);    float* bf4 = alloc(64);
  float* W5LT4 = alloc(64*64);    float* W5RT4 = alloc(64*64); float* bf5 = alloc(64);
  float* U1  = alloc(4*KNB*64);
  float* x1t = alloc((size_t)4*N_PTS*64);
  float* x2t = alloc((size_t)4*N_PTS*64);
  float* Xcat = alloc((size_t)4*192*N_PTS);
  float* xx1 = alloc(4*N_PTS);
  float* xx2 = alloc(4*N_PTS);
  int* idx1 = (int*)alloc((size_t)4*N_PTS*KNB);
  int* idx2 = (int*)alloc((size_t)4*N_PTS*KNB);
  unsigned* genc = (unsigned*)alloc(4*1024);
  float* bias7 = alloc(4*512);
  float* h8 = alloc((size_t)4*256*N_PTS);
  // pdbuf takes the remainder; pick largest power-of-two stripe S (<=4096, >=512) that fits
  size_t remaining = (ws_size / 4 > off) ? (ws_size / 4 - off) : 0;
  int S = 4096;
  while (S > 512 && (size_t)4*S*N_PTS + 1024 > remaining) S >>= 1;
  int sshift = 31 - __builtin_clz(S);
  float* pdbuf = alloc((size_t)4*S*N_PTS);   // also reused as h7 (needs 32 MB <= pdbuf)
  float* h7 = pdbuf;

  // prep (every call: deterministic)
  k_scale_rows<<<(1024*192+255)/256,256,0,stream>>>(W6, bn6, Wf6, bf6, 1024, 192);
  k_scale_rows<<<(512*1216+255)/256,256,0,stream>>>(W7, bn7, Wf7, bf7, 512, 1216);
  k_scale_rows<<<(256*512+255)/256,256,0,stream>>>(W8, bn8, Wf8, bf8, 256, 512);
  k_build_T4<<<8,64,0,stream>>>(W1, 12, bn1, W1dT4, bf1, 0, 6, 6);     // (W1R - W1L), pad to 8
  k_build_T4<<<64,64,0,stream>>>(W2, 64, bn2, W2T4, bf2, 0, 0, 64);
  k_build_T4<<<64,64,0,stream>>>(W3, 128, bn3, W3LT4, bf3, 0, 0, 64);
  k_build_T4<<<64,64,0,stream>>>(W3, 128, bn3, W3RT4, nullptr, 64, 0, 64);
  k_build_T4<<<64,64,0,stream>>>(W4, 64, bn4, W4T4, bf4, 0, 0, 64);
  k_build_T4<<<64,64,0,stream>>>(W5, 128, bn5, W5LT4, bf5, 0, 0, 64);
  k_build_T4<<<64,64,0,stream>>>(W5, 128, bn5, W5RT4, nullptr, 64, 0, 64);
  k_build_U1<<<dim3(KNB,4),64,0,stream>>>(x, W1, bn1, U1);
  k_init_g<<<16,256,0,stream>>>(genc);

  // edge block 1 (neighbors = points 0..19 since KNN input is empty slice)
  k_edge1<<<4096,256,0,stream>>>(x, U1, W1dT4, bf1, W2T4, bf2, x1t, Xcat, xx1);

  int nstripe = N_PTS / S;
  // KNN on x1
  for (int s=0;s<nstripe;s++){
    k_knn_gemm<<<dim3(32,S/128,4),256,0,stream>>>(x1t, xx1, pdbuf, s*S, S);
    k_topk20<<<S,256,0,stream>>>(pdbuf, idx1, s*S, sshift);
  }

  // edge block 2 (two convs)
  k_edgeconv<1><<<4096,256,0,stream>>>(x1t, idx1, W3LT4, W3RT4, bf3, W4T4, bf4, x2t, Xcat, 64, xx2);

  // KNN on x2
  for (int s=0;s<nstripe;s++){
    k_knn_gemm<<<dim3(32,S/128,4),256,0,stream>>>(x2t, xx2, pdbuf, s*S, S);
    k_topk20<<<S,256,0,stream>>>(pdbuf, idx2, s*S, sshift);
  }

  // edge block 3 (one conv)
  k_edgeconv<0><<<4096,256,0,stream>>>(x2t, idx2, W5LT4, W5RT4, bf5, nullptr, nullptr, nullptr, Xcat, 128, nullptr);

  // conv6 (1024x192) -> only column max g (atomic, no store)
  k_gemm<<<dim3(32,8,4),256,0,stream>>>(Wf6, 192, Xcat, bf6, nullptr, genc, 1024, 192, 1);
  // bias7[b][o] = W7[:, :1024] @ g + bf7
  k_gemv7<<<dim3(128,4),256,0,stream>>>(Wf7, bf7, genc, bias7);
  // conv7: W7[:, 1024:1216] @ Xcat + bias7 (per batch)
  k_gemm<<<dim3(32,4,4),256,0,stream>>>(Wf7+1024, 1216, Xcat, bias7, h7, nullptr, 512, 192, 1|2|4);
  // conv8: 256x512
  k_gemm<<<dim3(32,2,4),256,0,stream>>>(Wf8, 512, h7, bf8, h8, nullptr, 256, 512, 1|2);
  // conv9: 13x256, no bias/relu -> d_out
  k_gemm<<<dim3(32,1,4),256,0,stream>>>(W9, 256, h8, nullptr, (float*)d_out, nullptr, 13, 256, 2);
}

// Round 5
// 1011.477 us; speedup vs baseline: 1.2556x; 1.0765x over previous
//
#include <hip/hip_runtime.h>
#include <math.h>

#define N_PTS 4096
#define BATCH 4
#define KNB 20

__device__ __forceinline__ float lrelu(float v){ return fmaxf(v, 0.2f*v); }
__device__ __forceinline__ unsigned fenc(float f){ unsigned u=__float_as_uint(f); return (u&0x80000000u)?~u:(u|0x80000000u); }
__device__ __forceinline__ float fdec(unsigned k){ return (k&0x80000000u)?__uint_as_float(k&0x7fffffffu):__uint_as_float(~k); }

// ---- prep: fold BN scale into weights ----
__global__ void k_scale_rows(const float* __restrict__ W, const float* __restrict__ bn,
                             float* __restrict__ Wf, float* __restrict__ bias, int O, int C){
  int i = blockIdx.x*256 + threadIdx.x;
  if (i >= O*C) return;
  int o = i / C;
  float s = bn[o] / sqrtf(bn[3*O+o] + 1e-5f);
  Wf[i] = W[i]*s;
  if (i % C == 0) bias[o] = bn[O+o] - s*bn[2*O+o];
}

// transposed float4-chunk layout: dst[(c/4)*256 + o*4 + c%4], O=64 fixed
__global__ void k_build_T4(const float* __restrict__ W, int ldw, const float* __restrict__ bn,
                           float* __restrict__ dst, float* __restrict__ bias,
                           int c0, int diffoff, int Csrc){
  int o = threadIdx.x, c = blockIdx.x;
  float s = bn[o] / sqrtf(bn[192+o] + 1e-5f);
  float val = 0.f;
  if (c < Csrc){
    val = W[o*ldw + c0 + c];
    if (diffoff) val = W[o*ldw + c0 + diffoff + c] - val;
    val *= s;
  }
  dst[(c>>2)*256 + o*4 + (c&3)] = val;
  if (bias != nullptr && c==0) bias[o] = bn[64+o] - s*bn[128+o];
}

// U1[b][k][o] = sum_{c<6} s_o*W1[o][c]*x[b][c][k]  (first-KNN neighbors are points 0..19)
__global__ void k_build_U1(const float* __restrict__ x, const float* __restrict__ W1,
                           const float* __restrict__ bn, float* __restrict__ U1){
  int o = threadIdx.x, k = blockIdx.x, b = blockIdx.y;
  float s = bn[o] / sqrtf(bn[192+o] + 1e-5f);
  float acc = 0.f;
  #pragma unroll
  for (int c=0;c<6;c++) acc += W1[o*12+c] * x[(b*6+c)*N_PTS + k];
  U1[(b*KNB+k)*64 + o] = acc*s;
}

__global__ void k_init_g(unsigned* g){ g[blockIdx.x*256+threadIdx.x] = fenc(-INFINITY); }

// ---- edge block 1 (trivial neighbors 0..19) : conv1 + conv2 + maxpool ----
__global__ __launch_bounds__(256) void k_edge1(const float* __restrict__ x, const float* __restrict__ U1,
                        const float* __restrict__ W1dT4, const float* __restrict__ bf1,
                        const float* __restrict__ W2T4, const float* __restrict__ bf2,
                        float* __restrict__ x1t, float* __restrict__ Xcat, float* __restrict__ xx1){
  __shared__ float hb[4][KNB][64];
  int wid = threadIdx.x>>6, lane = threadIdx.x&63;
  int pt = blockIdx.x*4 + wid, b = pt>>12, n = pt&4095;
  float xv[8];
  #pragma unroll
  for (int c=0;c<6;c++) xv[c] = x[(b*6+c)*N_PTS + n];
  xv[6]=0.f; xv[7]=0.f;
  float w = bf1[lane];
  #pragma unroll
  for (int cb=0;cb<2;cb++){
    float4 wv = ((const float4*)W1dT4)[cb*64+lane];
    w = fmaf(wv.x, xv[cb*4+0], w); w = fmaf(wv.y, xv[cb*4+1], w);
    w = fmaf(wv.z, xv[cb*4+2], w); w = fmaf(wv.w, xv[cb*4+3], w);
  }
  const float* Ub = U1 + b*KNB*64;
  #pragma unroll
  for (int k=0;k<KNB;k++) hb[wid][k][lane] = lrelu(Ub[k*64+lane] + w);
  __syncthreads();
  float acc[KNB];
  #pragma unroll
  for (int k=0;k<KNB;k++) acc[k] = bf2[lane];
  for (int cb=0;cb<16;cb++){
    float4 wv = ((const float4*)W2T4)[cb*64+lane];
    #pragma unroll
    for (int k=0;k<KNB;k++){
      float4 a = *(const float4*)&hb[wid][k][cb*4];
      acc[k]=fmaf(wv.x,a.x,acc[k]); acc[k]=fmaf(wv.y,a.y,acc[k]);
      acc[k]=fmaf(wv.z,a.z,acc[k]); acc[k]=fmaf(wv.w,a.w,acc[k]);
    }
  }
  float mx = -INFINITY;
  #pragma unroll
  for (int k=0;k<KNB;k++) mx = fmaxf(mx, acc[k]);
  mx = lrelu(mx);
  x1t[(size_t)pt*64 + lane] = mx;
  Xcat[((size_t)b*192 + 0 + lane)*N_PTS + n] = mx;
  float sq = mx*mx;
  #pragma unroll
  for (int off=32; off; off>>=1) sq += __shfl_xor(sq, off);
  if (lane==0) xx1[pt] = sq;
}

// ---- U/V precompute: Ut[n][o] = s*(WL@x_n); Vt[n][o] = s*((WR-WL)@x_n) + bias ----
__global__ __launch_bounds__(256) void k_uv(const float* __restrict__ xt, const float* __restrict__ WL,
    const float* __restrict__ WRd, const float* __restrict__ bf,
    float* __restrict__ Ut, float* __restrict__ Vt){
  __shared__ float xs[4][64];
  int wid = threadIdx.x>>6, lane = threadIdx.x&63;
  int pt = blockIdx.x*4 + wid;
  xs[wid][lane] = xt[(size_t)pt*64 + lane];
  __syncthreads();
  float U = 0.f, V = bf[lane];
  #pragma unroll
  for (int cb=0;cb<16;cb++){
    float4 wl = ((const float4*)WL)[cb*64+lane];
    float4 wr = ((const float4*)WRd)[cb*64+lane];
    float4 xv = *(const float4*)&xs[wid][cb*4];
    U=fmaf(wl.x,xv.x,U); U=fmaf(wl.y,xv.y,U); U=fmaf(wl.z,xv.z,U); U=fmaf(wl.w,xv.w,U);
    V=fmaf(wr.x,xv.x,V); V=fmaf(wr.y,xv.y,V); V=fmaf(wr.z,xv.z,V); V=fmaf(wr.w,xv.w,V);
  }
  Ut[(size_t)pt*64 + lane] = U;
  Vt[(size_t)pt*64 + lane] = V;
}

// ---- edge block 2: h = lrelu(U3[m_k]+V3[n]) (gather), then conv4 + max ----
__global__ __launch_bounds__(256) void k_ec2(const float* __restrict__ Ut, const float* __restrict__ Vt,
    const int* __restrict__ idx, const float* __restrict__ W2T4, const float* __restrict__ bfb,
    float* __restrict__ xout, float* __restrict__ Xcat, float* __restrict__ xxout){
  __shared__ float H[4][KNB][64];
  int wid = threadIdx.x>>6, lane = threadIdx.x&63;
  int pt = blockIdx.x*4 + wid, b = pt>>12, n = pt&4095;
  const float* Ub = Ut + (((size_t)b)<<12)*64;
  float Vv = Vt[(size_t)pt*64 + lane];
  int mr[KNB];
  const int4* ip4 = (const int4*)(idx + (size_t)pt*KNB);
  #pragma unroll
  for (int q=0;q<5;q++){ int4 t = ip4[q]; mr[q*4+0]=t.x; mr[q*4+1]=t.y; mr[q*4+2]=t.z; mr[q*4+3]=t.w; }
  #pragma unroll
  for (int k=0;k<KNB;k++) H[wid][k][lane] = lrelu(Ub[(size_t)mr[k]*64 + lane] + Vv);
  __syncthreads();
  float acc[KNB];
  #pragma unroll
  for (int k=0;k<KNB;k++) acc[k] = bfb[lane];
  for (int cb=0;cb<16;cb++){
    float4 wv = ((const float4*)W2T4)[cb*64+lane];
    #pragma unroll
    for (int k=0;k<KNB;k++){
      float4 a = *(const float4*)&H[wid][k][cb*4];
      acc[k]=fmaf(wv.x,a.x,acc[k]); acc[k]=fmaf(wv.y,a.y,acc[k]);
      acc[k]=fmaf(wv.z,a.z,acc[k]); acc[k]=fmaf(wv.w,a.w,acc[k]);
    }
  }
  float mx = -INFINITY;
  #pragma unroll
  for (int k=0;k<KNB;k++) mx = fmaxf(mx, acc[k]);
  mx = lrelu(mx);
  xout[(size_t)pt*64 + lane] = mx;
  Xcat[((size_t)b*192 + 64 + lane)*N_PTS + n] = mx;
  float sq = mx*mx;
  #pragma unroll
  for (int off=32;off;off>>=1) sq += __shfl_xor(sq,off);
  if (lane==0) xxout[pt] = sq;
}

// ---- edge block 3: x3[n] = lrelu(V5[n] + max_k U5[m_k]) -- pure gather+max ----
__global__ __launch_bounds__(256) void k_ec3(const float* __restrict__ Ut, const float* __restrict__ Vt,
    const int* __restrict__ idx, float* __restrict__ Xcat){
  int wid = threadIdx.x>>6, lane = threadIdx.x&63;
  int pt = blockIdx.x*4 + wid, b = pt>>12, n = pt&4095;
  const float* Ub = Ut + (((size_t)b)<<12)*64;
  int mr[KNB];
  const int4* ip4 = (const int4*)(idx + (size_t)pt*KNB);
  #pragma unroll
  for (int q=0;q<5;q++){ int4 t = ip4[q]; mr[q*4+0]=t.x; mr[q*4+1]=t.y; mr[q*4+2]=t.z; mr[q*4+3]=t.w; }
  float mx = -INFINITY;
  #pragma unroll
  for (int k=0;k<KNB;k++) mx = fmaxf(mx, Ub[(size_t)mr[k]*64 + lane]);
  mx = lrelu(mx + Vt[(size_t)pt*64 + lane]);
  Xcat[((size_t)b*192 + 128 + lane)*N_PTS + n] = mx;
}

// ---- KNN pairwise kernel: pd = fma(2,dot,-xx_n) - xx_m, 128x128 tile, K chunked by 32 ----
__global__ __launch_bounds__(256) void k_knn_gemm(const float* __restrict__ xt, const float* __restrict__ xx,
                          float* __restrict__ pd, int q0, int S){
  __shared__ float As[32][132];
  __shared__ float Bs[32][132];
  int tid = threadIdx.x;
  int bx = blockIdx.x, by = blockIdx.y, b = blockIdx.z;
  const float* xb = xt + (size_t)b*N_PTS*64;
  int u = tid&15, v = tid>>4;
  float acc[8][8];
  #pragma unroll
  for (int i=0;i<8;i++)
    #pragma unroll
    for (int j=0;j<8;j++) acc[i][j]=0.f;
  for (int kc=0;kc<2;kc++){
    #pragma unroll
    for (int p=0;p<4;p++){
      int row = (tid>>3) + p*32, c8 = tid&7;
      float4 av = *(const float4*)&xb[(size_t)(q0 + by*128 + row)*64 + kc*32 + c8*4];
      As[c8*4+0][row]=av.x; As[c8*4+1][row]=av.y; As[c8*4+2][row]=av.z; As[c8*4+3][row]=av.w;
      float4 bv = *(const float4*)&xb[(size_t)(bx*128 + row)*64 + kc*32 + c8*4];
      Bs[c8*4+0][row]=bv.x; Bs[c8*4+1][row]=bv.y; Bs[c8*4+2][row]=bv.z; Bs[c8*4+3][row]=bv.w;
    }
    __syncthreads();
    #pragma unroll 4
    for (int k=0;k<32;k++){
      float4 a0 = *(const float4*)&As[k][u*4];
      float4 a1 = *(const float4*)&As[k][64+u*4];
      float4 b0 = *(const float4*)&Bs[k][v*4];
      float4 b1 = *(const float4*)&Bs[k][64+v*4];
      float a[8] = {a0.x,a0.y,a0.z,a0.w,a1.x,a1.y,a1.z,a1.w};
      float bb[8] = {b0.x,b0.y,b0.z,b0.w,b1.x,b1.y,b1.z,b1.w};
      #pragma unroll
      for (int i=0;i<8;i++)
        #pragma unroll
        for (int j=0;j<8;j++)
          acc[i][j] = fmaf(a[i], bb[j], acc[i][j]);
    }
    __syncthreads();
  }
  float xn[8], xm[8];
  #pragma unroll
  for (int i=0;i<8;i++){
    int ri = (i<4)? u*4+i : 64+u*4+(i-4);
    xn[i] = xx[b*N_PTS + q0 + by*128 + ri];
  }
  #pragma unroll
  for (int j=0;j<8;j++){
    int cj = (j<4)? v*4+j : 64+v*4+(j-4);
    xm[j] = xx[b*N_PTS + bx*128 + cj];
  }
  #pragma unroll
  for (int i=0;i<8;i++){
    int ri = (i<4)? u*4+i : 64+u*4+(i-4);
    float* dst = pd + ((size_t)(b*S + by*128 + ri))*N_PTS + bx*128;
    float4 s0, s1;
    s0.x = fmaf(2.f,acc[i][0],-xn[i]) - xm[0];
    s0.y = fmaf(2.f,acc[i][1],-xn[i]) - xm[1];
    s0.z = fmaf(2.f,acc[i][2],-xn[i]) - xm[2];
    s0.w = fmaf(2.f,acc[i][3],-xn[i]) - xm[3];
    s1.x = fmaf(2.f,acc[i][4],-xn[i]) - xm[4];
    s1.y = fmaf(2.f,acc[i][5],-xn[i]) - xm[5];
    s1.z = fmaf(2.f,acc[i][6],-xn[i]) - xm[6];
    s1.w = fmaf(2.f,acc[i][7],-xn[i]) - xm[7];
    *(float4*)&dst[v*4] = s0;
    *(float4*)&dst[64+v*4] = s1;
  }
}

// ---- top-20 via ballot-bisection; exact jax set {key >= K20}, key=(val desc, idx asc) ----
__global__ __launch_bounds__(256) void k_topk20(const float* __restrict__ pdbuf, int* __restrict__ idxout,
                                                int q0, int sshift){
  __shared__ unsigned long long cand[4][64];
  int wid = threadIdx.x>>6, lane = threadIdx.x&63;
  int gw = blockIdx.x*4 + wid;
  int S = 1 << sshift;
  int b = gw >> sshift, i = gw & (S-1);
  const float* row = pdbuf + ((size_t)b*S + i)*N_PTS;
  int lane4 = lane*4;
  unsigned ve[64];
  #pragma unroll
  for (int t4=0;t4<16;t4++){
    float4 f = *(const float4*)&row[t4*256 + lane4];
    unsigned u;
    u=__float_as_uint(f.x); ve[t4*4+0] = u ^ ((unsigned)(((int)u)>>31) | 0x80000000u);
    u=__float_as_uint(f.y); ve[t4*4+1] = u ^ ((unsigned)(((int)u)>>31) | 0x80000000u);
    u=__float_as_uint(f.z); ve[t4*4+2] = u ^ ((unsigned)(((int)u)>>31) | 0x80000000u);
    u=__float_as_uint(f.w); ve[t4*4+3] = u ^ ((unsigned)(((int)u)>>31) | 0x80000000u);
  }
  unsigned tm[32];
  #pragma unroll
  for (int t=0;t<32;t++) tm[t] = ve[t] > ve[t+32] ? ve[t] : ve[t+32];
  #pragma unroll
  for (int t=0;t<16;t++) tm[t] = tm[t] > tm[t+16] ? tm[t] : tm[t+16];
  #pragma unroll
  for (int t=0;t<8;t++)  tm[t] = tm[t] > tm[t+8]  ? tm[t] : tm[t+8];
  #pragma unroll
  for (int t=0;t<4;t++)  tm[t] = tm[t] > tm[t+4]  ? tm[t] : tm[t+4];
  tm[0] = tm[0] > tm[2] ? tm[0] : tm[2];
  tm[1] = tm[1] > tm[3] ? tm[1] : tm[3];
  unsigned lmax = tm[0] > tm[1] ? tm[0] : tm[1];
  unsigned T = 0u;
  #pragma unroll
  for (int bb=31; bb>=0; --bb){
    unsigned cnd = T | (1u<<bb);
    int c = __popcll(__ballot(lmax >= cnd));
    if (c >= KNB) T = cnd;
  }
  unsigned long long msk = 0ull;
  #pragma unroll
  for (int t=0;t<64;t++){
    if (ve[t] >= T) msk |= (1ull<<t);
  }
  int cnt = __popcll(msk);
  int incl = cnt;
  #pragma unroll
  for (int off=1; off<64; off<<=1){ int vv = __shfl_up(incl, off); if (lane>=off) incl += vv; }
  int base = incl - cnt;
  int C = __shfl(incl, 63);
  unsigned long long K = 0ull;
  if (C <= 64){
    int p = base;
    #pragma unroll
    for (int t=0;t<64;t++){
      if ((msk>>t)&1ull){
        int m = ((t>>2)<<8) + lane4 + (t&3);
        cand[wid][p] = (((unsigned long long)ve[t])<<12) | (unsigned)(4095-m);
        p++;
      }
    }
    __threadfence_block();
    unsigned long long mykey = cand[wid][lane];
    bool valid = lane < C;
    #pragma unroll
    for (int bb=43; bb>=0; --bb){
      unsigned long long cnd = K | (1ull<<bb);
      int c = __popcll(__ballot(valid && mykey >= cnd));
      if (c >= KNB) K = cnd;
    }
  } else {
    for (int bb=43; bb>=0; --bb){
      unsigned long long cnd = K | (1ull<<bb);
      int lc = 0;
      #pragma unroll
      for (int t=0;t<64;t++){
        if ((msk>>t)&1ull){
          int m = ((t>>2)<<8) + lane4 + (t&3);
          unsigned long long key = (((unsigned long long)ve[t])<<12) | (unsigned)(4095-m);
          if (key >= cnd) lc++;
        }
      }
      #pragma unroll
      for (int off=32; off; off>>=1) lc += __shfl_xor(lc, off);
      if (lc >= KNB) K = cnd;
    }
  }
  unsigned long long msel = 0ull;
  #pragma unroll
  for (int t=0;t<64;t++){
    if ((msk>>t)&1ull){
      int m = ((t>>2)<<8) + lane4 + (t&3);
      unsigned long long key = (((unsigned long long)ve[t])<<12) | (unsigned)(4095-m);
      if (key >= K) msel |= (1ull<<t);
    }
  }
  int ce = __popcll(msel);
  int incl2 = ce;
  #pragma unroll
  for (int off=1; off<64; off<<=1){ int vv = __shfl_up(incl2, off); if (lane>=off) incl2 += vv; }
  int p2 = incl2 - ce;
  int* dst = idxout + ((size_t)b*N_PTS + (q0+i))*KNB;
  #pragma unroll
  for (int t=0;t<64;t++){
    if ((msel>>t)&1ull){
      dst[p2] = ((t>>2)<<8) + lane4 + (t&3);
      p2++;
    }
  }
}

// ---- generic fp32 GEMM: C[b][o][n] = act(A(OxK) @ B[b](KxN) + bias), optional col-max atomic ----
// flags: 1=leakyrelu, 2=store C, 4=bias per batch
__global__ __launch_bounds__(256) void k_gemm(const float* __restrict__ A, int lda,
        const float* __restrict__ B, const float* __restrict__ bias,
        float* __restrict__ C, unsigned* __restrict__ gmax,
        int O, int K, int flags){
  __shared__ float As[32][132];
  __shared__ float Bs[32][132];
  int tid = threadIdx.x, bx = blockIdx.x, by = blockIdx.y, b = blockIdx.z;
  int u = tid&15, v = tid>>4;
  float acc[8][8];
  #pragma unroll
  for (int i=0;i<8;i++)
    #pragma unroll
    for (int j=0;j<8;j++) acc[i][j]=0.f;
  const float* Bb = B + (size_t)b*K*N_PTS;
  for (int kt=0; kt<K; kt+=32){
    #pragma unroll
    for (int p=0;p<4;p++){
      int row = (tid>>3) + p*32, c8 = tid&7;
      int ga = by*128 + row;
      float4 av = (ga < O) ? *(const float4*)&A[(size_t)ga*lda + kt + c8*4] : make_float4(0.f,0.f,0.f,0.f);
      As[c8*4+0][row]=av.x; As[c8*4+1][row]=av.y; As[c8*4+2][row]=av.z; As[c8*4+3][row]=av.w;
      int kk = p*8 + (tid>>5), n4 = tid&31;
      float4 bv = *(const float4*)&Bb[(size_t)(kt+kk)*N_PTS + bx*128 + n4*4];
      *(float4*)&Bs[kk][n4*4] = bv;
    }
    __syncthreads();
    #pragma unroll 4
    for (int k=0;k<32;k++){
      float4 a0 = *(const float4*)&As[k][u*4];
      float4 a1 = *(const float4*)&As[k][64+u*4];
      float4 b0 = *(const float4*)&Bs[k][v*4];
      float4 b1 = *(const float4*)&Bs[k][64+v*4];
      float a[8] = {a0.x,a0.y,a0.z,a0.w,a1.x,a1.y,a1.z,a1.w};
      float bb[8] = {b0.x,b0.y,b0.z,b0.w,b1.x,b1.y,b1.z,b1.w};
      #pragma unroll
      for (int i=0;i<8;i++)
        #pragma unroll
        for (int j=0;j<8;j++)
          acc[i][j] = fmaf(a[i], bb[j], acc[i][j]);
    }
    __syncthreads();
  }
  bool relu = flags&1, store = flags&2, pbb = flags&4;
  float rowm[8];
  #pragma unroll
  for (int i=0;i<8;i++){
    int rl = (i<4)? u*4+i : 64+u*4+(i-4);
    int ri = by*128 + rl;
    float bvv = (bias != nullptr && ri < O) ? (pbb ? bias[b*O+ri] : bias[ri]) : 0.f;
    float vals[8];
    #pragma unroll
    for (int j=0;j<8;j++){
      float y = acc[i][j] + bvv;
      if (relu) y = lrelu(y);
      vals[j]=y;
    }
    if (store && ri < O){
      float* dst = C + ((size_t)b*O+ri)*N_PTS + bx*128;
      *(float4*)&dst[v*4] = make_float4(vals[0],vals[1],vals[2],vals[3]);
      *(float4*)&dst[64+v*4] = make_float4(vals[4],vals[5],vals[6],vals[7]);
    }
    float m = vals[0];
    #pragma unroll
    for (int j=1;j<8;j++) m = fmaxf(m, vals[j]);
    rowm[i] = m;
  }
  if (gmax != nullptr){
    float* red = &Bs[0][0];   // reuse as [128][16]
    #pragma unroll
    for (int i=0;i<8;i++){
      int rl = (i<4)? u*4+i : 64+u*4+(i-4);
      red[rl*16 + v] = rowm[i];
    }
    __syncthreads();
    if (tid < 128){
      float m = red[tid*16];
      #pragma unroll
      for (int j=1;j<16;j++) m = fmaxf(m, red[tid*16+j]);
      atomicMax(&gmax[b*1024 + by*128 + tid], fenc(m));
    }
  }
}

// bias7[b][o] = sum_{c<1024} Wf7[o][c]*g[b][c] + bf7[o]
__global__ __launch_bounds__(256) void k_gemv7(const float* __restrict__ Wf7, const float* __restrict__ bf7,
                        const unsigned* __restrict__ g, float* __restrict__ bias7){
  int wid = threadIdx.x>>6, lane = threadIdx.x&63;
  int o = blockIdx.x*4 + wid, b = blockIdx.y;
  const float* wr = Wf7 + (size_t)o*1216;
  const unsigned* gb = g + b*1024;
  float acc = 0.f;
  for (int c = lane; c < 1024; c += 64)
    acc = fmaf(wr[c], fdec(gb[c]), acc);
  #pragma unroll
  for (int off=32; off; off>>=1) acc += __shfl_xor(acc, off);
  if (lane==0) bias7[b*512+o] = acc + bf7[o];
}

extern "C" void kernel_launch(void* const* d_in, const int* in_sizes, int n_in,
                              void* d_out, int out_size, void* d_ws, size_t ws_size,
                              hipStream_t stream){
  const float* x  = (const float*)d_in[0];
  const float* W1 = (const float*)d_in[1];
  const float* W2 = (const float*)d_in[2];
  const float* W3 = (const float*)d_in[3];
  const float* W4 = (const float*)d_in[4];
  const float* W5 = (const float*)d_in[5];
  const float* W6 = (const float*)d_in[6];
  const float* W7 = (const float*)d_in[7];
  const float* W8 = (const float*)d_in[8];
  const float* W9 = (const float*)d_in[9];
  const float* bn1 = (const float*)d_in[10];
  const float* bn2 = (const float*)d_in[11];
  const float* bn3 = (const float*)d_in[12];
  const float* bn4 = (const float*)d_in[13];
  const float* bn5 = (const float*)d_in[14];
  const float* bn6 = (const float*)d_in[15];
  const float* bn7 = (const float*)d_in[16];
  const float* bn8 = (const float*)d_in[17];

  float* ws = (float*)d_ws;
  size_t off = 0;
  auto alloc = [&](size_t nf){ float* p = ws + off; off += (nf + 63) & ~(size_t)63; return p; };
  float* Wf6 = alloc(1024*192);   float* bf6 = alloc(1024);
  float* Wf7 = alloc((size_t)512*1216); float* bf7 = alloc(512);
  float* Wf8 = alloc(256*512);    float* bf8 = alloc(256);
  float* W1dT4 = alloc(8*64);     float* bf1 = alloc(64);
  float* W2T4  = alloc(64*64);    float* bf2 = alloc(64);
  float* W3LT4 = alloc(64*64);    float* W3RdT4 = alloc(64*64); float* bf3 = alloc(64);
  float* W4T4  = alloc(64*64);    float* bf4 = alloc(64);
  float* W5LT4 = alloc(64*64);    float* W5RdT4 = alloc(64*64); float* bf5 = alloc(64);
  float* U1  = alloc(4*KNB*64);
  float* x1t = alloc((size_t)4*N_PTS*64);
  float* x2t = alloc((size_t)4*N_PTS*64);
  float* Ut3 = alloc((size_t)4*N_PTS*64);
  float* Vt3 = alloc((size_t)4*N_PTS*64);
  float* Ut5 = alloc((size_t)4*N_PTS*64);
  float* Vt5 = alloc((size_t)4*N_PTS*64);
  float* Xcat = alloc((size_t)4*192*N_PTS);
  float* xx1 = alloc(4*N_PTS);
  float* xx2 = alloc(4*N_PTS);
  int* idx1 = (int*)alloc((size_t)4*N_PTS*KNB);
  int* idx2 = (int*)alloc((size_t)4*N_PTS*KNB);
  unsigned* genc = (unsigned*)alloc(4*1024);
  float* bias7 = alloc(4*512);
  float* h8 = alloc((size_t)4*256*N_PTS);
  // pdbuf takes the remainder; pick largest power-of-two stripe S (<=4096, >=512) that fits
  size_t remaining = (ws_size / 4 > off) ? (ws_size / 4 - off) : 0;
  int S = 4096;
  while (S > 512 && (size_t)4*S*N_PTS + 1024 > remaining) S >>= 1;
  int sshift = 31 - __builtin_clz(S);
  float* pdbuf = alloc((size_t)4*S*N_PTS);   // also reused as h7 (needs 32 MB <= pdbuf)
  float* h7 = pdbuf;

  // prep (every call: deterministic)
  k_scale_rows<<<(1024*192+255)/256,256,0,stream>>>(W6, bn6, Wf6, bf6, 1024, 192);
  k_scale_rows<<<(512*1216+255)/256,256,0,stream>>>(W7, bn7, Wf7, bf7, 512, 1216);
  k_scale_rows<<<(256*512+255)/256,256,0,stream>>>(W8, bn8, Wf8, bf8, 256, 512);
  k_build_T4<<<8,64,0,stream>>>(W1, 12, bn1, W1dT4, bf1, 0, 6, 6);     // (W1R - W1L), pad to 8
  k_build_T4<<<64,64,0,stream>>>(W2, 64, bn2, W2T4, bf2, 0, 0, 64);
  k_build_T4<<<64,64,0,stream>>>(W3, 128, bn3, W3LT4, bf3, 0, 0, 64);
  k_build_T4<<<64,64,0,stream>>>(W3, 128, bn3, W3RdT4, nullptr, 0, 64, 64);  // (W3R-W3L)*s
  k_build_T4<<<64,64,0,stream>>>(W4, 64, bn4, W4T4, bf4, 0, 0, 64);
  k_build_T4<<<64,64,0,stream>>>(W5, 128, bn5, W5LT4, bf5, 0, 0, 64);
  k_build_T4<<<64,64,0,stream>>>(W5, 128, bn5, W5RdT4, nullptr, 0, 64, 64);  // (W5R-W5L)*s
  k_build_U1<<<dim3(KNB,4),64,0,stream>>>(x, W1, bn1, U1);
  k_init_g<<<16,256,0,stream>>>(genc);

  // edge block 1 (neighbors = points 0..19 since KNN input is empty slice)
  k_edge1<<<4096,256,0,stream>>>(x, U1, W1dT4, bf1, W2T4, bf2, x1t, Xcat, xx1);

  int nstripe = N_PTS / S;
  // KNN on x1
  for (int s=0;s<nstripe;s++){
    k_knn_gemm<<<dim3(32,S/128,4),256,0,stream>>>(x1t, xx1, pdbuf, s*S, S);
    k_topk20<<<S,256,0,stream>>>(pdbuf, idx1, s*S, sshift);
  }

  // edge block 2: U3/V3 then gather+conv4
  k_uv<<<4096,256,0,stream>>>(x1t, W3LT4, W3RdT4, bf3, Ut3, Vt3);
  k_ec2<<<4096,256,0,stream>>>(Ut3, Vt3, idx1, W4T4, bf4, x2t, Xcat, xx2);

  // KNN on x2
  for (int s=0;s<nstripe;s++){
    k_knn_gemm<<<dim3(32,S/128,4),256,0,stream>>>(x2t, xx2, pdbuf, s*S, S);
    k_topk20<<<S,256,0,stream>>>(pdbuf, idx2, s*S, sshift);
  }

  // edge block 3: U5/V5 then pure gather+max
  k_uv<<<4096,256,0,stream>>>(x2t, W5LT4, W5RdT4, bf5, Ut5, Vt5);
  k_ec3<<<4096,256,0,stream>>>(Ut5, Vt5, idx2, Xcat);

  // conv6 (1024x192) -> only column max g (atomic, no store)
  k_gemm<<<dim3(32,8,4),256,0,stream>>>(Wf6, 192, Xcat, bf6, nullptr, genc, 1024, 192, 1);
  // bias7[b][o] = W7[:, :1024] @ g + bf7
  k_gemv7<<<dim3(128,4),256,0,stream>>>(Wf7, bf7, genc, bias7);
  // conv7: W7[:, 1024:1216] @ Xcat + bias7 (per batch)
  k_gemm<<<dim3(32,4,4),256,0,stream>>>(Wf7+1024, 1216, Xcat, bias7, h7, nullptr, 512, 192, 1|2|4);
  // conv8: 256x512
  k_gemm<<<dim3(32,2,4),256,0,stream>>>(Wf8, 512, h7, bf8, h8, nullptr, 256, 512, 1|2);
  // conv9: 13x256, no bias/relu -> d_out
  k_gemm<<<dim3(32,1,4),256,0,stream>>>(W9, 256, h8, nullptr, (float*)d_out, nullptr, 13, 256, 2);
}

// Round 6
// 943.577 us; speedup vs baseline: 1.3459x; 1.0720x over previous
//
#include <hip/hip_runtime.h>
#include <math.h>

#define N_PTS 4096
#define BATCH 4
#define KNB 20

__device__ __forceinline__ float lrelu(float v){ return fmaxf(v, 0.2f*v); }
__device__ __forceinline__ unsigned fenc(float f){ unsigned u=__float_as_uint(f); return (u&0x80000000u)?~u:(u|0x80000000u); }
__device__ __forceinline__ float fdec(unsigned k){ return (k&0x80000000u)?__uint_as_float(k&0x7fffffffu):__uint_as_float(~k); }

// ---- prep: fold BN scale into weights ----
__global__ void k_scale_rows(const float* __restrict__ W, const float* __restrict__ bn,
                             float* __restrict__ Wf, float* __restrict__ bias, int O, int C){
  int i = blockIdx.x*256 + threadIdx.x;
  if (i >= O*C) return;
  int o = i / C;
  float s = bn[o] / sqrtf(bn[3*O+o] + 1e-5f);
  Wf[i] = W[i]*s;
  if (i % C == 0) bias[o] = bn[O+o] - s*bn[2*O+o];
}

// transposed float4-chunk layout: dst[(c/4)*256 + o*4 + c%4], O=64 fixed
__global__ void k_build_T4(const float* __restrict__ W, int ldw, const float* __restrict__ bn,
                           float* __restrict__ dst, float* __restrict__ bias,
                           int c0, int diffoff, int Csrc){
  int o = threadIdx.x, c = blockIdx.x;
  float s = bn[o] / sqrtf(bn[192+o] + 1e-5f);
  float val = 0.f;
  if (c < Csrc){
    val = W[o*ldw + c0 + c];
    if (diffoff) val = W[o*ldw + c0 + diffoff + c] - val;
    val *= s;
  }
  dst[(c>>2)*256 + o*4 + (c&3)] = val;
  if (bias != nullptr && c==0) bias[o] = bn[64+o] - s*bn[128+o];
}

// U1[b][k][o] = sum_{c<6} s_o*W1[o][c]*x[b][c][k]  (first-KNN neighbors are points 0..19)
__global__ void k_build_U1(const float* __restrict__ x, const float* __restrict__ W1,
                           const float* __restrict__ bn, float* __restrict__ U1){
  int o = threadIdx.x, k = blockIdx.x, b = blockIdx.y;
  float s = bn[o] / sqrtf(bn[192+o] + 1e-5f);
  float acc = 0.f;
  #pragma unroll
  for (int c=0;c<6;c++) acc += W1[o*12+c] * x[(b*6+c)*N_PTS + k];
  U1[(b*KNB+k)*64 + o] = acc*s;
}

__global__ void k_init_g(unsigned* g){ g[blockIdx.x*256+threadIdx.x] = fenc(-INFINITY); }

// ---- edge block 1 (trivial neighbors 0..19) : conv1 + conv2 + maxpool ----
__global__ __launch_bounds__(256) void k_edge1(const float* __restrict__ x, const float* __restrict__ U1,
                        const float* __restrict__ W1dT4, const float* __restrict__ bf1,
                        const float* __restrict__ W2T4, const float* __restrict__ bf2,
                        float* __restrict__ x1t, float* __restrict__ Xcat, float* __restrict__ xx1){
  __shared__ float hb[4][KNB][64];
  int wid = threadIdx.x>>6, lane = threadIdx.x&63;
  int pt = blockIdx.x*4 + wid, b = pt>>12, n = pt&4095;
  float xv[8];
  #pragma unroll
  for (int c=0;c<6;c++) xv[c] = x[(b*6+c)*N_PTS + n];
  xv[6]=0.f; xv[7]=0.f;
  float w = bf1[lane];
  #pragma unroll
  for (int cb=0;cb<2;cb++){
    float4 wv = ((const float4*)W1dT4)[cb*64+lane];
    w = fmaf(wv.x, xv[cb*4+0], w); w = fmaf(wv.y, xv[cb*4+1], w);
    w = fmaf(wv.z, xv[cb*4+2], w); w = fmaf(wv.w, xv[cb*4+3], w);
  }
  const float* Ub = U1 + b*KNB*64;
  #pragma unroll
  for (int k=0;k<KNB;k++) hb[wid][k][lane] = lrelu(Ub[k*64+lane] + w);
  __syncthreads();
  float acc[KNB];
  #pragma unroll
  for (int k=0;k<KNB;k++) acc[k] = bf2[lane];
  for (int cb=0;cb<16;cb++){
    float4 wv = ((const float4*)W2T4)[cb*64+lane];
    #pragma unroll
    for (int k=0;k<KNB;k++){
      float4 a = *(const float4*)&hb[wid][k][cb*4];
      acc[k]=fmaf(wv.x,a.x,acc[k]); acc[k]=fmaf(wv.y,a.y,acc[k]);
      acc[k]=fmaf(wv.z,a.z,acc[k]); acc[k]=fmaf(wv.w,a.w,acc[k]);
    }
  }
  float mx = -INFINITY;
  #pragma unroll
  for (int k=0;k<KNB;k++) mx = fmaxf(mx, acc[k]);
  mx = lrelu(mx);
  x1t[(size_t)pt*64 + lane] = mx;
  Xcat[((size_t)b*192 + 0 + lane)*N_PTS + n] = mx;
  float sq = mx*mx;
  #pragma unroll
  for (int off=32; off; off>>=1) sq += __shfl_xor(sq, off);
  if (lane==0) xx1[pt] = sq;
}

// ---- U/V precompute: Ut[n][o] = s*(WL@x_n); Vt[n][o] = s*((WR-WL)@x_n) + bias ----
__global__ __launch_bounds__(256) void k_uv(const float* __restrict__ xt, const float* __restrict__ WL,
    const float* __restrict__ WRd, const float* __restrict__ bf,
    float* __restrict__ Ut, float* __restrict__ Vt){
  __shared__ float xs[4][64];
  int wid = threadIdx.x>>6, lane = threadIdx.x&63;
  int pt = blockIdx.x*4 + wid;
  xs[wid][lane] = xt[(size_t)pt*64 + lane];
  __syncthreads();
  float U = 0.f, V = bf[lane];
  #pragma unroll
  for (int cb=0;cb<16;cb++){
    float4 wl = ((const float4*)WL)[cb*64+lane];
    float4 wr = ((const float4*)WRd)[cb*64+lane];
    float4 xv = *(const float4*)&xs[wid][cb*4];
    U=fmaf(wl.x,xv.x,U); U=fmaf(wl.y,xv.y,U); U=fmaf(wl.z,xv.z,U); U=fmaf(wl.w,xv.w,U);
    V=fmaf(wr.x,xv.x,V); V=fmaf(wr.y,xv.y,V); V=fmaf(wr.z,xv.z,V); V=fmaf(wr.w,xv.w,V);
  }
  Ut[(size_t)pt*64 + lane] = U;
  Vt[(size_t)pt*64 + lane] = V;
}

// ---- edge block 2: h = lrelu(U3[m_k]+V3[n]) (gather), then conv4 + max ----
__global__ __launch_bounds__(256) void k_ec2(const float* __restrict__ Ut, const float* __restrict__ Vt,
    const int* __restrict__ idx, const float* __restrict__ W2T4, const float* __restrict__ bfb,
    float* __restrict__ xout, float* __restrict__ Xcat, float* __restrict__ xxout){
  __shared__ float H[4][KNB][64];
  int wid = threadIdx.x>>6, lane = threadIdx.x&63;
  int pt = blockIdx.x*4 + wid, b = pt>>12, n = pt&4095;
  const float* Ub = Ut + (((size_t)b)<<12)*64;
  float Vv = Vt[(size_t)pt*64 + lane];
  int mr[KNB];
  const int4* ip4 = (const int4*)(idx + (size_t)pt*KNB);
  #pragma unroll
  for (int q=0;q<5;q++){ int4 t = ip4[q]; mr[q*4+0]=t.x; mr[q*4+1]=t.y; mr[q*4+2]=t.z; mr[q*4+3]=t.w; }
  #pragma unroll
  for (int k=0;k<KNB;k++) H[wid][k][lane] = lrelu(Ub[(size_t)mr[k]*64 + lane] + Vv);
  __syncthreads();
  float acc[KNB];
  #pragma unroll
  for (int k=0;k<KNB;k++) acc[k] = bfb[lane];
  for (int cb=0;cb<16;cb++){
    float4 wv = ((const float4*)W2T4)[cb*64+lane];
    #pragma unroll
    for (int k=0;k<KNB;k++){
      float4 a = *(const float4*)&H[wid][k][cb*4];
      acc[k]=fmaf(wv.x,a.x,acc[k]); acc[k]=fmaf(wv.y,a.y,acc[k]);
      acc[k]=fmaf(wv.z,a.z,acc[k]); acc[k]=fmaf(wv.w,a.w,acc[k]);
    }
  }
  float mx = -INFINITY;
  #pragma unroll
  for (int k=0;k<KNB;k++) mx = fmaxf(mx, acc[k]);
  mx = lrelu(mx);
  xout[(size_t)pt*64 + lane] = mx;
  Xcat[((size_t)b*192 + 64 + lane)*N_PTS + n] = mx;
  float sq = mx*mx;
  #pragma unroll
  for (int off=32;off;off>>=1) sq += __shfl_xor(sq,off);
  if (lane==0) xxout[pt] = sq;
}

// ---- edge block 3: x3[n] = lrelu(V5[n] + max_k U5[m_k]) -- pure gather+max ----
__global__ __launch_bounds__(256) void k_ec3(const float* __restrict__ Ut, const float* __restrict__ Vt,
    const int* __restrict__ idx, float* __restrict__ Xcat){
  int wid = threadIdx.x>>6, lane = threadIdx.x&63;
  int pt = blockIdx.x*4 + wid, b = pt>>12, n = pt&4095;
  const float* Ub = Ut + (((size_t)b)<<12)*64;
  int mr[KNB];
  const int4* ip4 = (const int4*)(idx + (size_t)pt*KNB);
  #pragma unroll
  for (int q=0;q<5;q++){ int4 t = ip4[q]; mr[q*4+0]=t.x; mr[q*4+1]=t.y; mr[q*4+2]=t.z; mr[q*4+3]=t.w; }
  float mx = -INFINITY;
  #pragma unroll
  for (int k=0;k<KNB;k++) mx = fmaxf(mx, Ub[(size_t)mr[k]*64 + lane]);
  mx = lrelu(mx + Vt[(size_t)pt*64 + lane]);
  Xcat[((size_t)b*192 + 128 + lane)*N_PTS + n] = mx;
}

// ---- KNN pairwise kernel: pd = fma(2,dot,-xx_n) - xx_m, 128x128 tile, K chunked by 32 ----
// Writes ORDER-PRESERVING ENCODED u32 (fenc) so topk skips the encode.
__global__ __launch_bounds__(256) void k_knn_gemm(const float* __restrict__ xt, const float* __restrict__ xx,
                          unsigned* __restrict__ pd, int q0, int S){
  __shared__ float As[32][132];
  __shared__ float Bs[32][132];
  int tid = threadIdx.x;
  int bx = blockIdx.x, by = blockIdx.y, b = blockIdx.z;
  const float* xb = xt + (size_t)b*N_PTS*64;
  int u = tid&15, v = tid>>4;
  float acc[8][8];
  #pragma unroll
  for (int i=0;i<8;i++)
    #pragma unroll
    for (int j=0;j<8;j++) acc[i][j]=0.f;
  for (int kc=0;kc<2;kc++){
    #pragma unroll
    for (int p=0;p<4;p++){
      int row = (tid>>3) + p*32, c8 = tid&7;
      float4 av = *(const float4*)&xb[(size_t)(q0 + by*128 + row)*64 + kc*32 + c8*4];
      As[c8*4+0][row]=av.x; As[c8*4+1][row]=av.y; As[c8*4+2][row]=av.z; As[c8*4+3][row]=av.w;
      float4 bv = *(const float4*)&xb[(size_t)(bx*128 + row)*64 + kc*32 + c8*4];
      Bs[c8*4+0][row]=bv.x; Bs[c8*4+1][row]=bv.y; Bs[c8*4+2][row]=bv.z; Bs[c8*4+3][row]=bv.w;
    }
    __syncthreads();
    #pragma unroll 4
    for (int k=0;k<32;k++){
      float4 a0 = *(const float4*)&As[k][u*4];
      float4 a1 = *(const float4*)&As[k][64+u*4];
      float4 b0 = *(const float4*)&Bs[k][v*4];
      float4 b1 = *(const float4*)&Bs[k][64+v*4];
      float a[8] = {a0.x,a0.y,a0.z,a0.w,a1.x,a1.y,a1.z,a1.w};
      float bb[8] = {b0.x,b0.y,b0.z,b0.w,b1.x,b1.y,b1.z,b1.w};
      #pragma unroll
      for (int i=0;i<8;i++)
        #pragma unroll
        for (int j=0;j<8;j++)
          acc[i][j] = fmaf(a[i], bb[j], acc[i][j]);
    }
    __syncthreads();
  }
  float xn[8], xm[8];
  #pragma unroll
  for (int i=0;i<8;i++){
    int ri = (i<4)? u*4+i : 64+u*4+(i-4);
    xn[i] = xx[b*N_PTS + q0 + by*128 + ri];
  }
  #pragma unroll
  for (int j=0;j<8;j++){
    int cj = (j<4)? v*4+j : 64+v*4+(j-4);
    xm[j] = xx[b*N_PTS + bx*128 + cj];
  }
  #pragma unroll
  for (int i=0;i<8;i++){
    int ri = (i<4)? u*4+i : 64+u*4+(i-4);
    unsigned* dst = pd + ((size_t)(b*S + by*128 + ri))*N_PTS + bx*128;
    uint4 o0, o1;
    o0.x = fenc(fmaf(2.f,acc[i][0],-xn[i]) - xm[0]);
    o0.y = fenc(fmaf(2.f,acc[i][1],-xn[i]) - xm[1]);
    o0.z = fenc(fmaf(2.f,acc[i][2],-xn[i]) - xm[2]);
    o0.w = fenc(fmaf(2.f,acc[i][3],-xn[i]) - xm[3]);
    o1.x = fenc(fmaf(2.f,acc[i][4],-xn[i]) - xm[4]);
    o1.y = fenc(fmaf(2.f,acc[i][5],-xn[i]) - xm[5]);
    o1.z = fenc(fmaf(2.f,acc[i][6],-xn[i]) - xm[6]);
    o1.w = fenc(fmaf(2.f,acc[i][7],-xn[i]) - xm[7]);
    *(uint4*)&dst[v*4] = o0;
    *(uint4*)&dst[64+v*4] = o1;
  }
}

// ---- top-20 via cross-lane bitonic selection; exact jax set {key >= K20}, key=(val desc, idx asc) ----
// pd is pre-encoded u32. One wave per query; no SALU ballot chains in the common path.
__global__ __launch_bounds__(256,4) void k_topk20(const unsigned* __restrict__ pdbuf, int* __restrict__ idxout,
                                                  int q0, int sshift){
  __shared__ unsigned long long cand[4][64];
  int wid = threadIdx.x>>6, lane = threadIdx.x&63;
  int gw = blockIdx.x*4 + wid;
  int S = 1 << sshift;
  int b = gw >> sshift, i = gw & (S-1);
  const unsigned* row = pdbuf + ((size_t)b*S + i)*N_PTS;
  int lane4 = lane*4;
  // load 64 encoded values; value t lives at column m = (t>>2)*256 + lane*4 + (t&3)
  unsigned ve[64];
  #pragma unroll
  for (int t4=0;t4<16;t4++){
    uint4 f = *(const uint4*)&row[t4*256 + lane4];
    ve[t4*4+0]=f.x; ve[t4*4+1]=f.y; ve[t4*4+2]=f.z; ve[t4*4+3]=f.w;
  }
  // per-lane max: 8 grouped accumulators (ILP) then small tree
  unsigned g0=ve[0], g1=ve[8], g2=ve[16], g3=ve[24], g4=ve[32], g5=ve[40], g6=ve[48], g7=ve[56];
  #pragma unroll
  for (int s=1;s<8;s++){
    g0 = g0>ve[s]    ? g0 : ve[s];
    g1 = g1>ve[8+s]  ? g1 : ve[8+s];
    g2 = g2>ve[16+s] ? g2 : ve[16+s];
    g3 = g3>ve[24+s] ? g3 : ve[24+s];
    g4 = g4>ve[32+s] ? g4 : ve[32+s];
    g5 = g5>ve[40+s] ? g5 : ve[40+s];
    g6 = g6>ve[48+s] ? g6 : ve[48+s];
    g7 = g7>ve[56+s] ? g7 : ve[56+s];
  }
  g0 = g0>g1?g0:g1; g2 = g2>g3?g2:g3; g4 = g4>g5?g4:g5; g6 = g6>g7?g6:g7;
  g0 = g0>g2?g0:g2; g4 = g4>g6?g4:g6;
  unsigned lmax = g0>g4?g0:g4;
  // bitonic sort (ascending in lane) of the 64 lane-maxes; T = 20th largest = sorted[44]
  {
    unsigned v = lmax;
    #pragma unroll
    for (int k=2;k<=64;k<<=1){
      #pragma unroll
      for (int j=k>>1;j>0;j>>=1){
        unsigned o = (unsigned)__shfl_xor((int)v, j);
        bool up = ((lane & k) == 0);
        bool takeMax = (((lane & j) != 0) == up);
        unsigned mx = v>o?v:o, mn = v<o?v:o;
        v = takeMax ? mx : mn;
      }
    }
    lmax = (unsigned)__shfl((int)v, 44);
  }
  unsigned T = lmax;   // guaranteed: count(values >= T) >= 20
  // candidate mask
  unsigned long long msk = 0ull;
  #pragma unroll
  for (int t=0;t<64;t++){
    if (ve[t] >= T) msk |= (1ull<<t);
  }
  int cnt = __popcll(msk);
  int incl = cnt;
  #pragma unroll
  for (int off=1; off<64; off<<=1){ int vv = __shfl_up(incl, off); if (lane>=off) incl += vv; }
  int base = incl - cnt;
  int C = __shfl(incl, 63);
  unsigned long long K = 0ull;
  if (C <= 64){
    // compact candidate keys into LDS, one key per lane, bitonic sort u64, K = sorted[44]
    int p = base;
    #pragma unroll
    for (int t=0;t<64;t++){
      if ((msk>>t)&1ull){
        int m = ((t>>2)<<8) + lane4 + (t&3);
        cand[wid][p] = (((unsigned long long)ve[t])<<12) | (unsigned)(4095-m);
        p++;
      }
    }
    __threadfence_block();
    unsigned long long kv = (lane < C) ? cand[wid][lane] : 0ull;   // real keys > 0
    #pragma unroll
    for (int k=2;k<=64;k<<=1){
      #pragma unroll
      for (int j=k>>1;j>0;j>>=1){
        unsigned long long o = __shfl_xor(kv, j);
        bool up = ((lane & k) == 0);
        bool takeMax = (((lane & j) != 0) == up);
        unsigned long long mx = kv>o?kv:o, mn = kv<o?kv:o;
        kv = takeMax ? mx : mn;
      }
    }
    K = __shfl(kv, 44);
  } else {
    // degenerate (massive value ties): exact 44-bit bisect with per-lane masked counts
    for (int bb=43; bb>=0; --bb){
      unsigned long long cnd = K | (1ull<<bb);
      int lc = 0;
      #pragma unroll
      for (int t=0;t<64;t++){
        if ((msk>>t)&1ull){
          int m = ((t>>2)<<8) + lane4 + (t&3);
          unsigned long long key = (((unsigned long long)ve[t])<<12) | (unsigned)(4095-m);
          if (key >= cnd) lc++;
        }
      }
      #pragma unroll
      for (int off=32; off; off>>=1) lc += __shfl_xor(lc, off);
      if (lc >= KNB) K = cnd;
    }
  }
  // emission: exactly the 20 keys >= K (keys unique)
  unsigned long long msel = 0ull;
  #pragma unroll
  for (int t=0;t<64;t++){
    if ((msk>>t)&1ull){
      int m = ((t>>2)<<8) + lane4 + (t&3);
      unsigned long long key = (((unsigned long long)ve[t])<<12) | (unsigned)(4095-m);
      if (key >= K) msel |= (1ull<<t);
    }
  }
  int ce = __popcll(msel);
  int incl2 = ce;
  #pragma unroll
  for (int off=1; off<64; off<<=1){ int vv = __shfl_up(incl2, off); if (lane>=off) incl2 += vv; }
  int p2 = incl2 - ce;
  int* dst = idxout + ((size_t)b*N_PTS + (q0+i))*KNB;
  #pragma unroll
  for (int t=0;t<64;t++){
    if ((msel>>t)&1ull){
      dst[p2] = ((t>>2)<<8) + lane4 + (t&3);
      p2++;
    }
  }
}

// ---- generic fp32 GEMM: C[b][o][n] = act(A(OxK) @ B[b](KxN) + bias), optional col-max atomic ----
// flags: 1=leakyrelu, 2=store C, 4=bias per batch
__global__ __launch_bounds__(256) void k_gemm(const float* __restrict__ A, int lda,
        const float* __restrict__ B, const float* __restrict__ bias,
        float* __restrict__ C, unsigned* __restrict__ gmax,
        int O, int K, int flags){
  __shared__ float As[32][132];
  __shared__ float Bs[32][132];
  int tid = threadIdx.x, bx = blockIdx.x, by = blockIdx.y, b = blockIdx.z;
  int u = tid&15, v = tid>>4;
  float acc[8][8];
  #pragma unroll
  for (int i=0;i<8;i++)
    #pragma unroll
    for (int j=0;j<8;j++) acc[i][j]=0.f;
  const float* Bb = B + (size_t)b*K*N_PTS;
  for (int kt=0; kt<K; kt+=32){
    #pragma unroll
    for (int p=0;p<4;p++){
      int row = (tid>>3) + p*32, c8 = tid&7;
      int ga = by*128 + row;
      float4 av = (ga < O) ? *(const float4*)&A[(size_t)ga*lda + kt + c8*4] : make_float4(0.f,0.f,0.f,0.f);
      As[c8*4+0][row]=av.x; As[c8*4+1][row]=av.y; As[c8*4+2][row]=av.z; As[c8*4+3][row]=av.w;
      int kk = p*8 + (tid>>5), n4 = tid&31;
      float4 bv = *(const float4*)&Bb[(size_t)(kt+kk)*N_PTS + bx*128 + n4*4];
      *(float4*)&Bs[kk][n4*4] = bv;
    }
    __syncthreads();
    #pragma unroll 4
    for (int k=0;k<32;k++){
      float4 a0 = *(const float4*)&As[k][u*4];
      float4 a1 = *(const float4*)&As[k][64+u*4];
      float4 b0 = *(const float4*)&Bs[k][v*4];
      float4 b1 = *(const float4*)&Bs[k][64+v*4];
      float a[8] = {a0.x,a0.y,a0.z,a0.w,a1.x,a1.y,a1.z,a1.w};
      float bb[8] = {b0.x,b0.y,b0.z,b0.w,b1.x,b1.y,b1.z,b1.w};
      #pragma unroll
      for (int i=0;i<8;i++)
        #pragma unroll
        for (int j=0;j<8;j++)
          acc[i][j] = fmaf(a[i], bb[j], acc[i][j]);
    }
    __syncthreads();
  }
  bool relu = flags&1, store = flags&2, pbb = flags&4;
  float rowm[8];
  #pragma unroll
  for (int i=0;i<8;i++){
    int rl = (i<4)? u*4+i : 64+u*4+(i-4);
    int ri = by*128 + rl;
    float bvv = (bias != nullptr && ri < O) ? (pbb ? bias[b*O+ri] : bias[ri]) : 0.f;
    float vals[8];
    #pragma unroll
    for (int j=0;j<8;j++){
      float y = acc[i][j] + bvv;
      if (relu) y = lrelu(y);
      vals[j]=y;
    }
    if (store && ri < O){
      float* dst = C + ((size_t)b*O+ri)*N_PTS + bx*128;
      *(float4*)&dst[v*4] = make_float4(vals[0],vals[1],vals[2],vals[3]);
      *(float4*)&dst[64+v*4] = make_float4(vals[4],vals[5],vals[6],vals[7]);
    }
    float m = vals[0];
    #pragma unroll
    for (int j=1;j<8;j++) m = fmaxf(m, vals[j]);
    rowm[i] = m;
  }
  if (gmax != nullptr){
    float* red = &Bs[0][0];   // reuse as [128][16]
    #pragma unroll
    for (int i=0;i<8;i++){
      int rl = (i<4)? u*4+i : 64+u*4+(i-4);
      red[rl*16 + v] = rowm[i];
    }
    __syncthreads();
    if (tid < 128){
      float m = red[tid*16];
      #pragma unroll
      for (int j=1;j<16;j++) m = fmaxf(m, red[tid*16+j]);
      atomicMax(&gmax[b*1024 + by*128 + tid], fenc(m));
    }
  }
}

// bias7[b][o] = sum_{c<1024} Wf7[o][c]*g[b][c] + bf7[o]
__global__ __launch_bounds__(256) void k_gemv7(const float* __restrict__ Wf7, const float* __restrict__ bf7,
                        const unsigned* __restrict__ g, float* __restrict__ bias7){
  int wid = threadIdx.x>>6, lane = threadIdx.x&63;
  int o = blockIdx.x*4 + wid, b = blockIdx.y;
  const float* wr = Wf7 + (size_t)o*1216;
  const unsigned* gb = g + b*1024;
  float acc = 0.f;
  for (int c = lane; c < 1024; c += 64)
    acc = fmaf(wr[c], fdec(gb[c]), acc);
  #pragma unroll
  for (int off=32; off; off>>=1) acc += __shfl_xor(acc, off);
  if (lane==0) bias7[b*512+o] = acc + bf7[o];
}

extern "C" void kernel_launch(void* const* d_in, const int* in_sizes, int n_in,
                              void* d_out, int out_size, void* d_ws, size_t ws_size,
                              hipStream_t stream){
  const float* x  = (const float*)d_in[0];
  const float* W1 = (const float*)d_in[1];
  const float* W2 = (const float*)d_in[2];
  const float* W3 = (const float*)d_in[3];
  const float* W4 = (const float*)d_in[4];
  const float* W5 = (const float*)d_in[5];
  const float* W6 = (const float*)d_in[6];
  const float* W7 = (const float*)d_in[7];
  const float* W8 = (const float*)d_in[8];
  const float* W9 = (const float*)d_in[9];
  const float* bn1 = (const float*)d_in[10];
  const float* bn2 = (const float*)d_in[11];
  const float* bn3 = (const float*)d_in[12];
  const float* bn4 = (const float*)d_in[13];
  const float* bn5 = (const float*)d_in[14];
  const float* bn6 = (const float*)d_in[15];
  const float* bn7 = (const float*)d_in[16];
  const float* bn8 = (const float*)d_in[17];

  float* ws = (float*)d_ws;
  size_t off = 0;
  auto alloc = [&](size_t nf){ float* p = ws + off; off += (nf + 63) & ~(size_t)63; return p; };
  float* Wf6 = alloc(1024*192);   float* bf6 = alloc(1024);
  float* Wf7 = alloc((size_t)512*1216); float* bf7 = alloc(512);
  float* Wf8 = alloc(256*512);    float* bf8 = alloc(256);
  float* W1dT4 = alloc(8*64);     float* bf1 = alloc(64);
  float* W2T4  = alloc(64*64);    float* bf2 = alloc(64);
  float* W3LT4 = alloc(64*64);    float* W3RdT4 = alloc(64*64); float* bf3 = alloc(64);
  float* W4T4  = alloc(64*64);    float* bf4 = alloc(64);
  float* W5LT4 = alloc(64*64);    float* W5RdT4 = alloc(64*64); float* bf5 = alloc(64);
  float* U1  = alloc(4*KNB*64);
  float* x1t = alloc((size_t)4*N_PTS*64);
  float* x2t = alloc((size_t)4*N_PTS*64);
  float* Ut3 = alloc((size_t)4*N_PTS*64);
  float* Vt3 = alloc((size_t)4*N_PTS*64);
  float* Ut5 = alloc((size_t)4*N_PTS*64);
  float* Vt5 = alloc((size_t)4*N_PTS*64);
  float* Xcat = alloc((size_t)4*192*N_PTS);
  float* xx1 = alloc(4*N_PTS);
  float* xx2 = alloc(4*N_PTS);
  int* idx1 = (int*)alloc((size_t)4*N_PTS*KNB);
  int* idx2 = (int*)alloc((size_t)4*N_PTS*KNB);
  unsigned* genc = (unsigned*)alloc(4*1024);
  float* bias7 = alloc(4*512);
  float* h8 = alloc((size_t)4*256*N_PTS);
  // pdbuf takes the remainder; pick largest power-of-two stripe S (<=4096, >=512) that fits
  size_t remaining = (ws_size / 4 > off) ? (ws_size / 4 - off) : 0;
  int S = 4096;
  while (S > 512 && (size_t)4*S*N_PTS + 1024 > remaining) S >>= 1;
  int sshift = 31 - __builtin_clz(S);
  unsigned* pdbuf = (unsigned*)alloc((size_t)4*S*N_PTS);   // encoded u32; reused as h7 later
  float* h7 = (float*)pdbuf;

  // prep (every call: deterministic)
  k_scale_rows<<<(1024*192+255)/256,256,0,stream>>>(W6, bn6, Wf6, bf6, 1024, 192);
  k_scale_rows<<<(512*1216+255)/256,256,0,stream>>>(W7, bn7, Wf7, bf7, 512, 1216);
  k_scale_rows<<<(256*512+255)/256,256,0,stream>>>(W8, bn8, Wf8, bf8, 256, 512);
  k_build_T4<<<8,64,0,stream>>>(W1, 12, bn1, W1dT4, bf1, 0, 6, 6);     // (W1R - W1L), pad to 8
  k_build_T4<<<64,64,0,stream>>>(W2, 64, bn2, W2T4, bf2, 0, 0, 64);
  k_build_T4<<<64,64,0,stream>>>(W3, 128, bn3, W3LT4, bf3, 0, 0, 64);
  k_build_T4<<<64,64,0,stream>>>(W3, 128, bn3, W3RdT4, nullptr, 0, 64, 64);  // (W3R-W3L)*s
  k_build_T4<<<64,64,0,stream>>>(W4, 64, bn4, W4T4, bf4, 0, 0, 64);
  k_build_T4<<<64,64,0,stream>>>(W5, 128, bn5, W5LT4, bf5, 0, 0, 64);
  k_build_T4<<<64,64,0,stream>>>(W5, 128, bn5, W5RdT4, nullptr, 0, 64, 64);  // (W5R-W5L)*s
  k_build_U1<<<dim3(KNB,4),64,0,stream>>>(x, W1, bn1, U1);
  k_init_g<<<16,256,0,stream>>>(genc);

  // edge block 1 (neighbors = points 0..19 since KNN input is empty slice)
  k_edge1<<<4096,256,0,stream>>>(x, U1, W1dT4, bf1, W2T4, bf2, x1t, Xcat, xx1);

  int nstripe = N_PTS / S;
  // KNN on x1
  for (int s=0;s<nstripe;s++){
    k_knn_gemm<<<dim3(32,S/128,4),256,0,stream>>>(x1t, xx1, pdbuf, s*S, S);
    k_topk20<<<S,256,0,stream>>>(pdbuf, idx1, s*S, sshift);
  }

  // edge block 2: U3/V3 then gather+conv4
  k_uv<<<4096,256,0,stream>>>(x1t, W3LT4, W3RdT4, bf3, Ut3, Vt3);
  k_ec2<<<4096,256,0,stream>>>(Ut3, Vt3, idx1, W4T4, bf4, x2t, Xcat, xx2);

  // KNN on x2
  for (int s=0;s<nstripe;s++){
    k_knn_gemm<<<dim3(32,S/128,4),256,0,stream>>>(x2t, xx2, pdbuf, s*S, S);
    k_topk20<<<S,256,0,stream>>>(pdbuf, idx2, s*S, sshift);
  }

  // edge block 3: U5/V5 then pure gather+max
  k_uv<<<4096,256,0,stream>>>(x2t, W5LT4, W5RdT4, bf5, Ut5, Vt5);
  k_ec3<<<4096,256,0,stream>>>(Ut5, Vt5, idx2, Xcat);

  // conv6 (1024x192) -> only column max g (atomic, no store)
  k_gemm<<<dim3(32,8,4),256,0,stream>>>(Wf6, 192, Xcat, bf6, nullptr, genc, 1024, 192, 1);
  // bias7[b][o] = W7[:, :1024] @ g + bf7
  k_gemv7<<<dim3(128,4),256,0,stream>>>(Wf7, bf7, genc, bias7);
  // conv7: W7[:, 1024:1216] @ Xcat + bias7 (per batch)
  k_gemm<<<dim3(32,4,4),256,0,stream>>>(Wf7+1024, 1216, Xcat, bias7, h7, nullptr, 512, 192, 1|2|4);
  // conv8: 256x512
  k_gemm<<<dim3(32,2,4),256,0,stream>>>(Wf8, 512, h7, bf8, h8, nullptr, 256, 512, 1|2);
  // conv9: 13x256, no bias/relu -> d_out
  k_gemm<<<dim3(32,1,4),256,0,stream>>>(W9, 256, h8, nullptr, (float*)d_out, nullptr, 13, 256, 2);
}

// Round 7
// 831.616 us; speedup vs baseline: 1.5271x; 1.1346x over previous
//
#include <hip/hip_runtime.h>
#include <math.h>

#define N_PTS 4096
#define BATCH 4
#define KNB 20

__device__ __forceinline__ float lrelu(float v){ return fmaxf(v, 0.2f*v); }
__device__ __forceinline__ unsigned fenc(float f){ unsigned u=__float_as_uint(f); return (u&0x80000000u)?~u:(u|0x80000000u); }
__device__ __forceinline__ float fdec(unsigned k){ return (k&0x80000000u)?__uint_as_float(k&0x7fffffffu):__uint_as_float(~k); }

// ---- prep: fold BN scale into weights ----
__global__ void k_scale_rows(const float* __restrict__ W, const float* __restrict__ bn,
                             float* __restrict__ Wf, float* __restrict__ bias, int O, int C){
  int i = blockIdx.x*256 + threadIdx.x;
  if (i >= O*C) return;
  int o = i / C;
  float s = bn[o] / sqrtf(bn[3*O+o] + 1e-5f);
  Wf[i] = W[i]*s;
  if (i % C == 0) bias[o] = bn[O+o] - s*bn[2*O+o];
}

// transposed float4-chunk layout: dst[(c/4)*256 + o*4 + c%4], O=64 fixed
__global__ void k_build_T4(const float* __restrict__ W, int ldw, const float* __restrict__ bn,
                           float* __restrict__ dst, float* __restrict__ bias,
                           int c0, int diffoff, int Csrc){
  int o = threadIdx.x, c = blockIdx.x;
  float s = bn[o] / sqrtf(bn[192+o] + 1e-5f);
  float val = 0.f;
  if (c < Csrc){
    val = W[o*ldw + c0 + c];
    if (diffoff) val = W[o*ldw + c0 + diffoff + c] - val;
    val *= s;
  }
  dst[(c>>2)*256 + o*4 + (c&3)] = val;
  if (bias != nullptr && c==0) bias[o] = bn[64+o] - s*bn[128+o];
}

// U1[b][k][o] = sum_{c<6} s_o*W1[o][c]*x[b][c][k]  (first-KNN neighbors are points 0..19)
__global__ void k_build_U1(const float* __restrict__ x, const float* __restrict__ W1,
                           const float* __restrict__ bn, float* __restrict__ U1){
  int o = threadIdx.x, k = blockIdx.x, b = blockIdx.y;
  float s = bn[o] / sqrtf(bn[192+o] + 1e-5f);
  float acc = 0.f;
  #pragma unroll
  for (int c=0;c<6;c++) acc += W1[o*12+c] * x[(b*6+c)*N_PTS + k];
  U1[(b*KNB+k)*64 + o] = acc*s;
}

__global__ void k_init_g(unsigned* g){ g[blockIdx.x*256+threadIdx.x] = fenc(-INFINITY); }

// ---- edge block 1 (trivial neighbors 0..19) : conv1 + conv2 + maxpool ----
__global__ __launch_bounds__(256) void k_edge1(const float* __restrict__ x, const float* __restrict__ U1,
                        const float* __restrict__ W1dT4, const float* __restrict__ bf1,
                        const float* __restrict__ W2T4, const float* __restrict__ bf2,
                        float* __restrict__ x1t, float* __restrict__ Xcat, float* __restrict__ xx1){
  __shared__ float hb[4][KNB][64];
  int wid = threadIdx.x>>6, lane = threadIdx.x&63;
  int pt = blockIdx.x*4 + wid, b = pt>>12, n = pt&4095;
  float xv[8];
  #pragma unroll
  for (int c=0;c<6;c++) xv[c] = x[(b*6+c)*N_PTS + n];
  xv[6]=0.f; xv[7]=0.f;
  float w = bf1[lane];
  #pragma unroll
  for (int cb=0;cb<2;cb++){
    float4 wv = ((const float4*)W1dT4)[cb*64+lane];
    w = fmaf(wv.x, xv[cb*4+0], w); w = fmaf(wv.y, xv[cb*4+1], w);
    w = fmaf(wv.z, xv[cb*4+2], w); w = fmaf(wv.w, xv[cb*4+3], w);
  }
  const float* Ub = U1 + b*KNB*64;
  #pragma unroll
  for (int k=0;k<KNB;k++) hb[wid][k][lane] = lrelu(Ub[k*64+lane] + w);
  __syncthreads();
  float acc[KNB];
  #pragma unroll
  for (int k=0;k<KNB;k++) acc[k] = bf2[lane];
  for (int cb=0;cb<16;cb++){
    float4 wv = ((const float4*)W2T4)[cb*64+lane];
    #pragma unroll
    for (int k=0;k<KNB;k++){
      float4 a = *(const float4*)&hb[wid][k][cb*4];
      acc[k]=fmaf(wv.x,a.x,acc[k]); acc[k]=fmaf(wv.y,a.y,acc[k]);
      acc[k]=fmaf(wv.z,a.z,acc[k]); acc[k]=fmaf(wv.w,a.w,acc[k]);
    }
  }
  float mx = -INFINITY;
  #pragma unroll
  for (int k=0;k<KNB;k++) mx = fmaxf(mx, acc[k]);
  mx = lrelu(mx);
  x1t[(size_t)pt*64 + lane] = mx;
  Xcat[((size_t)b*192 + 0 + lane)*N_PTS + n] = mx;
  float sq = mx*mx;
  #pragma unroll
  for (int off=32; off; off>>=1) sq += __shfl_xor(sq, off);
  if (lane==0) xx1[pt] = sq;
}

// ---- U/V precompute: Ut[n][o] = s*(WL@x_n); Vt[n][o] = s*((WR-WL)@x_n) + bias ----
__global__ __launch_bounds__(256) void k_uv(const float* __restrict__ xt, const float* __restrict__ WL,
    const float* __restrict__ WRd, const float* __restrict__ bf,
    float* __restrict__ Ut, float* __restrict__ Vt){
  __shared__ float xs[4][64];
  int wid = threadIdx.x>>6, lane = threadIdx.x&63;
  int pt = blockIdx.x*4 + wid;
  xs[wid][lane] = xt[(size_t)pt*64 + lane];
  __syncthreads();
  float U = 0.f, V = bf[lane];
  #pragma unroll
  for (int cb=0;cb<16;cb++){
    float4 wl = ((const float4*)WL)[cb*64+lane];
    float4 wr = ((const float4*)WRd)[cb*64+lane];
    float4 xv = *(const float4*)&xs[wid][cb*4];
    U=fmaf(wl.x,xv.x,U); U=fmaf(wl.y,xv.y,U); U=fmaf(wl.z,xv.z,U); U=fmaf(wl.w,xv.w,U);
    V=fmaf(wr.x,xv.x,V); V=fmaf(wr.y,xv.y,V); V=fmaf(wr.z,xv.z,V); V=fmaf(wr.w,xv.w,V);
  }
  Ut[(size_t)pt*64 + lane] = U;
  Vt[(size_t)pt*64 + lane] = V;
}

// ---- edge block 2: h = lrelu(U3[m_k]+V3[n]) (gather), then conv4 + max ----
__global__ __launch_bounds__(256) void k_ec2(const float* __restrict__ Ut, const float* __restrict__ Vt,
    const int* __restrict__ idx, const float* __restrict__ W2T4, const float* __restrict__ bfb,
    float* __restrict__ xout, float* __restrict__ Xcat, float* __restrict__ xxout){
  __shared__ float H[4][KNB][64];
  int wid = threadIdx.x>>6, lane = threadIdx.x&63;
  int pt = blockIdx.x*4 + wid, b = pt>>12, n = pt&4095;
  const float* Ub = Ut + (((size_t)b)<<12)*64;
  float Vv = Vt[(size_t)pt*64 + lane];
  int mr[KNB];
  const int4* ip4 = (const int4*)(idx + (size_t)pt*KNB);
  #pragma unroll
  for (int q=0;q<5;q++){ int4 t = ip4[q]; mr[q*4+0]=t.x; mr[q*4+1]=t.y; mr[q*4+2]=t.z; mr[q*4+3]=t.w; }
  #pragma unroll
  for (int k=0;k<KNB;k++) H[wid][k][lane] = lrelu(Ub[(size_t)mr[k]*64 + lane] + Vv);
  __syncthreads();
  float acc[KNB];
  #pragma unroll
  for (int k=0;k<KNB;k++) acc[k] = bfb[lane];
  for (int cb=0;cb<16;cb++){
    float4 wv = ((const float4*)W2T4)[cb*64+lane];
    #pragma unroll
    for (int k=0;k<KNB;k++){
      float4 a = *(const float4*)&H[wid][k][cb*4];
      acc[k]=fmaf(wv.x,a.x,acc[k]); acc[k]=fmaf(wv.y,a.y,acc[k]);
      acc[k]=fmaf(wv.z,a.z,acc[k]); acc[k]=fmaf(wv.w,a.w,acc[k]);
    }
  }
  float mx = -INFINITY;
  #pragma unroll
  for (int k=0;k<KNB;k++) mx = fmaxf(mx, acc[k]);
  mx = lrelu(mx);
  xout[(size_t)pt*64 + lane] = mx;
  Xcat[((size_t)b*192 + 64 + lane)*N_PTS + n] = mx;
  float sq = mx*mx;
  #pragma unroll
  for (int off=32;off;off>>=1) sq += __shfl_xor(sq,off);
  if (lane==0) xxout[pt] = sq;
}

// ---- edge block 3: x3[n] = lrelu(V5[n] + max_k U5[m_k]) -- pure gather+max ----
__global__ __launch_bounds__(256) void k_ec3(const float* __restrict__ Ut, const float* __restrict__ Vt,
    const int* __restrict__ idx, float* __restrict__ Xcat){
  int wid = threadIdx.x>>6, lane = threadIdx.x&63;
  int pt = blockIdx.x*4 + wid, b = pt>>12, n = pt&4095;
  const float* Ub = Ut + (((size_t)b)<<12)*64;
  int mr[KNB];
  const int4* ip4 = (const int4*)(idx + (size_t)pt*KNB);
  #pragma unroll
  for (int q=0;q<5;q++){ int4 t = ip4[q]; mr[q*4+0]=t.x; mr[q*4+1]=t.y; mr[q*4+2]=t.z; mr[q*4+3]=t.w; }
  float mx = -INFINITY;
  #pragma unroll
  for (int k=0;k<KNB;k++) mx = fmaxf(mx, Ub[(size_t)mr[k]*64 + lane]);
  mx = lrelu(mx + Vt[(size_t)pt*64 + lane]);
  Xcat[((size_t)b*192 + 128 + lane)*N_PTS + n] = mx;
}

// ---- KNN pairwise kernel: pd = fenc(fma(2,dot,-xx_n) - xx_m), 128x128 tile ----
// Also emits per-(row, 64-col-chunk) max cmax[b][q][64] (fenc'd) for filtered top-k.
__global__ __launch_bounds__(256) void k_knn_gemm(const float* __restrict__ xt, const float* __restrict__ xx,
                          unsigned* __restrict__ pd, unsigned* __restrict__ cmax, int q0, int S){
  __shared__ float As[32][132];
  __shared__ float Bs[32][132];
  int tid = threadIdx.x;
  int bx = blockIdx.x, by = blockIdx.y, b = blockIdx.z;
  const float* xb = xt + (size_t)b*N_PTS*64;
  int u = tid&15, v = tid>>4;
  float acc[8][8];
  #pragma unroll
  for (int i=0;i<8;i++)
    #pragma unroll
    for (int j=0;j<8;j++) acc[i][j]=0.f;
  for (int kc=0;kc<2;kc++){
    #pragma unroll
    for (int p=0;p<4;p++){
      int row = (tid>>3) + p*32, c8 = tid&7;
      float4 av = *(const float4*)&xb[(size_t)(q0 + by*128 + row)*64 + kc*32 + c8*4];
      As[c8*4+0][row]=av.x; As[c8*4+1][row]=av.y; As[c8*4+2][row]=av.z; As[c8*4+3][row]=av.w;
      float4 bv = *(const float4*)&xb[(size_t)(bx*128 + row)*64 + kc*32 + c8*4];
      Bs[c8*4+0][row]=bv.x; Bs[c8*4+1][row]=bv.y; Bs[c8*4+2][row]=bv.z; Bs[c8*4+3][row]=bv.w;
    }
    __syncthreads();
    #pragma unroll 4
    for (int k=0;k<32;k++){
      float4 a0 = *(const float4*)&As[k][u*4];
      float4 a1 = *(const float4*)&As[k][64+u*4];
      float4 b0 = *(const float4*)&Bs[k][v*4];
      float4 b1 = *(const float4*)&Bs[k][64+v*4];
      float a[8] = {a0.x,a0.y,a0.z,a0.w,a1.x,a1.y,a1.z,a1.w};
      float bb[8] = {b0.x,b0.y,b0.z,b0.w,b1.x,b1.y,b1.z,b1.w};
      #pragma unroll
      for (int i=0;i<8;i++)
        #pragma unroll
        for (int j=0;j<8;j++)
          acc[i][j] = fmaf(a[i], bb[j], acc[i][j]);
    }
    __syncthreads();
  }
  float xn[8], xm[8];
  #pragma unroll
  for (int i=0;i<8;i++){
    int ri = (i<4)? u*4+i : 64+u*4+(i-4);
    xn[i] = xx[b*N_PTS + q0 + by*128 + ri];
  }
  #pragma unroll
  for (int j=0;j<8;j++){
    int cj = (j<4)? v*4+j : 64+v*4+(j-4);
    xm[j] = xx[b*N_PTS + bx*128 + cj];
  }
  float* red = &Bs[0][0];   // reuse as [128 rows][16 v][2 halves] = 16KB
  #pragma unroll
  for (int i=0;i<8;i++){
    int rl = (i<4)? u*4+i : 64+u*4+(i-4);
    unsigned* dst = pd + ((size_t)(b*S + by*128 + rl))*N_PTS + bx*128;
    float f[8];
    #pragma unroll
    for (int j=0;j<8;j++) f[j] = fmaf(2.f,acc[i][j],-xn[i]) - xm[j];
    uint4 o0 = make_uint4(fenc(f[0]),fenc(f[1]),fenc(f[2]),fenc(f[3]));
    uint4 o1 = make_uint4(fenc(f[4]),fenc(f[5]),fenc(f[6]),fenc(f[7]));
    *(uint4*)&dst[v*4] = o0;
    *(uint4*)&dst[64+v*4] = o1;
    float m0 = fmaxf(fmaxf(f[0],f[1]), fmaxf(f[2],f[3]));
    float m1 = fmaxf(fmaxf(f[4],f[5]), fmaxf(f[6],f[7]));
    red[rl*32 + v*2 + 0] = m0;
    red[rl*32 + v*2 + 1] = m1;
  }
  __syncthreads();
  {
    int rr = tid & 127, hh = tid >> 7;
    float m = red[rr*32 + hh];
    #pragma unroll
    for (int v2=1; v2<16; v2++) m = fmaxf(m, red[rr*32 + v2*2 + hh]);
    cmax[((size_t)b*N_PTS + q0 + by*128 + rr)*64 + bx*2 + hh] = fenc(m);
  }
}

__device__ __forceinline__ unsigned bitsort_u32(unsigned v, int lane){
  #pragma unroll
  for (int k=2;k<=64;k<<=1){
    #pragma unroll
    for (int j=k>>1;j>0;j>>=1){
      unsigned o = (unsigned)__shfl_xor((int)v, j);
      bool takeMax = (((lane & j) != 0) == ((lane & k) == 0));
      unsigned mx = v>o?v:o, mn = v<o?v:o;
      v = takeMax ? mx : mn;
    }
  }
  return v;   // ascending by lane
}

// ---- filtered top-20: chunk-max prefilter + streaming candidate selection ----
// Exact jax set {key >= K20}, key=(val desc, idx asc); output order arbitrary.
__global__ __launch_bounds__(256,4) void k_topk20(const unsigned* __restrict__ pdbuf,
        const unsigned* __restrict__ cmax, int* __restrict__ idxout, int q0, int sshift){
  __shared__ unsigned long long cand[4][64];
  int wid = threadIdx.x>>6, lane = threadIdx.x&63;
  int gw = blockIdx.x*4 + wid;
  int S = 1 << sshift;
  int b = gw >> sshift, i = gw & (S-1);
  const unsigned* row = pdbuf + ((size_t)b*S + i)*N_PTS;
  // chunk-max threshold: T = 20th largest of the 64 chunk maxes
  unsigned cm = cmax[((size_t)b*N_PTS + q0 + i)*64 + lane];
  unsigned T = (unsigned)__shfl((int)bitsort_u32(cm, lane), 44);
  unsigned long long qual = __ballot(cm >= T);   // >=20 qualifying chunks
  // pass 1: per-lane max over qualifying chunks
  unsigned lmax = 0u;
  for (int c=0;c<64;c++){
    if (!((qual>>c)&1ull)) continue;
    unsigned vv = row[c*64 + lane];
    lmax = lmax > vv ? lmax : vv;
  }
  unsigned T2 = (unsigned)__shfl((int)bitsort_u32(lmax, lane), 44);
  // pass 2: compact candidates (v >= T2) into LDS as u64 keys
  int base = 0;
  unsigned long long below = (1ull<<lane) - 1ull;
  for (int c=0;c<64;c++){
    if (!((qual>>c)&1ull)) continue;
    unsigned vv = row[c*64 + lane];
    bool isc = vv >= T2;
    unsigned long long mb = __ballot(isc);
    int pos = base + __popcll(mb & below);
    if (isc && pos < 64){
      int m = c*64 + lane;
      cand[wid][pos] = (((unsigned long long)vv)<<12) | (unsigned)(4095-m);
    }
    base += __popcll(mb);
  }
  unsigned long long K;
  if (base <= 64){
    unsigned long long kv = (lane < base) ? cand[wid][lane] : 0ull;
    #pragma unroll
    for (int k=2;k<=64;k<<=1){
      #pragma unroll
      for (int j=k>>1;j>0;j>>=1){
        unsigned long long o = __shfl_xor(kv, j);
        bool takeMax = (((lane & j) != 0) == ((lane & k) == 0));
        unsigned long long mx = kv>o?kv:o, mn = kv<o?kv:o;
        kv = takeMax ? mx : mn;
      }
    }
    K = __shfl(kv, 44);
  } else {
    // degenerate tie storm: exact 44-bit bisect over streamed keys
    K = 0ull;
    for (int bb2=43; bb2>=0; --bb2){
      unsigned long long cnd = K | (1ull<<bb2);
      int lc = 0;
      for (int c=0;c<64;c++){
        if (!((qual>>c)&1ull)) continue;
        unsigned vv = row[c*64 + lane];
        int m = c*64 + lane;
        unsigned long long key = (((unsigned long long)vv)<<12) | (unsigned)(4095-m);
        if (key >= cnd) lc++;
      }
      #pragma unroll
      for (int off=32; off; off>>=1) lc += __shfl_xor(lc, off);
      if (lc >= KNB) K = cnd;
    }
  }
  // pass 3: emission of exactly the 20 keys >= K
  int eb = 0;
  int* dst = idxout + ((size_t)b*N_PTS + (q0+i))*KNB;
  for (int c=0;c<64;c++){
    if (!((qual>>c)&1ull)) continue;
    unsigned vv = row[c*64 + lane];
    int m = c*64 + lane;
    unsigned long long key = (((unsigned long long)vv)<<12) | (unsigned)(4095-m);
    bool sel = key >= K;
    unsigned long long mb = __ballot(sel);
    int pos = eb + __popcll(mb & below);
    if (sel) dst[pos] = m;
    eb += __popcll(mb);
  }
}

// ---- generic fp32 GEMM, 64x64 tiles: C[b][o][n] = act(A(OxK) @ B[b](KxN) + bias) ----
// flags: 1=leakyrelu, 2=store C, 4=bias per batch; gmax: fenc'd col-max atomic
__global__ __launch_bounds__(256) void k_gemm(const float* __restrict__ A, int lda,
        const float* __restrict__ B, const float* __restrict__ bias,
        float* __restrict__ C, unsigned* __restrict__ gmax,
        int O, int K, int flags){
  __shared__ float As[32][68];
  __shared__ float Bs[32][68];
  int tid = threadIdx.x, bx = blockIdx.x, by = blockIdx.y, b = blockIdx.z;
  int u = tid&15, v = tid>>4;
  float acc[4][4];
  #pragma unroll
  for (int i=0;i<4;i++)
    #pragma unroll
    for (int j=0;j<4;j++) acc[i][j]=0.f;
  const float* Bb = B + (size_t)b*K*N_PTS;
  for (int kt=0; kt<K; kt+=32){
    #pragma unroll
    for (int p=0;p<2;p++){
      int row = (tid>>3) + p*32, c8 = tid&7;
      int ga = by*64 + row;
      float4 av = (ga < O) ? *(const float4*)&A[(size_t)ga*lda + kt + c8*4] : make_float4(0.f,0.f,0.f,0.f);
      As[c8*4+0][row]=av.x; As[c8*4+1][row]=av.y; As[c8*4+2][row]=av.z; As[c8*4+3][row]=av.w;
      int kk = (tid>>4) + p*16, c4 = tid&15;
      float4 bv = *(const float4*)&Bb[(size_t)(kt+kk)*N_PTS + bx*64 + c4*4];
      *(float4*)&Bs[kk][c4*4] = bv;
    }
    __syncthreads();
    #pragma unroll 8
    for (int k=0;k<32;k++){
      float4 a0 = *(const float4*)&As[k][u*4];
      float4 b0 = *(const float4*)&Bs[k][v*4];
      float a[4] = {a0.x,a0.y,a0.z,a0.w};
      float bb[4] = {b0.x,b0.y,b0.z,b0.w};
      #pragma unroll
      for (int i=0;i<4;i++)
        #pragma unroll
        for (int j=0;j<4;j++)
          acc[i][j] = fmaf(a[i], bb[j], acc[i][j]);
    }
    __syncthreads();
  }
  bool relu = flags&1, store = flags&2, pbb = flags&4;
  float rowm[4];
  #pragma unroll
  for (int i=0;i<4;i++){
    int ri = by*64 + u*4 + i;
    float bvv = (bias != nullptr && ri < O) ? (pbb ? bias[b*O+ri] : bias[ri]) : 0.f;
    float vals[4];
    #pragma unroll
    for (int j=0;j<4;j++){
      float y = acc[i][j] + bvv;
      if (relu) y = lrelu(y);
      vals[j]=y;
    }
    if (store && ri < O){
      float* dst = C + ((size_t)b*O+ri)*N_PTS + bx*64;
      *(float4*)&dst[v*4] = make_float4(vals[0],vals[1],vals[2],vals[3]);
    }
    float m = fmaxf(fmaxf(vals[0],vals[1]), fmaxf(vals[2],vals[3]));
    rowm[i] = m;
  }
  if (gmax != nullptr){
    float* red = &Bs[0][0];   // [64 rows][16 v] = 4KB
    #pragma unroll
    for (int i=0;i<4;i++) red[(u*4+i)*16 + v] = rowm[i];
    __syncthreads();
    if (tid < 64){
      float m = red[tid*16];
      #pragma unroll
      for (int j=1;j<16;j++) m = fmaxf(m, red[tid*16+j]);
      atomicMax(&gmax[b*1024 + by*64 + tid], fenc(m));
    }
  }
}

// bias7[b][o] = sum_{c<1024} Wf7[o][c]*g[b][c] + bf7[o]
__global__ __launch_bounds__(256) void k_gemv7(const float* __restrict__ Wf7, const float* __restrict__ bf7,
                        const unsigned* __restrict__ g, float* __restrict__ bias7){
  int wid = threadIdx.x>>6, lane = threadIdx.x&63;
  int o = blockIdx.x*4 + wid, b = blockIdx.y;
  const float* wr = Wf7 + (size_t)o*1216;
  const unsigned* gb = g + b*1024;
  float acc = 0.f;
  for (int c = lane; c < 1024; c += 64)
    acc = fmaf(wr[c], fdec(gb[c]), acc);
  #pragma unroll
  for (int off=32; off; off>>=1) acc += __shfl_xor(acc, off);
  if (lane==0) bias7[b*512+o] = acc + bf7[o];
}

extern "C" void kernel_launch(void* const* d_in, const int* in_sizes, int n_in,
                              void* d_out, int out_size, void* d_ws, size_t ws_size,
                              hipStream_t stream){
  const float* x  = (const float*)d_in[0];
  const float* W1 = (const float*)d_in[1];
  const float* W2 = (const float*)d_in[2];
  const float* W3 = (const float*)d_in[3];
  const float* W4 = (const float*)d_in[4];
  const float* W5 = (const float*)d_in[5];
  const float* W6 = (const float*)d_in[6];
  const float* W7 = (const float*)d_in[7];
  const float* W8 = (const float*)d_in[8];
  const float* W9 = (const float*)d_in[9];
  const float* bn1 = (const float*)d_in[10];
  const float* bn2 = (const float*)d_in[11];
  const float* bn3 = (const float*)d_in[12];
  const float* bn4 = (const float*)d_in[13];
  const float* bn5 = (const float*)d_in[14];
  const float* bn6 = (const float*)d_in[15];
  const float* bn7 = (const float*)d_in[16];
  const float* bn8 = (const float*)d_in[17];

  float* ws = (float*)d_ws;
  size_t off = 0;
  auto alloc = [&](size_t nf){ float* p = ws + off; off += (nf + 63) & ~(size_t)63; return p; };
  float* Wf6 = alloc(1024*192);   float* bf6 = alloc(1024);
  float* Wf7 = alloc((size_t)512*1216); float* bf7 = alloc(512);
  float* Wf8 = alloc(256*512);    float* bf8 = alloc(256);
  float* W1dT4 = alloc(8*64);     float* bf1 = alloc(64);
  float* W2T4  = alloc(64*64);    float* bf2 = alloc(64);
  float* W3LT4 = alloc(64*64);    float* W3RdT4 = alloc(64*64); float* bf3 = alloc(64);
  float* W4T4  = alloc(64*64);    float* bf4 = alloc(64);
  float* W5LT4 = alloc(64*64);    float* W5RdT4 = alloc(64*64); float* bf5 = alloc(64);
  float* U1  = alloc(4*KNB*64);
  float* x1t = alloc((size_t)4*N_PTS*64);
  float* x2t = alloc((size_t)4*N_PTS*64);
  float* Ut3 = alloc((size_t)4*N_PTS*64);
  float* Vt3 = alloc((size_t)4*N_PTS*64);
  float* Ut5 = alloc((size_t)4*N_PTS*64);
  float* Vt5 = alloc((size_t)4*N_PTS*64);
  float* Xcat = alloc((size_t)4*192*N_PTS);
  float* xx1 = alloc(4*N_PTS);
  float* xx2 = alloc(4*N_PTS);
  int* idx1 = (int*)alloc((size_t)4*N_PTS*KNB);
  int* idx2 = (int*)alloc((size_t)4*N_PTS*KNB);
  unsigned* genc = (unsigned*)alloc(4*1024);
  float* bias7 = alloc(4*512);
  float* h8 = alloc((size_t)4*256*N_PTS);
  unsigned* cmaxb = (unsigned*)alloc((size_t)4*N_PTS*64);
  // pdbuf takes the remainder; pick largest power-of-two stripe S (<=4096, >=512) that fits
  size_t remaining = (ws_size / 4 > off) ? (ws_size / 4 - off) : 0;
  int S = 4096;
  while (S > 512 && (size_t)4*S*N_PTS + 1024 > remaining) S >>= 1;
  int sshift = 31 - __builtin_clz(S);
  unsigned* pdbuf = (unsigned*)alloc((size_t)4*S*N_PTS);   // encoded u32; reused as h7 later
  float* h7 = (float*)pdbuf;

  // prep (every call: deterministic)
  k_scale_rows<<<(1024*192+255)/256,256,0,stream>>>(W6, bn6, Wf6, bf6, 1024, 192);
  k_scale_rows<<<(512*1216+255)/256,256,0,stream>>>(W7, bn7, Wf7, bf7, 512, 1216);
  k_scale_rows<<<(256*512+255)/256,256,0,stream>>>(W8, bn8, Wf8, bf8, 256, 512);
  k_build_T4<<<8,64,0,stream>>>(W1, 12, bn1, W1dT4, bf1, 0, 6, 6);     // (W1R - W1L), pad to 8
  k_build_T4<<<64,64,0,stream>>>(W2, 64, bn2, W2T4, bf2, 0, 0, 64);
  k_build_T4<<<64,64,0,stream>>>(W3, 128, bn3, W3LT4, bf3, 0, 0, 64);
  k_build_T4<<<64,64,0,stream>>>(W3, 128, bn3, W3RdT4, nullptr, 0, 64, 64);  // (W3R-W3L)*s
  k_build_T4<<<64,64,0,stream>>>(W4, 64, bn4, W4T4, bf4, 0, 0, 64);
  k_build_T4<<<64,64,0,stream>>>(W5, 128, bn5, W5LT4, bf5, 0, 0, 64);
  k_build_T4<<<64,64,0,stream>>>(W5, 128, bn5, W5RdT4, nullptr, 0, 64, 64);  // (W5R-W5L)*s
  k_build_U1<<<dim3(KNB,4),64,0,stream>>>(x, W1, bn1, U1);
  k_init_g<<<16,256,0,stream>>>(genc);

  // edge block 1 (neighbors = points 0..19 since KNN input is empty slice)
  k_edge1<<<4096,256,0,stream>>>(x, U1, W1dT4, bf1, W2T4, bf2, x1t, Xcat, xx1);

  int nstripe = N_PTS / S;
  // KNN on x1
  for (int s=0;s<nstripe;s++){
    k_knn_gemm<<<dim3(32,S/128,4),256,0,stream>>>(x1t, xx1, pdbuf, cmaxb, s*S, S);
    k_topk20<<<S,256,0,stream>>>(pdbuf, cmaxb, idx1, s*S, sshift);
  }

  // edge block 2: U3/V3 then gather+conv4
  k_uv<<<4096,256,0,stream>>>(x1t, W3LT4, W3RdT4, bf3, Ut3, Vt3);
  k_ec2<<<4096,256,0,stream>>>(Ut3, Vt3, idx1, W4T4, bf4, x2t, Xcat, xx2);

  // KNN on x2
  for (int s=0;s<nstripe;s++){
    k_knn_gemm<<<dim3(32,S/128,4),256,0,stream>>>(x2t, xx2, pdbuf, cmaxb, s*S, S);
    k_topk20<<<S,256,0,stream>>>(pdbuf, cmaxb, idx2, s*S, sshift);
  }

  // edge block 3: U5/V5 then pure gather+max
  k_uv<<<4096,256,0,stream>>>(x2t, W5LT4, W5RdT4, bf5, Ut5, Vt5);
  k_ec3<<<4096,256,0,stream>>>(Ut5, Vt5, idx2, Xcat);

  // conv6 (1024x192) -> only column max g (atomic, no store)
  k_gemm<<<dim3(64,16,4),256,0,stream>>>(Wf6, 192, Xcat, bf6, nullptr, genc, 1024, 192, 1);
  // bias7[b][o] = W7[:, :1024] @ g + bf7
  k_gemv7<<<dim3(128,4),256,0,stream>>>(Wf7, bf7, genc, bias7);
  // conv7: W7[:, 1024:1216] @ Xcat + bias7 (per batch)
  k_gemm<<<dim3(64,8,4),256,0,stream>>>(Wf7+1024, 1216, Xcat, bias7, h7, nullptr, 512, 192, 1|2|4);
  // conv8: 256x512
  k_gemm<<<dim3(64,4,4),256,0,stream>>>(Wf8, 512, h7, bf8, h8, nullptr, 256, 512, 1|2);
  // conv9: 13x256, no bias/relu -> d_out
  k_gemm<<<dim3(64,1,4),256,0,stream>>>(W9, 256, h8, nullptr, (float*)d_out, nullptr, 13, 256, 2);
}

// Round 8
// 690.052 us; speedup vs baseline: 1.8404x; 1.2051x over previous
//
#include <hip/hip_runtime.h>
#include <math.h>

#define N_PTS 4096
#define BATCH 4
#define KNB 20

typedef __attribute__((ext_vector_type(8))) short short8v;   // 8 bf16
typedef __attribute__((ext_vector_type(4))) float f32x4;

__device__ __forceinline__ float lrelu(float v){ return fmaxf(v, 0.2f*v); }
__device__ __forceinline__ unsigned fenc(float f){ unsigned u=__float_as_uint(f); return (u&0x80000000u)?~u:(u|0x80000000u); }
__device__ __forceinline__ float fdec(unsigned k){ return (k&0x80000000u)?__uint_as_float(k&0x7fffffffu):__uint_as_float(~k); }

// split f32 -> packed (bf16_hi << 16) | bf16_lo,  v ~= hi + lo, err ~2^-18 rel
__device__ __forceinline__ unsigned pack2(float v){
  unsigned u = __float_as_uint(v);
  unsigned hi = (u + 0x7fffu + ((u>>16)&1u)) >> 16;
  float hf = __uint_as_float(hi<<16);
  unsigned u2 = __float_as_uint(v - hf);
  unsigned lo = (u2 + 0x7fffu + ((u2>>16)&1u)) >> 16;
  return (hi<<16) | lo;
}
__device__ __forceinline__ void cvt8(uint4 v0, uint4 v1, short8v& h, short8v& l){
  unsigned a0=v0.x,a1=v0.y,a2=v0.z,a3=v0.w,a4=v1.x,a5=v1.y,a6=v1.z,a7=v1.w;
  h[0]=(short)(a0>>16); l[0]=(short)(a0&0xffffu);
  h[1]=(short)(a1>>16); l[1]=(short)(a1&0xffffu);
  h[2]=(short)(a2>>16); l[2]=(short)(a2&0xffffu);
  h[3]=(short)(a3>>16); l[3]=(short)(a3&0xffffu);
  h[4]=(short)(a4>>16); l[4]=(short)(a4&0xffffu);
  h[5]=(short)(a5>>16); l[5]=(short)(a5&0xffffu);
  h[6]=(short)(a6>>16); l[6]=(short)(a6&0xffffu);
  h[7]=(short)(a7>>16); l[7]=(short)(a7&0xffffu);
}

// ---- prep: fold BN scale into weights (f32, for gemv7) ----
__global__ void k_scale_rows(const float* __restrict__ W, const float* __restrict__ bn,
                             float* __restrict__ Wf, float* __restrict__ bias, int O, int C){
  int i = blockIdx.x*256 + threadIdx.x;
  if (i >= O*C) return;
  int o = i / C;
  float s = bn[o] / sqrtf(bn[3*O+o] + 1e-5f);
  Wf[i] = W[i]*s;
  if (i % C == 0) bias[o] = bn[O+o] - s*bn[2*O+o];
}

// pack scaled weights to (hi|lo) u32 [Opad][C]; rows >= O zero-padded
__global__ void k_pack_w(const float* __restrict__ W, int ldw, int c0,
                         const float* __restrict__ bn, int O, int C, int Opad,
                         unsigned* __restrict__ out, float* __restrict__ bias){
  int i = blockIdx.x*256 + threadIdx.x;
  if (i >= Opad*C) return;
  int o = i / C, c = i - o*C;
  float v = 0.f;
  if (o < O){
    float s = 1.f;
    if (bn != nullptr){
      s = bn[o] / sqrtf(bn[3*O+o] + 1e-5f);
      if (bias != nullptr && c == 0) bias[o] = bn[O+o] - s*bn[2*O+o];
    }
    v = W[o*ldw + c0 + c] * s;
  }
  out[i] = pack2(v);
}

// transposed float4-chunk layout: dst[(c/4)*256 + o*4 + c%4], O=64 fixed
__global__ void k_build_T4(const float* __restrict__ W, int ldw, const float* __restrict__ bn,
                           float* __restrict__ dst, float* __restrict__ bias,
                           int c0, int diffoff, int Csrc){
  int o = threadIdx.x, c = blockIdx.x;
  float s = bn[o] / sqrtf(bn[192+o] + 1e-5f);
  float val = 0.f;
  if (c < Csrc){
    val = W[o*ldw + c0 + c];
    if (diffoff) val = W[o*ldw + c0 + diffoff + c] - val;
    val *= s;
  }
  dst[(c>>2)*256 + o*4 + (c&3)] = val;
  if (bias != nullptr && c==0) bias[o] = bn[64+o] - s*bn[128+o];
}

// U1[b][k][o] = sum_{c<6} s_o*W1[o][c]*x[b][c][k]  (first-KNN neighbors are points 0..19)
__global__ void k_build_U1(const float* __restrict__ x, const float* __restrict__ W1,
                           const float* __restrict__ bn, float* __restrict__ U1){
  int o = threadIdx.x, k = blockIdx.x, b = blockIdx.y;
  float s = bn[o] / sqrtf(bn[192+o] + 1e-5f);
  float acc = 0.f;
  #pragma unroll
  for (int c=0;c<6;c++) acc += W1[o*12+c] * x[(b*6+c)*N_PTS + k];
  U1[(b*KNB+k)*64 + o] = acc*s;
}

__global__ void k_init_g(unsigned* g){ g[blockIdx.x*256+threadIdx.x] = fenc(-INFINITY); }

// ---- edge block 1 (trivial neighbors 0..19) : conv1 + conv2 + maxpool ----
__global__ __launch_bounds__(256) void k_edge1(const float* __restrict__ x, const float* __restrict__ U1,
                        const float* __restrict__ W1dT4, const float* __restrict__ bf1,
                        const float* __restrict__ W2T4, const float* __restrict__ bf2,
                        float* __restrict__ x1t, unsigned* __restrict__ Xb, float* __restrict__ xx1){
  __shared__ float hb[4][KNB][64];
  int wid = threadIdx.x>>6, lane = threadIdx.x&63;
  int pt = blockIdx.x*4 + wid, b = pt>>12, n = pt&4095;
  float xv[8];
  #pragma unroll
  for (int c=0;c<6;c++) xv[c] = x[(b*6+c)*N_PTS + n];
  xv[6]=0.f; xv[7]=0.f;
  float w = bf1[lane];
  #pragma unroll
  for (int cb=0;cb<2;cb++){
    float4 wv = ((const float4*)W1dT4)[cb*64+lane];
    w = fmaf(wv.x, xv[cb*4+0], w); w = fmaf(wv.y, xv[cb*4+1], w);
    w = fmaf(wv.z, xv[cb*4+2], w); w = fmaf(wv.w, xv[cb*4+3], w);
  }
  const float* Ub = U1 + b*KNB*64;
  #pragma unroll
  for (int k=0;k<KNB;k++) hb[wid][k][lane] = lrelu(Ub[k*64+lane] + w);
  __syncthreads();
  float acc[KNB];
  #pragma unroll
  for (int k=0;k<KNB;k++) acc[k] = bf2[lane];
  for (int cb=0;cb<16;cb++){
    float4 wv = ((const float4*)W2T4)[cb*64+lane];
    #pragma unroll
    for (int k=0;k<KNB;k++){
      float4 a = *(const float4*)&hb[wid][k][cb*4];
      acc[k]=fmaf(wv.x,a.x,acc[k]); acc[k]=fmaf(wv.y,a.y,acc[k]);
      acc[k]=fmaf(wv.z,a.z,acc[k]); acc[k]=fmaf(wv.w,a.w,acc[k]);
    }
  }
  float mx = -INFINITY;
  #pragma unroll
  for (int k=0;k<KNB;k++) mx = fmaxf(mx, acc[k]);
  mx = lrelu(mx);
  x1t[(size_t)pt*64 + lane] = mx;
  Xb[((size_t)((b<<12)+n))*192 + 0 + lane] = pack2(mx);
  float sq = mx*mx;
  #pragma unroll
  for (int off=32; off; off>>=1) sq += __shfl_xor(sq, off);
  if (lane==0) xx1[pt] = sq;
}

// ---- U/V precompute: Ut[n][o] = s*(WL@x_n); Vt[n][o] = s*((WR-WL)@x_n) + bias ----
__global__ __launch_bounds__(256) void k_uv(const float* __restrict__ xt, const float* __restrict__ WL,
    const float* __restrict__ WRd, const float* __restrict__ bf,
    float* __restrict__ Ut, float* __restrict__ Vt){
  __shared__ float xs[4][64];
  int wid = threadIdx.x>>6, lane = threadIdx.x&63;
  int pt = blockIdx.x*4 + wid;
  xs[wid][lane] = xt[(size_t)pt*64 + lane];
  __syncthreads();
  float U = 0.f, V = bf[lane];
  #pragma unroll
  for (int cb=0;cb<16;cb++){
    float4 wl = ((const float4*)WL)[cb*64+lane];
    float4 wr = ((const float4*)WRd)[cb*64+lane];
    float4 xv = *(const float4*)&xs[wid][cb*4];
    U=fmaf(wl.x,xv.x,U); U=fmaf(wl.y,xv.y,U); U=fmaf(wl.z,xv.z,U); U=fmaf(wl.w,xv.w,U);
    V=fmaf(wr.x,xv.x,V); V=fmaf(wr.y,xv.y,V); V=fmaf(wr.z,xv.z,V); V=fmaf(wr.w,xv.w,V);
  }
  Ut[(size_t)pt*64 + lane] = U;
  Vt[(size_t)pt*64 + lane] = V;
}

// ---- edge block 2: h = lrelu(U3[m_k]+V3[n]) (gather), then conv4 + max ----
__global__ __launch_bounds__(256) void k_ec2(const float* __restrict__ Ut, const float* __restrict__ Vt,
    const int* __restrict__ idx, const float* __restrict__ W2T4, const float* __restrict__ bfb,
    float* __restrict__ xout, unsigned* __restrict__ Xb, float* __restrict__ xxout){
  __shared__ float H[4][KNB][64];
  int wid = threadIdx.x>>6, lane = threadIdx.x&63;
  int pt = blockIdx.x*4 + wid, b = pt>>12, n = pt&4095;
  const float* Ub = Ut + (((size_t)b)<<12)*64;
  float Vv = Vt[(size_t)pt*64 + lane];
  int mr[KNB];
  const int4* ip4 = (const int4*)(idx + (size_t)pt*KNB);
  #pragma unroll
  for (int q=0;q<5;q++){ int4 t = ip4[q]; mr[q*4+0]=t.x; mr[q*4+1]=t.y; mr[q*4+2]=t.z; mr[q*4+3]=t.w; }
  #pragma unroll
  for (int k=0;k<KNB;k++) H[wid][k][lane] = lrelu(Ub[(size_t)mr[k]*64 + lane] + Vv);
  __syncthreads();
  float acc[KNB];
  #pragma unroll
  for (int k=0;k<KNB;k++) acc[k] = bfb[lane];
  for (int cb=0;cb<16;cb++){
    float4 wv = ((const float4*)W2T4)[cb*64+lane];
    #pragma unroll
    for (int k=0;k<KNB;k++){
      float4 a = *(const float4*)&H[wid][k][cb*4];
      acc[k]=fmaf(wv.x,a.x,acc[k]); acc[k]=fmaf(wv.y,a.y,acc[k]);
      acc[k]=fmaf(wv.z,a.z,acc[k]); acc[k]=fmaf(wv.w,a.w,acc[k]);
    }
  }
  float mx = -INFINITY;
  #pragma unroll
  for (int k=0;k<KNB;k++) mx = fmaxf(mx, acc[k]);
  mx = lrelu(mx);
  xout[(size_t)pt*64 + lane] = mx;
  Xb[((size_t)((b<<12)+n))*192 + 64 + lane] = pack2(mx);
  float sq = mx*mx;
  #pragma unroll
  for (int off=32;off;off>>=1) sq += __shfl_xor(sq,off);
  if (lane==0) xxout[pt] = sq;
}

// ---- edge block 3: x3[n] = lrelu(V5[n] + max_k U5[m_k]) -- pure gather+max ----
__global__ __launch_bounds__(256) void k_ec3(const float* __restrict__ Ut, const float* __restrict__ Vt,
    const int* __restrict__ idx, unsigned* __restrict__ Xb){
  int wid = threadIdx.x>>6, lane = threadIdx.x&63;
  int pt = blockIdx.x*4 + wid, b = pt>>12, n = pt&4095;
  const float* Ub = Ut + (((size_t)b)<<12)*64;
  int mr[KNB];
  const int4* ip4 = (const int4*)(idx + (size_t)pt*KNB);
  #pragma unroll
  for (int q=0;q<5;q++){ int4 t = ip4[q]; mr[q*4+0]=t.x; mr[q*4+1]=t.y; mr[q*4+2]=t.z; mr[q*4+3]=t.w; }
  float mx = -INFINITY;
  #pragma unroll
  for (int k=0;k<KNB;k++) mx = fmaxf(mx, Ub[(size_t)mr[k]*64 + lane]);
  mx = lrelu(mx + Vt[(size_t)pt*64 + lane]);
  Xb[((size_t)((b<<12)+n))*192 + 128 + lane] = pack2(mx);
}

// ---- KNN pairwise kernel: pd = fenc(fma(2,dot,-xx_n) - xx_m), 128x128 tile ----
// Also emits per-(row, 64-col-chunk) max cmax[b][q][64] (fenc'd) for filtered top-k.
__global__ __launch_bounds__(256) void k_knn_gemm(const float* __restrict__ xt, const float* __restrict__ xx,
                          unsigned* __restrict__ pd, unsigned* __restrict__ cmax, int q0, int S){
  __shared__ float As[32][132];
  __shared__ float Bs[32][132];
  int tid = threadIdx.x;
  int bx = blockIdx.x, by = blockIdx.y, b = blockIdx.z;
  const float* xb = xt + (size_t)b*N_PTS*64;
  int u = tid&15, v = tid>>4;
  float acc[8][8];
  #pragma unroll
  for (int i=0;i<8;i++)
    #pragma unroll
    for (int j=0;j<8;j++) acc[i][j]=0.f;
  for (int kc=0;kc<2;kc++){
    #pragma unroll
    for (int p=0;p<4;p++){
      int row = (tid>>3) + p*32, c8 = tid&7;
      float4 av = *(const float4*)&xb[(size_t)(q0 + by*128 + row)*64 + kc*32 + c8*4];
      As[c8*4+0][row]=av.x; As[c8*4+1][row]=av.y; As[c8*4+2][row]=av.z; As[c8*4+3][row]=av.w;
      float4 bv = *(const float4*)&xb[(size_t)(bx*128 + row)*64 + kc*32 + c8*4];
      Bs[c8*4+0][row]=bv.x; Bs[c8*4+1][row]=bv.y; Bs[c8*4+2][row]=bv.z; Bs[c8*4+3][row]=bv.w;
    }
    __syncthreads();
    #pragma unroll 4
    for (int k=0;k<32;k++){
      float4 a0 = *(const float4*)&As[k][u*4];
      float4 a1 = *(const float4*)&As[k][64+u*4];
      float4 b0 = *(const float4*)&Bs[k][v*4];
      float4 b1 = *(const float4*)&Bs[k][64+v*4];
      float a[8] = {a0.x,a0.y,a0.z,a0.w,a1.x,a1.y,a1.z,a1.w};
      float bb[8] = {b0.x,b0.y,b0.z,b0.w,b1.x,b1.y,b1.z,b1.w};
      #pragma unroll
      for (int i=0;i<8;i++)
        #pragma unroll
        for (int j=0;j<8;j++)
          acc[i][j] = fmaf(a[i], bb[j], acc[i][j]);
    }
    __syncthreads();
  }
  float xn[8], xm[8];
  #pragma unroll
  for (int i=0;i<8;i++){
    int ri = (i<4)? u*4+i : 64+u*4+(i-4);
    xn[i] = xx[b*N_PTS + q0 + by*128 + ri];
  }
  #pragma unroll
  for (int j=0;j<8;j++){
    int cj = (j<4)? v*4+j : 64+v*4+(j-4);
    xm[j] = xx[b*N_PTS + bx*128 + cj];
  }
  float* red = &Bs[0][0];   // reuse as [128 rows][16 v][2 halves] = 16KB
  #pragma unroll
  for (int i=0;i<8;i++){
    int rl = (i<4)? u*4+i : 64+u*4+(i-4);
    unsigned* dst = pd + ((size_t)(b*S + by*128 + rl))*N_PTS + bx*128;
    float f[8];
    #pragma unroll
    for (int j=0;j<8;j++) f[j] = fmaf(2.f,acc[i][j],-xn[i]) - xm[j];
    uint4 o0 = make_uint4(fenc(f[0]),fenc(f[1]),fenc(f[2]),fenc(f[3]));
    uint4 o1 = make_uint4(fenc(f[4]),fenc(f[5]),fenc(f[6]),fenc(f[7]));
    *(uint4*)&dst[v*4] = o0;
    *(uint4*)&dst[64+v*4] = o1;
    float m0 = fmaxf(fmaxf(f[0],f[1]), fmaxf(f[2],f[3]));
    float m1 = fmaxf(fmaxf(f[4],f[5]), fmaxf(f[6],f[7]));
    red[rl*32 + v*2 + 0] = m0;
    red[rl*32 + v*2 + 1] = m1;
  }
  __syncthreads();
  {
    int rr = tid & 127, hh = tid >> 7;
    float m = red[rr*32 + hh];
    #pragma unroll
    for (int v2=1; v2<16; v2++) m = fmaxf(m, red[rr*32 + v2*2 + hh]);
    cmax[((size_t)b*N_PTS + q0 + by*128 + rr)*64 + bx*2 + hh] = fenc(m);
  }
}

__device__ __forceinline__ unsigned bitsort_u32(unsigned v, int lane){
  #pragma unroll
  for (int k=2;k<=64;k<<=1){
    #pragma unroll
    for (int j=k>>1;j>0;j>>=1){
      unsigned o = (unsigned)__shfl_xor((int)v, j);
      bool takeMax = (((lane & j) != 0) == ((lane & k) == 0));
      unsigned mx = v>o?v:o, mn = v<o?v:o;
      v = takeMax ? mx : mn;
    }
  }
  return v;   // ascending by lane
}

// ---- filtered top-20: chunk-max prefilter + streaming candidate selection ----
__global__ __launch_bounds__(256,4) void k_topk20(const unsigned* __restrict__ pdbuf,
        const unsigned* __restrict__ cmax, int* __restrict__ idxout, int q0, int sshift){
  __shared__ unsigned long long cand[4][64];
  int wid = threadIdx.x>>6, lane = threadIdx.x&63;
  int gw = blockIdx.x*4 + wid;
  int S = 1 << sshift;
  int b = gw >> sshift, i = gw & (S-1);
  const unsigned* row = pdbuf + ((size_t)b*S + i)*N_PTS;
  unsigned cm = cmax[((size_t)b*N_PTS + q0 + i)*64 + lane];
  unsigned T = (unsigned)__shfl((int)bitsort_u32(cm, lane), 44);
  unsigned long long qual = __ballot(cm >= T);
  unsigned lmax = 0u;
  for (int c=0;c<64;c++){
    if (!((qual>>c)&1ull)) continue;
    unsigned vv = row[c*64 + lane];
    lmax = lmax > vv ? lmax : vv;
  }
  unsigned T2 = (unsigned)__shfl((int)bitsort_u32(lmax, lane), 44);
  int base = 0;
  unsigned long long below = (1ull<<lane) - 1ull;
  for (int c=0;c<64;c++){
    if (!((qual>>c)&1ull)) continue;
    unsigned vv = row[c*64 + lane];
    bool isc = vv >= T2;
    unsigned long long mb = __ballot(isc);
    int pos = base + __popcll(mb & below);
    if (isc && pos < 64){
      int m = c*64 + lane;
      cand[wid][pos] = (((unsigned long long)vv)<<12) | (unsigned)(4095-m);
    }
    base += __popcll(mb);
  }
  unsigned long long K;
  if (base <= 64){
    unsigned long long kv = (lane < base) ? cand[wid][lane] : 0ull;
    #pragma unroll
    for (int k=2;k<=64;k<<=1){
      #pragma unroll
      for (int j=k>>1;j>0;j>>=1){
        unsigned long long o = __shfl_xor(kv, j);
        bool takeMax = (((lane & j) != 0) == ((lane & k) == 0));
        unsigned long long mx = kv>o?kv:o, mn = kv<o?kv:o;
        kv = takeMax ? mx : mn;
      }
    }
    K = __shfl(kv, 44);
  } else {
    K = 0ull;
    for (int bb2=43; bb2>=0; --bb2){
      unsigned long long cnd = K | (1ull<<bb2);
      int lc = 0;
      for (int c=0;c<64;c++){
        if (!((qual>>c)&1ull)) continue;
        unsigned vv = row[c*64 + lane];
        int m = c*64 + lane;
        unsigned long long key = (((unsigned long long)vv)<<12) | (unsigned)(4095-m);
        if (key >= cnd) lc++;
      }
      #pragma unroll
      for (int off=32; off; off>>=1) lc += __shfl_xor(lc, off);
      if (lc >= KNB) K = cnd;
    }
  }
  int eb = 0;
  int* dst = idxout + ((size_t)b*N_PTS + (q0+i))*KNB;
  for (int c=0;c<64;c++){
    if (!((qual>>c)&1ull)) continue;
    unsigned vv = row[c*64 + lane];
    int m = c*64 + lane;
    unsigned long long key = (((unsigned long long)vv)<<12) | (unsigned)(4095-m);
    bool sel = key >= K;
    unsigned long long mb = __ballot(sel);
    int pos = eb + __popcll(mb & below);
    if (sel) dst[pos] = m;
    eb += __popcll(mb);
  }
}

// ---- split-bf16 MFMA GEMM: D[pt][o] = act( sum_c Xp[pt][c] * Wp[o][c] + bias ) ----
// A operand = packed activations [16384][lda]; B operand = packed weights [Opad][ldb].
// STORE: 0 = column-max only (gmax, fenc'd atomic), 1 = packed u32 store [pt][ldo], 2 = f32 store to d_out (O=13)
template<int STORE, int RELU>
__global__ __launch_bounds__(512) void k_mgemm(const unsigned* __restrict__ Ap, int lda,
        const unsigned* __restrict__ Bp, int ldb,
        const float* __restrict__ bias, int perBatch,
        unsigned* __restrict__ Cp, int ldo, float* __restrict__ Cf,
        unsigned* __restrict__ gmax, int O, int K){
  __shared__ short Ah[128][40];
  __shared__ short Al[128][40];
  __shared__ short Bh[128][40];
  __shared__ short Bl[128][40];
  int tid = threadIdx.x;
  int bx = blockIdx.x, by = blockIdx.y, bz = blockIdx.z;
  int w = tid>>6, lane = tid&63;
  int r15 = lane&15, rb = lane>>4;
  int mibase = (w&3)*32, oibase = (w>>2)*64;
  f32x4 acc[2][4];
  #pragma unroll
  for (int mi=0;mi<2;mi++)
    #pragma unroll
    for (int oi=0;oi<4;oi++) acc[mi][oi] = (f32x4){0.f,0.f,0.f,0.f};
  int srow = tid>>2, sc = (tid&3)*8;
  const unsigned* pa = Ap + ((size_t)((bz<<12) + bx*128 + srow))*lda + sc;
  const unsigned* pb = Bp + (size_t)(by*128 + srow)*ldb + sc;
  for (int kt=0; kt<K; kt+=32){
    if (kt) __syncthreads();
    uint4 a0 = *(const uint4*)(pa+kt);
    uint4 a1 = *(const uint4*)(pa+kt+4);
    uint4 b0 = *(const uint4*)(pb+kt);
    uint4 b1 = *(const uint4*)(pb+kt+4);
    short8v h, l;
    cvt8(a0,a1,h,l);
    *(short8v*)&Ah[srow][sc] = h; *(short8v*)&Al[srow][sc] = l;
    cvt8(b0,b1,h,l);
    *(short8v*)&Bh[srow][sc] = h; *(short8v*)&Bl[srow][sc] = l;
    __syncthreads();
    short8v ah[2], al[2];
    #pragma unroll
    for (int mi=0;mi<2;mi++){
      ah[mi] = *(const short8v*)&Ah[mibase+mi*16+r15][rb*8];
      al[mi] = *(const short8v*)&Al[mibase+mi*16+r15][rb*8];
    }
    #pragma unroll
    for (int oi=0;oi<4;oi++){
      short8v bh = *(const short8v*)&Bh[oibase+oi*16+r15][rb*8];
      short8v bl = *(const short8v*)&Bl[oibase+oi*16+r15][rb*8];
      #pragma unroll
      for (int mi=0;mi<2;mi++){
        acc[mi][oi] = __builtin_amdgcn_mfma_f32_16x16x32_bf16(ah[mi], bh, acc[mi][oi], 0,0,0);
        acc[mi][oi] = __builtin_amdgcn_mfma_f32_16x16x32_bf16(ah[mi], bl, acc[mi][oi], 0,0,0);
        acc[mi][oi] = __builtin_amdgcn_mfma_f32_16x16x32_bf16(al[mi], bh, acc[mi][oi], 0,0,0);
      }
    }
  }
  // epilogue: D row = mibase+mi*16+rb*4+r (point), col = oibase+oi*16+r15 (channel)
  #pragma unroll
  for (int oi=0;oi<4;oi++){
    int o = by*128 + oibase + oi*16 + r15;
    float bv = 0.f;
    if (bias != nullptr) bv = perBatch ? bias[bz*O + o] : bias[o];
    float cmx = -INFINITY;
    #pragma unroll
    for (int mi=0;mi<2;mi++){
      #pragma unroll
      for (int r=0;r<4;r++){
        float y = acc[mi][oi][r] + bv;
        if (RELU) y = lrelu(y);
        if (STORE==1){
          int pt = bx*128 + mibase + mi*16 + rb*4 + r;
          Cp[((size_t)((bz<<12)+pt))*ldo + o] = pack2(y);
        } else if (STORE==2){
          if (o < 13){
            int pt = bx*128 + mibase + mi*16 + rb*4 + r;
            Cf[(((size_t)(bz*13 + o))<<12) + pt] = y;
          }
        } else {
          cmx = fmaxf(cmx, y);
        }
      }
    }
    if (STORE==0){
      cmx = fmaxf(cmx, __shfl_xor(cmx,16));
      cmx = fmaxf(cmx, __shfl_xor(cmx,32));
      if (rb==0) atomicMax(&gmax[bz*1024 + o], fenc(cmx));
    }
  }
}

// bias7[b][o] = sum_{c<1024} Wf7[o][c]*g[b][c] + bf7[o]
__global__ __launch_bounds__(256) void k_gemv7(const float* __restrict__ Wf7, const float* __restrict__ bf7,
                        const unsigned* __restrict__ g, float* __restrict__ bias7){
  int wid = threadIdx.x>>6, lane = threadIdx.x&63;
  int o = blockIdx.x*4 + wid, b = blockIdx.y;
  const float* wr = Wf7 + (size_t)o*1216;
  const unsigned* gb = g + b*1024;
  float acc = 0.f;
  for (int c = lane; c < 1024; c += 64)
    acc = fmaf(wr[c], fdec(gb[c]), acc);
  #pragma unroll
  for (int off=32; off; off>>=1) acc += __shfl_xor(acc, off);
  if (lane==0) bias7[b*512+o] = acc + bf7[o];
}

extern "C" void kernel_launch(void* const* d_in, const int* in_sizes, int n_in,
                              void* d_out, int out_size, void* d_ws, size_t ws_size,
                              hipStream_t stream){
  const float* x  = (const float*)d_in[0];
  const float* W1 = (const float*)d_in[1];
  const float* W2 = (const float*)d_in[2];
  const float* W3 = (const float*)d_in[3];
  const float* W4 = (const float*)d_in[4];
  const float* W5 = (const float*)d_in[5];
  const float* W6 = (const float*)d_in[6];
  const float* W7 = (const float*)d_in[7];
  const float* W8 = (const float*)d_in[8];
  const float* W9 = (const float*)d_in[9];
  const float* bn1 = (const float*)d_in[10];
  const float* bn2 = (const float*)d_in[11];
  const float* bn3 = (const float*)d_in[12];
  const float* bn4 = (const float*)d_in[13];
  const float* bn5 = (const float*)d_in[14];
  const float* bn6 = (const float*)d_in[15];
  const float* bn7 = (const float*)d_in[16];
  const float* bn8 = (const float*)d_in[17];

  float* ws = (float*)d_ws;
  size_t off = 0;
  auto alloc = [&](size_t nf){ float* p = ws + off; off += (nf + 63) & ~(size_t)63; return p; };
  float* Wf7 = alloc((size_t)512*1216); float* bf7 = alloc(512);
  float* bf6 = alloc(1024);
  float* bf8 = alloc(256);
  unsigned* Wb6p = (unsigned*)alloc((size_t)1024*192);
  unsigned* Wb7p = (unsigned*)alloc((size_t)512*192);
  unsigned* Wb8p = (unsigned*)alloc((size_t)256*512);
  unsigned* Wb9p = (unsigned*)alloc((size_t)128*256);
  float* W1dT4 = alloc(8*64);     float* bf1 = alloc(64);
  float* W2T4  = alloc(64*64);    float* bf2 = alloc(64);
  float* W3LT4 = alloc(64*64);    float* W3RdT4 = alloc(64*64); float* bf3 = alloc(64);
  float* W4T4  = alloc(64*64);    float* bf4 = alloc(64);
  float* W5LT4 = alloc(64*64);    float* W5RdT4 = alloc(64*64); float* bf5 = alloc(64);
  float* U1  = alloc(4*KNB*64);
  float* x1t = alloc((size_t)4*N_PTS*64);
  float* x2t = alloc((size_t)4*N_PTS*64);
  float* Ut3 = alloc((size_t)4*N_PTS*64);
  float* Vt3 = alloc((size_t)4*N_PTS*64);
  float* Ut5 = alloc((size_t)4*N_PTS*64);
  float* Vt5 = alloc((size_t)4*N_PTS*64);
  unsigned* Xb = (unsigned*)alloc((size_t)4*N_PTS*192);   // packed activations [n][192]
  float* xx1 = alloc(4*N_PTS);
  float* xx2 = alloc(4*N_PTS);
  int* idx1 = (int*)alloc((size_t)4*N_PTS*KNB);
  int* idx2 = (int*)alloc((size_t)4*N_PTS*KNB);
  unsigned* genc = (unsigned*)alloc(4*1024);
  float* bias7 = alloc(4*512);
  unsigned* h8p = (unsigned*)alloc((size_t)4*N_PTS*256);  // packed conv8 out [n][256]
  unsigned* cmaxb = (unsigned*)alloc((size_t)4*N_PTS*64);
  // pdbuf takes the remainder; pick largest power-of-two stripe S (<=4096, >=512) that fits
  size_t remaining = (ws_size / 4 > off) ? (ws_size / 4 - off) : 0;
  int S = 4096;
  while (S > 512 && (size_t)4*S*N_PTS + 1024 > remaining) S >>= 1;
  int sshift = 31 - __builtin_clz(S);
  unsigned* pdbuf = (unsigned*)alloc((size_t)4*S*N_PTS);   // encoded u32; reused as h7p (needs 32MB)
  unsigned* h7p = pdbuf;                                    // packed conv7 out [n][512]

  // prep (every call: deterministic)
  k_scale_rows<<<(512*1216+255)/256,256,0,stream>>>(W7, bn7, Wf7, bf7, 512, 1216);
  k_pack_w<<<(1024*192+255)/256,256,0,stream>>>(W6, 192, 0, bn6, 1024, 192, 1024, Wb6p, bf6);
  k_pack_w<<<(512*192+255)/256,256,0,stream>>>(W7, 1216, 1024, bn7, 512, 192, 512, Wb7p, nullptr);
  k_pack_w<<<(256*512+255)/256,256,0,stream>>>(W8, 512, 0, bn8, 256, 512, 256, Wb8p, bf8);
  k_pack_w<<<(128*256+255)/256,256,0,stream>>>(W9, 256, 0, nullptr, 13, 256, 128, Wb9p, nullptr);
  k_build_T4<<<8,64,0,stream>>>(W1, 12, bn1, W1dT4, bf1, 0, 6, 6);     // (W1R - W1L), pad to 8
  k_build_T4<<<64,64,0,stream>>>(W2, 64, bn2, W2T4, bf2, 0, 0, 64);
  k_build_T4<<<64,64,0,stream>>>(W3, 128, bn3, W3LT4, bf3, 0, 0, 64);
  k_build_T4<<<64,64,0,stream>>>(W3, 128, bn3, W3RdT4, nullptr, 0, 64, 64);  // (W3R-W3L)*s
  k_build_T4<<<64,64,0,stream>>>(W4, 64, bn4, W4T4, bf4, 0, 0, 64);
  k_build_T4<<<64,64,0,stream>>>(W5, 128, bn5, W5LT4, bf5, 0, 0, 64);
  k_build_T4<<<64,64,0,stream>>>(W5, 128, bn5, W5RdT4, nullptr, 0, 64, 64);  // (W5R-W5L)*s
  k_build_U1<<<dim3(KNB,4),64,0,stream>>>(x, W1, bn1, U1);
  k_init_g<<<16,256,0,stream>>>(genc);

  // edge block 1 (neighbors = points 0..19 since KNN input is empty slice)
  k_edge1<<<4096,256,0,stream>>>(x, U1, W1dT4, bf1, W2T4, bf2, x1t, Xb, xx1);

  int nstripe = N_PTS / S;
  // KNN on x1
  for (int s=0;s<nstripe;s++){
    k_knn_gemm<<<dim3(32,S/128,4),256,0,stream>>>(x1t, xx1, pdbuf, cmaxb, s*S, S);
    k_topk20<<<S,256,0,stream>>>(pdbuf, cmaxb, idx1, s*S, sshift);
  }

  // edge block 2: U3/V3 then gather+conv4
  k_uv<<<4096,256,0,stream>>>(x1t, W3LT4, W3RdT4, bf3, Ut3, Vt3);
  k_ec2<<<4096,256,0,stream>>>(Ut3, Vt3, idx1, W4T4, bf4, x2t, Xb, xx2);

  // KNN on x2
  for (int s=0;s<nstripe;s++){
    k_knn_gemm<<<dim3(32,S/128,4),256,0,stream>>>(x2t, xx2, pdbuf, cmaxb, s*S, S);
    k_topk20<<<S,256,0,stream>>>(pdbuf, cmaxb, idx2, s*S, sshift);
  }

  // edge block 3: U5/V5 then pure gather+max
  k_uv<<<4096,256,0,stream>>>(x2t, W5LT4, W5RdT4, bf5, Ut5, Vt5);
  k_ec3<<<4096,256,0,stream>>>(Ut5, Vt5, idx2, Xb);

  // conv6 (1024x192) -> only column max g (MFMA, gmax atomic)
  k_mgemm<0,1><<<dim3(32,8,4),512,0,stream>>>(Xb, 192, Wb6p, 192, bf6, 0, nullptr, 0, nullptr, genc, 1024, 192);
  // bias7[b][o] = W7[:, :1024] @ g + bf7
  k_gemv7<<<dim3(128,4),256,0,stream>>>(Wf7, bf7, genc, bias7);
  // conv7: W7[:, 1024:1216] @ X + bias7 (per batch) -> packed h7
  k_mgemm<1,1><<<dim3(32,4,4),512,0,stream>>>(Xb, 192, Wb7p, 192, bias7, 1, h7p, 512, nullptr, nullptr, 512, 192);
  // conv8: 256x512 -> packed h8
  k_mgemm<1,1><<<dim3(32,2,4),512,0,stream>>>(h7p, 512, Wb8p, 512, bf8, 0, h8p, 256, nullptr, nullptr, 256, 512);
  // conv9: 13x256 (padded to 128), no bias/relu -> d_out f32
  k_mgemm<2,0><<<dim3(32,1,4),512,0,stream>>>(h8p, 256, Wb9p, 256, nullptr, 0, nullptr, 0, (float*)d_out, nullptr, 13, 256);
}

// Round 9
// 616.470 us; speedup vs baseline: 2.0601x; 1.1194x over previous
//
#include <hip/hip_runtime.h>
#include <math.h>

#define N_PTS 4096
#define BATCH 4
#define KNB 20

typedef __attribute__((ext_vector_type(8))) short short8v;   // 8 bf16
typedef __attribute__((ext_vector_type(4))) float f32x4;

__device__ __forceinline__ float lrelu(float v){ return fmaxf(v, 0.2f*v); }
__device__ __forceinline__ unsigned fenc(float f){ unsigned u=__float_as_uint(f); return (u&0x80000000u)?~u:(u|0x80000000u); }
__device__ __forceinline__ float fdec(unsigned k){ return (k&0x80000000u)?__uint_as_float(k&0x7fffffffu):__uint_as_float(~k); }

// split f32 -> packed (bf16_hi << 16) | bf16_lo,  v ~= hi + lo, err ~2^-18 rel
__device__ __forceinline__ unsigned pack2(float v){
  unsigned u = __float_as_uint(v);
  unsigned hi = (u + 0x7fffu + ((u>>16)&1u)) >> 16;
  float hf = __uint_as_float(hi<<16);
  unsigned u2 = __float_as_uint(v - hf);
  unsigned lo = (u2 + 0x7fffu + ((u2>>16)&1u)) >> 16;
  return (hi<<16) | lo;
}
__device__ __forceinline__ void cvt8(uint4 v0, uint4 v1, short8v& h, short8v& l){
  unsigned a0=v0.x,a1=v0.y,a2=v0.z,a3=v0.w,a4=v1.x,a5=v1.y,a6=v1.z,a7=v1.w;
  h[0]=(short)(a0>>16); l[0]=(short)(a0&0xffffu);
  h[1]=(short)(a1>>16); l[1]=(short)(a1&0xffffu);
  h[2]=(short)(a2>>16); l[2]=(short)(a2&0xffffu);
  h[3]=(short)(a3>>16); l[3]=(short)(a3&0xffffu);
  h[4]=(short)(a4>>16); l[4]=(short)(a4&0xffffu);
  h[5]=(short)(a5>>16); l[5]=(short)(a5&0xffffu);
  h[6]=(short)(a6>>16); l[6]=(short)(a6&0xffffu);
  h[7]=(short)(a7>>16); l[7]=(short)(a7&0xffffu);
}

// ---- prep: fold BN scale into weights (f32, for gemv7) ----
__global__ void k_scale_rows(const float* __restrict__ W, const float* __restrict__ bn,
                             float* __restrict__ Wf, float* __restrict__ bias, int O, int C){
  int i = blockIdx.x*256 + threadIdx.x;
  if (i >= O*C) return;
  int o = i / C;
  float s = bn[o] / sqrtf(bn[3*O+o] + 1e-5f);
  Wf[i] = W[i]*s;
  if (i % C == 0) bias[o] = bn[O+o] - s*bn[2*O+o];
}

// pack scaled weights to (hi|lo) u32 [Opad][C]; rows >= O zero-padded
__global__ void k_pack_w(const float* __restrict__ W, int ldw, int c0,
                         const float* __restrict__ bn, int O, int C, int Opad,
                         unsigned* __restrict__ out, float* __restrict__ bias){
  int i = blockIdx.x*256 + threadIdx.x;
  if (i >= Opad*C) return;
  int o = i / C, c = i - o*C;
  float v = 0.f;
  if (o < O){
    float s = 1.f;
    if (bn != nullptr){
      s = bn[o] / sqrtf(bn[3*O+o] + 1e-5f);
      if (bias != nullptr && c == 0) bias[o] = bn[O+o] - s*bn[2*O+o];
    }
    v = W[o*ldw + c0 + c] * s;
  }
  out[i] = pack2(v);
}

// transposed float4-chunk layout: dst[(c/4)*256 + o*4 + c%4], O=64 fixed
__global__ void k_build_T4(const float* __restrict__ W, int ldw, const float* __restrict__ bn,
                           float* __restrict__ dst, float* __restrict__ bias,
                           int c0, int diffoff, int Csrc){
  int o = threadIdx.x, c = blockIdx.x;
  float s = bn[o] / sqrtf(bn[192+o] + 1e-5f);
  float val = 0.f;
  if (c < Csrc){
    val = W[o*ldw + c0 + c];
    if (diffoff) val = W[o*ldw + c0 + diffoff + c] - val;
    val *= s;
  }
  dst[(c>>2)*256 + o*4 + (c&3)] = val;
  if (bias != nullptr && c==0) bias[o] = bn[64+o] - s*bn[128+o];
}

// U1[b][k][o] = sum_{c<6} s_o*W1[o][c]*x[b][c][k]  (first-KNN neighbors are points 0..19)
__global__ void k_build_U1(const float* __restrict__ x, const float* __restrict__ W1,
                           const float* __restrict__ bn, float* __restrict__ U1){
  int o = threadIdx.x, k = blockIdx.x, b = blockIdx.y;
  float s = bn[o] / sqrtf(bn[192+o] + 1e-5f);
  float acc = 0.f;
  #pragma unroll
  for (int c=0;c<6;c++) acc += W1[o*12+c] * x[(b*6+c)*N_PTS + k];
  U1[(b*KNB+k)*64 + o] = acc*s;
}

__global__ void k_init_g(unsigned* g){ g[blockIdx.x*256+threadIdx.x] = fenc(-INFINITY); }

// ---- edge block 1 (trivial neighbors 0..19) : conv1 + conv2 + maxpool ----
__global__ __launch_bounds__(256) void k_edge1(const float* __restrict__ x, const float* __restrict__ U1,
                        const float* __restrict__ W1dT4, const float* __restrict__ bf1,
                        const float* __restrict__ W2T4, const float* __restrict__ bf2,
                        float* __restrict__ x1t, unsigned* __restrict__ Xb, float* __restrict__ xx1){
  __shared__ float hb[4][KNB][64];
  int wid = threadIdx.x>>6, lane = threadIdx.x&63;
  int pt = blockIdx.x*4 + wid, b = pt>>12, n = pt&4095;
  float xv[8];
  #pragma unroll
  for (int c=0;c<6;c++) xv[c] = x[(b*6+c)*N_PTS + n];
  xv[6]=0.f; xv[7]=0.f;
  float w = bf1[lane];
  #pragma unroll
  for (int cb=0;cb<2;cb++){
    float4 wv = ((const float4*)W1dT4)[cb*64+lane];
    w = fmaf(wv.x, xv[cb*4+0], w); w = fmaf(wv.y, xv[cb*4+1], w);
    w = fmaf(wv.z, xv[cb*4+2], w); w = fmaf(wv.w, xv[cb*4+3], w);
  }
  const float* Ub = U1 + b*KNB*64;
  #pragma unroll
  for (int k=0;k<KNB;k++) hb[wid][k][lane] = lrelu(Ub[k*64+lane] + w);
  __syncthreads();
  float acc[KNB];
  #pragma unroll
  for (int k=0;k<KNB;k++) acc[k] = bf2[lane];
  for (int cb=0;cb<16;cb++){
    float4 wv = ((const float4*)W2T4)[cb*64+lane];
    #pragma unroll
    for (int k=0;k<KNB;k++){
      float4 a = *(const float4*)&hb[wid][k][cb*4];
      acc[k]=fmaf(wv.x,a.x,acc[k]); acc[k]=fmaf(wv.y,a.y,acc[k]);
      acc[k]=fmaf(wv.z,a.z,acc[k]); acc[k]=fmaf(wv.w,a.w,acc[k]);
    }
  }
  float mx = -INFINITY;
  #pragma unroll
  for (int k=0;k<KNB;k++) mx = fmaxf(mx, acc[k]);
  mx = lrelu(mx);
  x1t[(size_t)pt*64 + lane] = mx;
  Xb[((size_t)((b<<12)+n))*192 + 0 + lane] = pack2(mx);
  float sq = mx*mx;
  #pragma unroll
  for (int off=32; off; off>>=1) sq += __shfl_xor(sq, off);
  if (lane==0) xx1[pt] = sq;
}

// ---- U/V precompute: Ut[n][o] = s*(WL@x_n); Vt[n][o] = s*((WR-WL)@x_n) + bias ----
__global__ __launch_bounds__(256) void k_uv(const float* __restrict__ xt, const float* __restrict__ WL,
    const float* __restrict__ WRd, const float* __restrict__ bf,
    float* __restrict__ Ut, float* __restrict__ Vt){
  __shared__ float xs[4][64];
  int wid = threadIdx.x>>6, lane = threadIdx.x&63;
  int pt = blockIdx.x*4 + wid;
  xs[wid][lane] = xt[(size_t)pt*64 + lane];
  __syncthreads();
  float U = 0.f, V = bf[lane];
  #pragma unroll
  for (int cb=0;cb<16;cb++){
    float4 wl = ((const float4*)WL)[cb*64+lane];
    float4 wr = ((const float4*)WRd)[cb*64+lane];
    float4 xv = *(const float4*)&xs[wid][cb*4];
    U=fmaf(wl.x,xv.x,U); U=fmaf(wl.y,xv.y,U); U=fmaf(wl.z,xv.z,U); U=fmaf(wl.w,xv.w,U);
    V=fmaf(wr.x,xv.x,V); V=fmaf(wr.y,xv.y,V); V=fmaf(wr.z,xv.z,V); V=fmaf(wr.w,xv.w,V);
  }
  Ut[(size_t)pt*64 + lane] = U;
  Vt[(size_t)pt*64 + lane] = V;
}

// ---- edge block 2: h = lrelu(U3[m_k]+V3[n]) (gather), then conv4 + max ----
__global__ __launch_bounds__(256) void k_ec2(const float* __restrict__ Ut, const float* __restrict__ Vt,
    const int* __restrict__ idx, const float* __restrict__ W2T4, const float* __restrict__ bfb,
    float* __restrict__ xout, unsigned* __restrict__ Xb, float* __restrict__ xxout){
  __shared__ float H[4][KNB][64];
  int wid = threadIdx.x>>6, lane = threadIdx.x&63;
  int pt = blockIdx.x*4 + wid, b = pt>>12, n = pt&4095;
  const float* Ub = Ut + (((size_t)b)<<12)*64;
  float Vv = Vt[(size_t)pt*64 + lane];
  int mr[KNB];
  const int4* ip4 = (const int4*)(idx + (size_t)pt*KNB);
  #pragma unroll
  for (int q=0;q<5;q++){ int4 t = ip4[q]; mr[q*4+0]=t.x; mr[q*4+1]=t.y; mr[q*4+2]=t.z; mr[q*4+3]=t.w; }
  #pragma unroll
  for (int k=0;k<KNB;k++) H[wid][k][lane] = lrelu(Ub[(size_t)mr[k]*64 + lane] + Vv);
  __syncthreads();
  float acc[KNB];
  #pragma unroll
  for (int k=0;k<KNB;k++) acc[k] = bfb[lane];
  for (int cb=0;cb<16;cb++){
    float4 wv = ((const float4*)W2T4)[cb*64+lane];
    #pragma unroll
    for (int k=0;k<KNB;k++){
      float4 a = *(const float4*)&H[wid][k][cb*4];
      acc[k]=fmaf(wv.x,a.x,acc[k]); acc[k]=fmaf(wv.y,a.y,acc[k]);
      acc[k]=fmaf(wv.z,a.z,acc[k]); acc[k]=fmaf(wv.w,a.w,acc[k]);
    }
  }
  float mx = -INFINITY;
  #pragma unroll
  for (int k=0;k<KNB;k++) mx = fmaxf(mx, acc[k]);
  mx = lrelu(mx);
  xout[(size_t)pt*64 + lane] = mx;
  Xb[((size_t)((b<<12)+n))*192 + 64 + lane] = pack2(mx);
  float sq = mx*mx;
  #pragma unroll
  for (int off=32;off;off>>=1) sq += __shfl_xor(sq,off);
  if (lane==0) xxout[pt] = sq;
}

// ---- edge block 3: x3[n] = lrelu(V5[n] + max_k U5[m_k]) -- pure gather+max ----
__global__ __launch_bounds__(256) void k_ec3(const float* __restrict__ Ut, const float* __restrict__ Vt,
    const int* __restrict__ idx, unsigned* __restrict__ Xb){
  int wid = threadIdx.x>>6, lane = threadIdx.x&63;
  int pt = blockIdx.x*4 + wid, b = pt>>12, n = pt&4095;
  const float* Ub = Ut + (((size_t)b)<<12)*64;
  int mr[KNB];
  const int4* ip4 = (const int4*)(idx + (size_t)pt*KNB);
  #pragma unroll
  for (int q=0;q<5;q++){ int4 t = ip4[q]; mr[q*4+0]=t.x; mr[q*4+1]=t.y; mr[q*4+2]=t.z; mr[q*4+3]=t.w; }
  float mx = -INFINITY;
  #pragma unroll
  for (int k=0;k<KNB;k++) mx = fmaxf(mx, Ub[(size_t)mr[k]*64 + lane]);
  mx = lrelu(mx + Vt[(size_t)pt*64 + lane]);
  Xb[((size_t)((b<<12)+n))*192 + 128 + lane] = pack2(mx);
}

// ---- KNN distance via split-bf16 MFMA: pd = fenc(fma(2,dot,-xx_n) - xx_m) ----
// A and B operands both from packed Xb [n][192] at column offset coff.
// Emits per-(row, 64-col-chunk) max via shfl reduce (no LDS pass).
__global__ __launch_bounds__(512) void k_knn_mfma(const unsigned* __restrict__ Xp, int coff,
        const float* __restrict__ xx, unsigned* __restrict__ pd, unsigned* __restrict__ cmax,
        int q0, int S){
  __shared__ short Ah[128][40];
  __shared__ short Al[128][40];
  __shared__ short Bh[128][40];
  __shared__ short Bl[128][40];
  int tid = threadIdx.x;
  int bx = blockIdx.x, by = blockIdx.y, bz = blockIdx.z;
  int w = tid>>6, lane = tid&63;
  int r15 = lane&15, rb = lane>>4;
  int mibase = (w&3)*32, oibase = (w>>2)*64;
  f32x4 acc[2][4];
  #pragma unroll
  for (int mi=0;mi<2;mi++)
    #pragma unroll
    for (int oi=0;oi<4;oi++) acc[mi][oi] = (f32x4){0.f,0.f,0.f,0.f};
  int srow = tid>>2, sc = (tid&3)*8;
  const unsigned* pa = Xp + ((size_t)((bz<<12) + q0 + by*128 + srow))*192 + coff + sc;
  const unsigned* pb = Xp + ((size_t)((bz<<12) + bx*128 + srow))*192 + coff + sc;
  for (int kt=0; kt<64; kt+=32){
    if (kt) __syncthreads();
    uint4 a0 = *(const uint4*)(pa+kt);
    uint4 a1 = *(const uint4*)(pa+kt+4);
    uint4 b0 = *(const uint4*)(pb+kt);
    uint4 b1 = *(const uint4*)(pb+kt+4);
    short8v h, l;
    cvt8(a0,a1,h,l);
    *(short8v*)&Ah[srow][sc] = h; *(short8v*)&Al[srow][sc] = l;
    cvt8(b0,b1,h,l);
    *(short8v*)&Bh[srow][sc] = h; *(short8v*)&Bl[srow][sc] = l;
    __syncthreads();
    short8v ah[2], al[2];
    #pragma unroll
    for (int mi=0;mi<2;mi++){
      ah[mi] = *(const short8v*)&Ah[mibase+mi*16+r15][rb*8];
      al[mi] = *(const short8v*)&Al[mibase+mi*16+r15][rb*8];
    }
    #pragma unroll
    for (int oi=0;oi<4;oi++){
      short8v bh = *(const short8v*)&Bh[oibase+oi*16+r15][rb*8];
      short8v bl = *(const short8v*)&Bl[oibase+oi*16+r15][rb*8];
      #pragma unroll
      for (int mi=0;mi<2;mi++){
        acc[mi][oi] = __builtin_amdgcn_mfma_f32_16x16x32_bf16(ah[mi], bh, acc[mi][oi], 0,0,0);
        acc[mi][oi] = __builtin_amdgcn_mfma_f32_16x16x32_bf16(ah[mi], bl, acc[mi][oi], 0,0,0);
        acc[mi][oi] = __builtin_amdgcn_mfma_f32_16x16x32_bf16(al[mi], bh, acc[mi][oi], 0,0,0);
      }
    }
  }
  // epilogue: D row = query (mibase+mi*16+rb*4+r), col = mibase.. (oibase+oi*16+r15)
  float xm[4];
  #pragma unroll
  for (int oi=0;oi<4;oi++) xm[oi] = xx[(bz<<12) + bx*128 + oibase + oi*16 + r15];
  #pragma unroll
  for (int mi=0;mi<2;mi++){
    #pragma unroll
    for (int r=0;r<4;r++){
      int row = by*128 + mibase + mi*16 + rb*4 + r;
      float xn = xx[(bz<<12) + q0 + row];
      float f0 = fmaf(2.f, acc[mi][0][r], -xn) - xm[0];
      float f1 = fmaf(2.f, acc[mi][1][r], -xn) - xm[1];
      float f2 = fmaf(2.f, acc[mi][2][r], -xn) - xm[2];
      float f3 = fmaf(2.f, acc[mi][3][r], -xn) - xm[3];
      unsigned* dst = pd + ((size_t)(bz*S + row))*N_PTS + bx*128 + oibase;
      dst[ 0+r15] = fenc(f0);
      dst[16+r15] = fenc(f1);
      dst[32+r15] = fenc(f2);
      dst[48+r15] = fenc(f3);
      float m = fmaxf(fmaxf(f0,f1), fmaxf(f2,f3));
      m = fmaxf(m, __shfl_xor(m,1));
      m = fmaxf(m, __shfl_xor(m,2));
      m = fmaxf(m, __shfl_xor(m,4));
      m = fmaxf(m, __shfl_xor(m,8));
      if (r15 == 0)
        cmax[((size_t)(bz<<12) + q0 + row)*64 + bx*2 + (oibase>>6)] = fenc(m);
    }
  }
}

__device__ __forceinline__ unsigned bitsort_u32(unsigned v, int lane){
  #pragma unroll
  for (int k=2;k<=64;k<<=1){
    #pragma unroll
    for (int j=k>>1;j>0;j>>=1){
      unsigned o = (unsigned)__shfl_xor((int)v, j);
      bool takeMax = (((lane & j) != 0) == ((lane & k) == 0));
      unsigned mx = v>o?v:o, mn = v<o?v:o;
      v = takeMax ? mx : mn;
    }
  }
  return v;   // ascending by lane
}

// ---- filtered top-20: chunk-max prefilter + streaming candidate selection ----
__global__ __launch_bounds__(256,4) void k_topk20(const unsigned* __restrict__ pdbuf,
        const unsigned* __restrict__ cmax, int* __restrict__ idxout, int q0, int sshift){
  __shared__ unsigned long long cand[4][64];
  int wid = threadIdx.x>>6, lane = threadIdx.x&63;
  int gw = blockIdx.x*4 + wid;
  int S = 1 << sshift;
  int b = gw >> sshift, i = gw & (S-1);
  const unsigned* row = pdbuf + ((size_t)b*S + i)*N_PTS;
  unsigned cm = cmax[((size_t)b*N_PTS + q0 + i)*64 + lane];
  unsigned T = (unsigned)__shfl((int)bitsort_u32(cm, lane), 44);
  unsigned long long qual = __ballot(cm >= T);
  unsigned lmax = 0u;
  for (int c=0;c<64;c++){
    if (!((qual>>c)&1ull)) continue;
    unsigned vv = row[c*64 + lane];
    lmax = lmax > vv ? lmax : vv;
  }
  unsigned T2 = (unsigned)__shfl((int)bitsort_u32(lmax, lane), 44);
  int base = 0;
  unsigned long long below = (1ull<<lane) - 1ull;
  for (int c=0;c<64;c++){
    if (!((qual>>c)&1ull)) continue;
    unsigned vv = row[c*64 + lane];
    bool isc = vv >= T2;
    unsigned long long mb = __ballot(isc);
    int pos = base + __popcll(mb & below);
    if (isc && pos < 64){
      int m = c*64 + lane;
      cand[wid][pos] = (((unsigned long long)vv)<<12) | (unsigned)(4095-m);
    }
    base += __popcll(mb);
  }
  unsigned long long K;
  if (base <= 64){
    unsigned long long kv = (lane < base) ? cand[wid][lane] : 0ull;
    #pragma unroll
    for (int k=2;k<=64;k<<=1){
      #pragma unroll
      for (int j=k>>1;j>0;j>>=1){
        unsigned long long o = __shfl_xor(kv, j);
        bool takeMax = (((lane & j) != 0) == ((lane & k) == 0));
        unsigned long long mx = kv>o?kv:o, mn = kv<o?kv:o;
        kv = takeMax ? mx : mn;
      }
    }
    K = __shfl(kv, 44);
  } else {
    K = 0ull;
    for (int bb2=43; bb2>=0; --bb2){
      unsigned long long cnd = K | (1ull<<bb2);
      int lc = 0;
      for (int c=0;c<64;c++){
        if (!((qual>>c)&1ull)) continue;
        unsigned vv = row[c*64 + lane];
        int m = c*64 + lane;
        unsigned long long key = (((unsigned long long)vv)<<12) | (unsigned)(4095-m);
        if (key >= cnd) lc++;
      }
      #pragma unroll
      for (int off=32; off; off>>=1) lc += __shfl_xor(lc, off);
      if (lc >= KNB) K = cnd;
    }
  }
  int eb = 0;
  int* dst = idxout + ((size_t)b*N_PTS + (q0+i))*KNB;
  for (int c=0;c<64;c++){
    if (!((qual>>c)&1ull)) continue;
    unsigned vv = row[c*64 + lane];
    int m = c*64 + lane;
    unsigned long long key = (((unsigned long long)vv)<<12) | (unsigned)(4095-m);
    bool sel = key >= K;
    unsigned long long mb = __ballot(sel);
    int pos = eb + __popcll(mb & below);
    if (sel) dst[pos] = m;
    eb += __popcll(mb);
  }
}

// ---- split-bf16 MFMA GEMM: D[pt][o] = act( sum_c Xp[pt][c] * Wp[o][c] + bias ) ----
// STORE: 0 = column-max only (gmax), 1 = packed u32 store [pt][ldo], 2 = f32 store to d_out (O=13)
template<int STORE, int RELU>
__global__ __launch_bounds__(512) void k_mgemm(const unsigned* __restrict__ Ap, int lda,
        const unsigned* __restrict__ Bp, int ldb,
        const float* __restrict__ bias, int perBatch,
        unsigned* __restrict__ Cp, int ldo, float* __restrict__ Cf,
        unsigned* __restrict__ gmax, int O, int K){
  __shared__ short Ah[128][40];
  __shared__ short Al[128][40];
  __shared__ short Bh[128][40];
  __shared__ short Bl[128][40];
  int tid = threadIdx.x;
  int bx = blockIdx.x, by = blockIdx.y, bz = blockIdx.z;
  int w = tid>>6, lane = tid&63;
  int r15 = lane&15, rb = lane>>4;
  int mibase = (w&3)*32, oibase = (w>>2)*64;
  f32x4 acc[2][4];
  #pragma unroll
  for (int mi=0;mi<2;mi++)
    #pragma unroll
    for (int oi=0;oi<4;oi++) acc[mi][oi] = (f32x4){0.f,0.f,0.f,0.f};
  int srow = tid>>2, sc = (tid&3)*8;
  const unsigned* pa = Ap + ((size_t)((bz<<12) + bx*128 + srow))*lda + sc;
  const unsigned* pb = Bp + (size_t)(by*128 + srow)*ldb + sc;
  for (int kt=0; kt<K; kt+=32){
    if (kt) __syncthreads();
    uint4 a0 = *(const uint4*)(pa+kt);
    uint4 a1 = *(const uint4*)(pa+kt+4);
    uint4 b0 = *(const uint4*)(pb+kt);
    uint4 b1 = *(const uint4*)(pb+kt+4);
    short8v h, l;
    cvt8(a0,a1,h,l);
    *(short8v*)&Ah[srow][sc] = h; *(short8v*)&Al[srow][sc] = l;
    cvt8(b0,b1,h,l);
    *(short8v*)&Bh[srow][sc] = h; *(short8v*)&Bl[srow][sc] = l;
    __syncthreads();
    short8v ah[2], al[2];
    #pragma unroll
    for (int mi=0;mi<2;mi++){
      ah[mi] = *(const short8v*)&Ah[mibase+mi*16+r15][rb*8];
      al[mi] = *(const short8v*)&Al[mibase+mi*16+r15][rb*8];
    }
    #pragma unroll
    for (int oi=0;oi<4;oi++){
      short8v bh = *(const short8v*)&Bh[oibase+oi*16+r15][rb*8];
      short8v bl = *(const short8v*)&Bl[oibase+oi*16+r15][rb*8];
      #pragma unroll
      for (int mi=0;mi<2;mi++){
        acc[mi][oi] = __builtin_amdgcn_mfma_f32_16x16x32_bf16(ah[mi], bh, acc[mi][oi], 0,0,0);
        acc[mi][oi] = __builtin_amdgcn_mfma_f32_16x16x32_bf16(ah[mi], bl, acc[mi][oi], 0,0,0);
        acc[mi][oi] = __builtin_amdgcn_mfma_f32_16x16x32_bf16(al[mi], bh, acc[mi][oi], 0,0,0);
      }
    }
  }
  // epilogue: D row = mibase+mi*16+rb*4+r (point), col = oibase+oi*16+r15 (channel)
  #pragma unroll
  for (int oi=0;oi<4;oi++){
    int o = by*128 + oibase + oi*16 + r15;
    float bv = 0.f;
    if (bias != nullptr) bv = perBatch ? bias[bz*O + o] : bias[o];
    float cmx = -INFINITY;
    #pragma unroll
    for (int mi=0;mi<2;mi++){
      #pragma unroll
      for (int r=0;r<4;r++){
        float y = acc[mi][oi][r] + bv;
        if (RELU) y = lrelu(y);
        if (STORE==1){
          int pt = bx*128 + mibase + mi*16 + rb*4 + r;
          Cp[((size_t)((bz<<12)+pt))*ldo + o] = pack2(y);
        } else if (STORE==2){
          if (o < 13){
            int pt = bx*128 + mibase + mi*16 + rb*4 + r;
            Cf[(((size_t)(bz*13 + o))<<12) + pt] = y;
          }
        } else {
          cmx = fmaxf(cmx, y);
        }
      }
    }
    if (STORE==0){
      cmx = fmaxf(cmx, __shfl_xor(cmx,16));
      cmx = fmaxf(cmx, __shfl_xor(cmx,32));
      if (rb==0) atomicMax(&gmax[bz*1024 + o], fenc(cmx));
    }
  }
}

// bias7[b][o] = sum_{c<1024} Wf7[o][c]*g[b][c] + bf7[o]
__global__ __launch_bounds__(256) void k_gemv7(const float* __restrict__ Wf7, const float* __restrict__ bf7,
                        const unsigned* __restrict__ g, float* __restrict__ bias7){
  int wid = threadIdx.x>>6, lane = threadIdx.x&63;
  int o = blockIdx.x*4 + wid, b = blockIdx.y;
  const float* wr = Wf7 + (size_t)o*1216;
  const unsigned* gb = g + b*1024;
  float acc = 0.f;
  for (int c = lane; c < 1024; c += 64)
    acc = fmaf(wr[c], fdec(gb[c]), acc);
  #pragma unroll
  for (int off=32; off; off>>=1) acc += __shfl_xor(acc, off);
  if (lane==0) bias7[b*512+o] = acc + bf7[o];
}

extern "C" void kernel_launch(void* const* d_in, const int* in_sizes, int n_in,
                              void* d_out, int out_size, void* d_ws, size_t ws_size,
                              hipStream_t stream){
  const float* x  = (const float*)d_in[0];
  const float* W1 = (const float*)d_in[1];
  const float* W2 = (const float*)d_in[2];
  const float* W3 = (const float*)d_in[3];
  const float* W4 = (const float*)d_in[4];
  const float* W5 = (const float*)d_in[5];
  const float* W6 = (const float*)d_in[6];
  const float* W7 = (const float*)d_in[7];
  const float* W8 = (const float*)d_in[8];
  const float* W9 = (const float*)d_in[9];
  const float* bn1 = (const float*)d_in[10];
  const float* bn2 = (const float*)d_in[11];
  const float* bn3 = (const float*)d_in[12];
  const float* bn4 = (const float*)d_in[13];
  const float* bn5 = (const float*)d_in[14];
  const float* bn6 = (const float*)d_in[15];
  const float* bn7 = (const float*)d_in[16];
  const float* bn8 = (const float*)d_in[17];

  float* ws = (float*)d_ws;
  size_t off = 0;
  auto alloc = [&](size_t nf){ float* p = ws + off; off += (nf + 63) & ~(size_t)63; return p; };
  float* Wf7 = alloc((size_t)512*1216); float* bf7 = alloc(512);
  float* bf6 = alloc(1024);
  float* bf8 = alloc(256);
  unsigned* Wb6p = (unsigned*)alloc((size_t)1024*192);
  unsigned* Wb7p = (unsigned*)alloc((size_t)512*192);
  unsigned* Wb8p = (unsigned*)alloc((size_t)256*512);
  unsigned* Wb9p = (unsigned*)alloc((size_t)128*256);
  float* W1dT4 = alloc(8*64);     float* bf1 = alloc(64);
  float* W2T4  = alloc(64*64);    float* bf2 = alloc(64);
  float* W3LT4 = alloc(64*64);    float* W3RdT4 = alloc(64*64); float* bf3 = alloc(64);
  float* W4T4  = alloc(64*64);    float* bf4 = alloc(64);
  float* W5LT4 = alloc(64*64);    float* W5RdT4 = alloc(64*64); float* bf5 = alloc(64);
  float* U1  = alloc(4*KNB*64);
  float* x1t = alloc((size_t)4*N_PTS*64);
  float* x2t = alloc((size_t)4*N_PTS*64);
  float* Ut3 = alloc((size_t)4*N_PTS*64);
  float* Vt3 = alloc((size_t)4*N_PTS*64);
  float* Ut5 = alloc((size_t)4*N_PTS*64);
  float* Vt5 = alloc((size_t)4*N_PTS*64);
  unsigned* Xb = (unsigned*)alloc((size_t)4*N_PTS*192);   // packed activations [n][192]
  float* xx1 = alloc(4*N_PTS);
  float* xx2 = alloc(4*N_PTS);
  int* idx1 = (int*)alloc((size_t)4*N_PTS*KNB);
  int* idx2 = (int*)alloc((size_t)4*N_PTS*KNB);
  unsigned* genc = (unsigned*)alloc(4*1024);
  float* bias7 = alloc(4*512);
  unsigned* h8p = (unsigned*)alloc((size_t)4*N_PTS*256);  // packed conv8 out [n][256]
  unsigned* cmaxb = (unsigned*)alloc((size_t)4*N_PTS*64);
  // pdbuf stripe: cap at S=1024 (64 MB) so the gemm->topk round-trip stays L3-resident
  size_t remaining = (ws_size / 4 > off) ? (ws_size / 4 - off) : 0;
  int S = 4096;
  while (S > 512 && (size_t)4*S*N_PTS + 1024 > remaining) S >>= 1;
  if (S > 1024) S = 1024;
  int sshift = 31 - __builtin_clz(S);
  unsigned* pdbuf = (unsigned*)alloc((size_t)4*S*N_PTS);   // encoded u32; reused as h7p (needs 32MB)
  unsigned* h7p = pdbuf;                                    // packed conv7 out [n][512]

  // prep (every call: deterministic)
  k_scale_rows<<<(512*1216+255)/256,256,0,stream>>>(W7, bn7, Wf7, bf7, 512, 1216);
  k_pack_w<<<(1024*192+255)/256,256,0,stream>>>(W6, 192, 0, bn6, 1024, 192, 1024, Wb6p, bf6);
  k_pack_w<<<(512*192+255)/256,256,0,stream>>>(W7, 1216, 1024, bn7, 512, 192, 512, Wb7p, nullptr);
  k_pack_w<<<(256*512+255)/256,256,0,stream>>>(W8, 512, 0, bn8, 256, 512, 256, Wb8p, bf8);
  k_pack_w<<<(128*256+255)/256,256,0,stream>>>(W9, 256, 0, nullptr, 13, 256, 128, Wb9p, nullptr);
  k_build_T4<<<8,64,0,stream>>>(W1, 12, bn1, W1dT4, bf1, 0, 6, 6);     // (W1R - W1L), pad to 8
  k_build_T4<<<64,64,0,stream>>>(W2, 64, bn2, W2T4, bf2, 0, 0, 64);
  k_build_T4<<<64,64,0,stream>>>(W3, 128, bn3, W3LT4, bf3, 0, 0, 64);
  k_build_T4<<<64,64,0,stream>>>(W3, 128, bn3, W3RdT4, nullptr, 0, 64, 64);  // (W3R-W3L)*s
  k_build_T4<<<64,64,0,stream>>>(W4, 64, bn4, W4T4, bf4, 0, 0, 64);
  k_build_T4<<<64,64,0,stream>>>(W5, 128, bn5, W5LT4, bf5, 0, 0, 64);
  k_build_T4<<<64,64,0,stream>>>(W5, 128, bn5, W5RdT4, nullptr, 0, 64, 64);  // (W5R-W5L)*s
  k_build_U1<<<dim3(KNB,4),64,0,stream>>>(x, W1, bn1, U1);
  k_init_g<<<16,256,0,stream>>>(genc);

  // edge block 1 (neighbors = points 0..19 since KNN input is empty slice)
  k_edge1<<<4096,256,0,stream>>>(x, U1, W1dT4, bf1, W2T4, bf2, x1t, Xb, xx1);

  int nstripe = N_PTS / S;
  // KNN on x1 (packed cols 0..63 of Xb)
  for (int s=0;s<nstripe;s++){
    k_knn_mfma<<<dim3(32,S/128,4),512,0,stream>>>(Xb, 0, xx1, pdbuf, cmaxb, s*S, S);
    k_topk20<<<S,256,0,stream>>>(pdbuf, cmaxb, idx1, s*S, sshift);
  }

  // edge block 2: U3/V3 then gather+conv4
  k_uv<<<4096,256,0,stream>>>(x1t, W3LT4, W3RdT4, bf3, Ut3, Vt3);
  k_ec2<<<4096,256,0,stream>>>(Ut3, Vt3, idx1, W4T4, bf4, x2t, Xb, xx2);

  // KNN on x2 (packed cols 64..127 of Xb)
  for (int s=0;s<nstripe;s++){
    k_knn_mfma<<<dim3(32,S/128,4),512,0,stream>>>(Xb, 64, xx2, pdbuf, cmaxb, s*S, S);
    k_topk20<<<S,256,0,stream>>>(pdbuf, cmaxb, idx2, s*S, sshift);
  }

  // edge block 3: U5/V5 then pure gather+max
  k_uv<<<4096,256,0,stream>>>(x2t, W5LT4, W5RdT4, bf5, Ut5, Vt5);
  k_ec3<<<4096,256,0,stream>>>(Ut5, Vt5, idx2, Xb);

  // conv6 (1024x192) -> only column max g (MFMA, gmax atomic)
  k_mgemm<0,1><<<dim3(32,8,4),512,0,stream>>>(Xb, 192, Wb6p, 192, bf6, 0, nullptr, 0, nullptr, genc, 1024, 192);
  // bias7[b][o] = W7[:, :1024] @ g + bf7
  k_gemv7<<<dim3(128,4),256,0,stream>>>(Wf7, bf7, genc, bias7);
  // conv7: W7[:, 1024:1216] @ X + bias7 (per batch) -> packed h7
  k_mgemm<1,1><<<dim3(32,4,4),512,0,stream>>>(Xb, 192, Wb7p, 192, bias7, 1, h7p, 512, nullptr, nullptr, 512, 192);
  // conv8: 256x512 -> packed h8
  k_mgemm<1,1><<<dim3(32,2,4),512,0,stream>>>(h7p, 512, Wb8p, 512, bf8, 0, h8p, 256, nullptr, nullptr, 256, 512);
  // conv9: 13x256 (padded to 128), no bias/relu -> d_out f32
  k_mgemm<2,0><<<dim3(32,1,4),512,0,stream>>>(h8p, 256, Wb9p, 256, nullptr, 0, nullptr, 0, (float*)d_out, nullptr, 13, 256);
}

// Round 10
// 561.348 us; speedup vs baseline: 2.2624x; 1.0982x over previous
//
#include <hip/hip_runtime.h>
#include <math.h>

#define N_PTS 4096
#define BATCH 4
#define KNB 20

typedef __attribute__((ext_vector_type(8))) short short8v;   // 8 bf16
typedef __attribute__((ext_vector_type(4))) float f32x4;

__device__ __forceinline__ float lrelu(float v){ return fmaxf(v, 0.2f*v); }
__device__ __forceinline__ unsigned fenc(float f){ unsigned u=__float_as_uint(f); return (u&0x80000000u)?~u:(u|0x80000000u); }
__device__ __forceinline__ float fdec(unsigned k){ return (k&0x80000000u)?__uint_as_float(k&0x7fffffffu):__uint_as_float(~k); }

// split f32 -> packed (bf16_hi << 16) | bf16_lo,  v ~= hi + lo, err ~2^-18 rel
__device__ __forceinline__ unsigned pack2(float v){
  unsigned u = __float_as_uint(v);
  unsigned hi = (u + 0x7fffu + ((u>>16)&1u)) >> 16;
  float hf = __uint_as_float(hi<<16);
  unsigned u2 = __float_as_uint(v - hf);
  unsigned lo = (u2 + 0x7fffu + ((u2>>16)&1u)) >> 16;
  return (hi<<16) | lo;
}
__device__ __forceinline__ void cvt8(uint4 v0, uint4 v1, short8v& h, short8v& l){
  unsigned a0=v0.x,a1=v0.y,a2=v0.z,a3=v0.w,a4=v1.x,a5=v1.y,a6=v1.z,a7=v1.w;
  h[0]=(short)(a0>>16); l[0]=(short)(a0&0xffffu);
  h[1]=(short)(a1>>16); l[1]=(short)(a1&0xffffu);
  h[2]=(short)(a2>>16); l[2]=(short)(a2&0xffffu);
  h[3]=(short)(a3>>16); l[3]=(short)(a3&0xffffu);
  h[4]=(short)(a4>>16); l[4]=(short)(a4&0xffffu);
  h[5]=(short)(a5>>16); l[5]=(short)(a5&0xffffu);
  h[6]=(short)(a6>>16); l[6]=(short)(a6&0xffffu);
  h[7]=(short)(a7>>16); l[7]=(short)(a7&0xffffu);
}

// ---- prep: fold BN scale into weights (f32, for gemv7) ----
__global__ void k_scale_rows(const float* __restrict__ W, const float* __restrict__ bn,
                             float* __restrict__ Wf, float* __restrict__ bias, int O, int C){
  int i = blockIdx.x*256 + threadIdx.x;
  if (i >= O*C) return;
  int o = i / C;
  float s = bn[o] / sqrtf(bn[3*O+o] + 1e-5f);
  Wf[i] = W[i]*s;
  if (i % C == 0) bias[o] = bn[O+o] - s*bn[2*O+o];
}

// pack scaled weights to (hi|lo) u32 [Opad][C]; rows >= O zero-padded
__global__ void k_pack_w(const float* __restrict__ W, int ldw, int c0,
                         const float* __restrict__ bn, int O, int C, int Opad,
                         unsigned* __restrict__ out, float* __restrict__ bias){
  int i = blockIdx.x*256 + threadIdx.x;
  if (i >= Opad*C) return;
  int o = i / C, c = i - o*C;
  float v = 0.f;
  if (o < O){
    float s = 1.f;
    if (bn != nullptr){
      s = bn[o] / sqrtf(bn[3*O+o] + 1e-5f);
      if (bias != nullptr && c == 0) bias[o] = bn[O+o] - s*bn[2*O+o];
    }
    v = W[o*ldw + c0 + c] * s;
  }
  out[i] = pack2(v);
}

// transposed float4-chunk layout: dst[(c/4)*256 + o*4 + c%4], O=64 fixed
__global__ void k_build_T4(const float* __restrict__ W, int ldw, const float* __restrict__ bn,
                           float* __restrict__ dst, float* __restrict__ bias,
                           int c0, int diffoff, int Csrc){
  int o = threadIdx.x, c = blockIdx.x;
  float s = bn[o] / sqrtf(bn[192+o] + 1e-5f);
  float val = 0.f;
  if (c < Csrc){
    val = W[o*ldw + c0 + c];
    if (diffoff) val = W[o*ldw + c0 + diffoff + c] - val;
    val *= s;
  }
  dst[(c>>2)*256 + o*4 + (c&3)] = val;
  if (bias != nullptr && c==0) bias[o] = bn[64+o] - s*bn[128+o];
}

// U1[b][k][o] = sum_{c<6} s_o*W1[o][c]*x[b][c][k]  (first-KNN neighbors are points 0..19)
__global__ void k_build_U1(const float* __restrict__ x, const float* __restrict__ W1,
                           const float* __restrict__ bn, float* __restrict__ U1){
  int o = threadIdx.x, k = blockIdx.x, b = blockIdx.y;
  float s = bn[o] / sqrtf(bn[192+o] + 1e-5f);
  float acc = 0.f;
  #pragma unroll
  for (int c=0;c<6;c++) acc += W1[o*12+c] * x[(b*6+c)*N_PTS + k];
  U1[(b*KNB+k)*64 + o] = acc*s;
}

// V1[pt][o] = s*((W1R-W1L)@x_pt)[o] + bias1[o]
__global__ __launch_bounds__(256) void k_v1(const float* __restrict__ x, const float* __restrict__ W1,
        const float* __restrict__ bn, float* __restrict__ V1){
  int o = threadIdx.x&63;
  int pt = blockIdx.x*4 + (threadIdx.x>>6);
  int b = pt>>12, n = pt&4095;
  float s = bn[o] / sqrtf(bn[192+o] + 1e-5f);
  float acc = bn[64+o] - s*bn[128+o];
  #pragma unroll
  for (int c=0;c<6;c++)
    acc += s*(W1[o*12+6+c]-W1[o*12+c]) * x[(b*6+c)*N_PTS + n];
  V1[(size_t)pt*64 + o] = acc;
}

__global__ void k_init_g(unsigned* g){ g[blockIdx.x*256+threadIdx.x] = fenc(-INFINITY); }

// ---- U/V precompute: Ut[n][o] = s*(WL@x_n); Vt[n][o] = s*((WR-WL)@x_n) + bias ----
__global__ __launch_bounds__(256) void k_uv(const float* __restrict__ xt, const float* __restrict__ WL,
    const float* __restrict__ WRd, const float* __restrict__ bf,
    float* __restrict__ Ut, float* __restrict__ Vt){
  __shared__ float xs[4][64];
  int wid = threadIdx.x>>6, lane = threadIdx.x&63;
  int pt = blockIdx.x*4 + wid;
  xs[wid][lane] = xt[(size_t)pt*64 + lane];
  __syncthreads();
  float U = 0.f, V = bf[lane];
  #pragma unroll
  for (int cb=0;cb<16;cb++){
    float4 wl = ((const float4*)WL)[cb*64+lane];
    float4 wr = ((const float4*)WRd)[cb*64+lane];
    float4 xv = *(const float4*)&xs[wid][cb*4];
    U=fmaf(wl.x,xv.x,U); U=fmaf(wl.y,xv.y,U); U=fmaf(wl.z,xv.z,U); U=fmaf(wl.w,xv.w,U);
    V=fmaf(wr.x,xv.x,V); V=fmaf(wr.y,xv.y,V); V=fmaf(wr.z,xv.z,V); V=fmaf(wr.w,xv.w,V);
  }
  Ut[(size_t)pt*64 + lane] = U;
  Vt[(size_t)pt*64 + lane] = V;
}

// ---- unified MFMA edge-conv: for each point, D[pt][o] = max_k conv(lrelu(U[m_k]+V[pt])) ----
// GATHER=0: U indexed [b][k][64] directly (edge1). GATHER=1: U gathered via idx (ec2).
// 64 points/block, 4 waves; double-buffered hi/lo bf16 h-tile; weights in VGPRs.
template<int GATHER>
__global__ __launch_bounds__(256) void k_edgemm(const float* __restrict__ Ut,
    const float* __restrict__ Vt, const int* __restrict__ idx,
    const unsigned* __restrict__ Wp, const float* __restrict__ bf,
    float* __restrict__ xout, unsigned* __restrict__ Xb, int coff,
    float* __restrict__ xxout){
  __shared__ short Hh[2][64][72];
  __shared__ short Hl[2][64][72];
  int tid = threadIdx.x;
  int b = blockIdx.z, p0 = blockIdx.x*64;
  int w = tid>>6, lane = tid&63, r15 = lane&15, rb = lane>>4;
  int ptl = tid>>2, c0 = (tid&3)*16;
  size_t ptg = ((size_t)b<<12) + p0 + ptl;
  float v[16];
  #pragma unroll
  for (int q=0;q<4;q++){
    float4 t = *(const float4*)&Vt[ptg*64 + c0 + q*4];
    v[q*4+0]=t.x; v[q*4+1]=t.y; v[q*4+2]=t.z; v[q*4+3]=t.w;
  }
  int mr[KNB];
  if (GATHER){
    const int4* ip4 = (const int4*)(idx + ptg*KNB);
    #pragma unroll
    for (int q=0;q<5;q++){ int4 t=ip4[q]; mr[q*4+0]=t.x; mr[q*4+1]=t.y; mr[q*4+2]=t.z; mr[q*4+3]=t.w; }
  }
  short8v wh[4][2], wl[4][2];
  #pragma unroll
  for (int oi=0;oi<4;oi++)
    #pragma unroll
    for (int ks=0;ks<2;ks++){
      const unsigned* pw = Wp + (size_t)(oi*16+r15)*64 + ks*32 + rb*8;
      uint4 w0 = *(const uint4*)pw, w1 = *(const uint4*)(pw+4);
      cvt8(w0,w1,wh[oi][ks],wl[oi][ks]);
    }
  f32x4 rmax[4];
  #pragma unroll
  for (int oi=0;oi<4;oi++) rmax[oi]=(f32x4){-INFINITY,-INFINITY,-INFINITY,-INFINITY};
  float uc[16], un[16];
  {
    const float* ur = GATHER ? (Ut + ((((size_t)b)<<12) + mr[0])*64 + c0)
                             : (Ut + ((size_t)b*KNB + 0)*64 + c0);
    #pragma unroll
    for (int q=0;q<4;q++){
      float4 t = *(const float4*)(ur + q*4);
      uc[q*4+0]=t.x; uc[q*4+1]=t.y; uc[q*4+2]=t.z; uc[q*4+3]=t.w;
    }
  }
  for (int k=0;k<KNB;k++){
    int buf = k&1;
    #pragma unroll
    for (int q=0;q<2;q++){
      short8v hh, hl;
      #pragma unroll
      for (int e=0;e<8;e++){
        unsigned pk = pack2(lrelu(uc[q*8+e] + v[q*8+e]));
        hh[e]=(short)(pk>>16); hl[e]=(short)(pk&0xffffu);
      }
      *(short8v*)&Hh[buf][ptl][c0+q*8] = hh;
      *(short8v*)&Hl[buf][ptl][c0+q*8] = hl;
    }
    if (k+1 < KNB){
      const float* ur = GATHER ? (Ut + ((((size_t)b)<<12) + mr[k+1])*64 + c0)
                               : (Ut + ((size_t)b*KNB + (k+1))*64 + c0);
      #pragma unroll
      for (int q=0;q<4;q++){
        float4 t = *(const float4*)(ur + q*4);
        un[q*4+0]=t.x; un[q*4+1]=t.y; un[q*4+2]=t.z; un[q*4+3]=t.w;
      }
    }
    __syncthreads();
    f32x4 acc[4];
    #pragma unroll
    for (int oi=0;oi<4;oi++) acc[oi]=(f32x4){0.f,0.f,0.f,0.f};
    #pragma unroll
    for (int ks=0;ks<2;ks++){
      short8v ah = *(const short8v*)&Hh[buf][w*16+r15][ks*32+rb*8];
      short8v al = *(const short8v*)&Hl[buf][w*16+r15][ks*32+rb*8];
      #pragma unroll
      for (int oi=0;oi<4;oi++){
        acc[oi] = __builtin_amdgcn_mfma_f32_16x16x32_bf16(ah, wh[oi][ks], acc[oi], 0,0,0);
        acc[oi] = __builtin_amdgcn_mfma_f32_16x16x32_bf16(ah, wl[oi][ks], acc[oi], 0,0,0);
        acc[oi] = __builtin_amdgcn_mfma_f32_16x16x32_bf16(al, wh[oi][ks], acc[oi], 0,0,0);
      }
    }
    #pragma unroll
    for (int oi=0;oi<4;oi++)
      #pragma unroll
      for (int r=0;r<4;r++) rmax[oi][r] = fmaxf(rmax[oi][r], acc[oi][r]);
    if (k+1 < KNB){
      #pragma unroll
      for (int e=0;e<16;e++) uc[e]=un[e];
    }
  }
  float xs[4] = {0.f,0.f,0.f,0.f};
  #pragma unroll
  for (int oi=0;oi<4;oi++){
    int o = oi*16 + r15;
    float bv = bf[o];
    #pragma unroll
    for (int r=0;r<4;r++){
      float y = lrelu(rmax[oi][r] + bv);
      size_t pg = ((size_t)b<<12) + p0 + w*16 + rb*4 + r;
      if (xout) xout[pg*64 + o] = y;
      Xb[pg*192 + coff + o] = pack2(y);
      xs[r] += y*y;
    }
  }
  if (xxout){
    #pragma unroll
    for (int r=0;r<4;r++){
      float s = xs[r];
      s += __shfl_xor(s,1); s += __shfl_xor(s,2); s += __shfl_xor(s,4); s += __shfl_xor(s,8);
      if (r15==0) xxout[((size_t)b<<12) + p0 + w*16 + rb*4 + r] = s;
    }
  }
}

// ---- edge block 3: x3[n] = lrelu(V5[n] + max_k U5[m_k]) -- pure gather+max ----
__global__ __launch_bounds__(256) void k_ec3(const float* __restrict__ Ut, const float* __restrict__ Vt,
    const int* __restrict__ idx, unsigned* __restrict__ Xb){
  int wid = threadIdx.x>>6, lane = threadIdx.x&63;
  int pt = blockIdx.x*4 + wid, b = pt>>12, n = pt&4095;
  const float* Ub = Ut + (((size_t)b)<<12)*64;
  int mr[KNB];
  const int4* ip4 = (const int4*)(idx + (size_t)pt*KNB);
  #pragma unroll
  for (int q=0;q<5;q++){ int4 t = ip4[q]; mr[q*4+0]=t.x; mr[q*4+1]=t.y; mr[q*4+2]=t.z; mr[q*4+3]=t.w; }
  float mx = -INFINITY;
  #pragma unroll
  for (int k=0;k<KNB;k++) mx = fmaxf(mx, Ub[(size_t)mr[k]*64 + lane]);
  mx = lrelu(mx + Vt[(size_t)pt*64 + lane]);
  Xb[((size_t)((b<<12)+n))*192 + 128 + lane] = pack2(mx);
}

// ---- KNN distance via split-bf16 MFMA: pd = fenc(fma(2,dot,-xx_n) - xx_m) ----
__global__ __launch_bounds__(512) void k_knn_mfma(const unsigned* __restrict__ Xp, int coff,
        const float* __restrict__ xx, unsigned* __restrict__ pd, unsigned* __restrict__ cmax,
        int q0, int S){
  __shared__ short Ah[128][40];
  __shared__ short Al[128][40];
  __shared__ short Bh[128][40];
  __shared__ short Bl[128][40];
  int tid = threadIdx.x;
  int bx = blockIdx.x, by = blockIdx.y, bz = blockIdx.z;
  int w = tid>>6, lane = tid&63;
  int r15 = lane&15, rb = lane>>4;
  int mibase = (w&3)*32, oibase = (w>>2)*64;
  f32x4 acc[2][4];
  #pragma unroll
  for (int mi=0;mi<2;mi++)
    #pragma unroll
    for (int oi=0;oi<4;oi++) acc[mi][oi] = (f32x4){0.f,0.f,0.f,0.f};
  int srow = tid>>2, sc = (tid&3)*8;
  const unsigned* pa = Xp + ((size_t)((bz<<12) + q0 + by*128 + srow))*192 + coff + sc;
  const unsigned* pb = Xp + ((size_t)((bz<<12) + bx*128 + srow))*192 + coff + sc;
  for (int kt=0; kt<64; kt+=32){
    if (kt) __syncthreads();
    uint4 a0 = *(const uint4*)(pa+kt);
    uint4 a1 = *(const uint4*)(pa+kt+4);
    uint4 b0 = *(const uint4*)(pb+kt);
    uint4 b1 = *(const uint4*)(pb+kt+4);
    short8v h, l;
    cvt8(a0,a1,h,l);
    *(short8v*)&Ah[srow][sc] = h; *(short8v*)&Al[srow][sc] = l;
    cvt8(b0,b1,h,l);
    *(short8v*)&Bh[srow][sc] = h; *(short8v*)&Bl[srow][sc] = l;
    __syncthreads();
    short8v ah[2], al[2];
    #pragma unroll
    for (int mi=0;mi<2;mi++){
      ah[mi] = *(const short8v*)&Ah[mibase+mi*16+r15][rb*8];
      al[mi] = *(const short8v*)&Al[mibase+mi*16+r15][rb*8];
    }
    #pragma unroll
    for (int oi=0;oi<4;oi++){
      short8v bh = *(const short8v*)&Bh[oibase+oi*16+r15][rb*8];
      short8v bl = *(const short8v*)&Bl[oibase+oi*16+r15][rb*8];
      #pragma unroll
      for (int mi=0;mi<2;mi++){
        acc[mi][oi] = __builtin_amdgcn_mfma_f32_16x16x32_bf16(ah[mi], bh, acc[mi][oi], 0,0,0);
        acc[mi][oi] = __builtin_amdgcn_mfma_f32_16x16x32_bf16(ah[mi], bl, acc[mi][oi], 0,0,0);
        acc[mi][oi] = __builtin_amdgcn_mfma_f32_16x16x32_bf16(al[mi], bh, acc[mi][oi], 0,0,0);
      }
    }
  }
  float xm[4];
  #pragma unroll
  for (int oi=0;oi<4;oi++) xm[oi] = xx[(bz<<12) + bx*128 + oibase + oi*16 + r15];
  #pragma unroll
  for (int mi=0;mi<2;mi++){
    #pragma unroll
    for (int r=0;r<4;r++){
      int row = by*128 + mibase + mi*16 + rb*4 + r;
      float xn = xx[(bz<<12) + q0 + row];
      float f0 = fmaf(2.f, acc[mi][0][r], -xn) - xm[0];
      float f1 = fmaf(2.f, acc[mi][1][r], -xn) - xm[1];
      float f2 = fmaf(2.f, acc[mi][2][r], -xn) - xm[2];
      float f3 = fmaf(2.f, acc[mi][3][r], -xn) - xm[3];
      unsigned* dst = pd + ((size_t)(bz*S + row))*N_PTS + bx*128 + oibase;
      dst[ 0+r15] = fenc(f0);
      dst[16+r15] = fenc(f1);
      dst[32+r15] = fenc(f2);
      dst[48+r15] = fenc(f3);
      float m = fmaxf(fmaxf(f0,f1), fmaxf(f2,f3));
      m = fmaxf(m, __shfl_xor(m,1));
      m = fmaxf(m, __shfl_xor(m,2));
      m = fmaxf(m, __shfl_xor(m,4));
      m = fmaxf(m, __shfl_xor(m,8));
      if (r15 == 0)
        cmax[((size_t)(bz<<12) + q0 + row)*64 + bx*2 + (oibase>>6)] = fenc(m);
    }
  }
}

__device__ __forceinline__ unsigned bitsort_u32(unsigned v, int lane){
  #pragma unroll
  for (int k=2;k<=64;k<<=1){
    #pragma unroll
    for (int j=k>>1;j>0;j>>=1){
      unsigned o = (unsigned)__shfl_xor((int)v, j);
      bool takeMax = (((lane & j) != 0) == ((lane & k) == 0));
      unsigned mx = v>o?v:o, mn = v<o?v:o;
      v = takeMax ? mx : mn;
    }
  }
  return v;   // ascending by lane
}

// ---- filtered top-20: chunk-max prefilter + streaming candidate selection ----
__global__ __launch_bounds__(256,4) void k_topk20(const unsigned* __restrict__ pdbuf,
        const unsigned* __restrict__ cmax, int* __restrict__ idxout, int q0, int sshift){
  __shared__ unsigned long long cand[4][64];
  int wid = threadIdx.x>>6, lane = threadIdx.x&63;
  int gw = blockIdx.x*4 + wid;
  int S = 1 << sshift;
  int b = gw >> sshift, i = gw & (S-1);
  const unsigned* row = pdbuf + ((size_t)b*S + i)*N_PTS;
  unsigned cm = cmax[((size_t)b*N_PTS + q0 + i)*64 + lane];
  unsigned T = (unsigned)__shfl((int)bitsort_u32(cm, lane), 44);
  unsigned long long qual = __ballot(cm >= T);
  unsigned lmax = 0u;
  for (int c=0;c<64;c++){
    if (!((qual>>c)&1ull)) continue;
    unsigned vv = row[c*64 + lane];
    lmax = lmax > vv ? lmax : vv;
  }
  unsigned T2 = (unsigned)__shfl((int)bitsort_u32(lmax, lane), 44);
  int base = 0;
  unsigned long long below = (1ull<<lane) - 1ull;
  for (int c=0;c<64;c++){
    if (!((qual>>c)&1ull)) continue;
    unsigned vv = row[c*64 + lane];
    bool isc = vv >= T2;
    unsigned long long mb = __ballot(isc);
    int pos = base + __popcll(mb & below);
    if (isc && pos < 64){
      int m = c*64 + lane;
      cand[wid][pos] = (((unsigned long long)vv)<<12) | (unsigned)(4095-m);
    }
    base += __popcll(mb);
  }
  unsigned long long K;
  if (base <= 64){
    unsigned long long kv = (lane < base) ? cand[wid][lane] : 0ull;
    #pragma unroll
    for (int k=2;k<=64;k<<=1){
      #pragma unroll
      for (int j=k>>1;j>0;j>>=1){
        unsigned long long o = __shfl_xor(kv, j);
        bool takeMax = (((lane & j) != 0) == ((lane & k) == 0));
        unsigned long long mx = kv>o?kv:o, mn = kv<o?kv:o;
        kv = takeMax ? mx : mn;
      }
    }
    K = __shfl(kv, 44);
  } else {
    K = 0ull;
    for (int bb2=43; bb2>=0; --bb2){
      unsigned long long cnd = K | (1ull<<bb2);
      int lc = 0;
      for (int c=0;c<64;c++){
        if (!((qual>>c)&1ull)) continue;
        unsigned vv = row[c*64 + lane];
        int m = c*64 + lane;
        unsigned long long key = (((unsigned long long)vv)<<12) | (unsigned)(4095-m);
        if (key >= cnd) lc++;
      }
      #pragma unroll
      for (int off=32; off; off>>=1) lc += __shfl_xor(lc, off);
      if (lc >= KNB) K = cnd;
    }
  }
  int eb = 0;
  int* dst = idxout + ((size_t)b*N_PTS + (q0+i))*KNB;
  for (int c=0;c<64;c++){
    if (!((qual>>c)&1ull)) continue;
    unsigned vv = row[c*64 + lane];
    int m = c*64 + lane;
    unsigned long long key = (((unsigned long long)vv)<<12) | (unsigned)(4095-m);
    bool sel = key >= K;
    unsigned long long mb = __ballot(sel);
    int pos = eb + __popcll(mb & below);
    if (sel) dst[pos] = m;
    eb += __popcll(mb);
  }
}

// ---- split-bf16 MFMA GEMM: D[pt][o] = act( sum_c Xp[pt][c] * Wp[o][c] + bias ) ----
// STORE: 0 = column-max only (gmax), 1 = packed u32 store [pt][ldo], 2 = f32 store to d_out (O=13)
template<int STORE, int RELU>
__global__ __launch_bounds__(512) void k_mgemm(const unsigned* __restrict__ Ap, int lda,
        const unsigned* __restrict__ Bp, int ldb,
        const float* __restrict__ bias, int perBatch,
        unsigned* __restrict__ Cp, int ldo, float* __restrict__ Cf,
        unsigned* __restrict__ gmax, int O, int K){
  __shared__ short Ah[128][40];
  __shared__ short Al[128][40];
  __shared__ short Bh[128][40];
  __shared__ short Bl[128][40];
  int tid = threadIdx.x;
  int bx = blockIdx.x, by = blockIdx.y, bz = blockIdx.z;
  int w = tid>>6, lane = tid&63;
  int r15 = lane&15, rb = lane>>4;
  int mibase = (w&3)*32, oibase = (w>>2)*64;
  f32x4 acc[2][4];
  #pragma unroll
  for (int mi=0;mi<2;mi++)
    #pragma unroll
    for (int oi=0;oi<4;oi++) acc[mi][oi] = (f32x4){0.f,0.f,0.f,0.f};
  int srow = tid>>2, sc = (tid&3)*8;
  const unsigned* pa = Ap + ((size_t)((bz<<12) + bx*128 + srow))*lda + sc;
  const unsigned* pb = Bp + (size_t)(by*128 + srow)*ldb + sc;
  for (int kt=0; kt<K; kt+=32){
    if (kt) __syncthreads();
    uint4 a0 = *(const uint4*)(pa+kt);
    uint4 a1 = *(const uint4*)(pa+kt+4);
    uint4 b0 = *(const uint4*)(pb+kt);
    uint4 b1 = *(const uint4*)(pb+kt+4);
    short8v h, l;
    cvt8(a0,a1,h,l);
    *(short8v*)&Ah[srow][sc] = h; *(short8v*)&Al[srow][sc] = l;
    cvt8(b0,b1,h,l);
    *(short8v*)&Bh[srow][sc] = h; *(short8v*)&Bl[srow][sc] = l;
    __syncthreads();
    short8v ah[2], al[2];
    #pragma unroll
    for (int mi=0;mi<2;mi++){
      ah[mi] = *(const short8v*)&Ah[mibase+mi*16+r15][rb*8];
      al[mi] = *(const short8v*)&Al[mibase+mi*16+r15][rb*8];
    }
    #pragma unroll
    for (int oi=0;oi<4;oi++){
      short8v bh = *(const short8v*)&Bh[oibase+oi*16+r15][rb*8];
      short8v bl = *(const short8v*)&Bl[oibase+oi*16+r15][rb*8];
      #pragma unroll
      for (int mi=0;mi<2;mi++){
        acc[mi][oi] = __builtin_amdgcn_mfma_f32_16x16x32_bf16(ah[mi], bh, acc[mi][oi], 0,0,0);
        acc[mi][oi] = __builtin_amdgcn_mfma_f32_16x16x32_bf16(ah[mi], bl, acc[mi][oi], 0,0,0);
        acc[mi][oi] = __builtin_amdgcn_mfma_f32_16x16x32_bf16(al[mi], bh, acc[mi][oi], 0,0,0);
      }
    }
  }
  #pragma unroll
  for (int oi=0;oi<4;oi++){
    int o = by*128 + oibase + oi*16 + r15;
    float bv = 0.f;
    if (bias != nullptr) bv = perBatch ? bias[bz*O + o] : bias[o];
    float cmx = -INFINITY;
    #pragma unroll
    for (int mi=0;mi<2;mi++){
      #pragma unroll
      for (int r=0;r<4;r++){
        float y = acc[mi][oi][r] + bv;
        if (RELU) y = lrelu(y);
        if (STORE==1){
          int pt = bx*128 + mibase + mi*16 + rb*4 + r;
          Cp[((size_t)((bz<<12)+pt))*ldo + o] = pack2(y);
        } else if (STORE==2){
          if (o < 13){
            int pt = bx*128 + mibase + mi*16 + rb*4 + r;
            Cf[(((size_t)(bz*13 + o))<<12) + pt] = y;
          }
        } else {
          cmx = fmaxf(cmx, y);
        }
      }
    }
    if (STORE==0){
      cmx = fmaxf(cmx, __shfl_xor(cmx,16));
      cmx = fmaxf(cmx, __shfl_xor(cmx,32));
      if (rb==0) atomicMax(&gmax[bz*1024 + o], fenc(cmx));
    }
  }
}

// bias7[b][o] = sum_{c<1024} Wf7[o][c]*g[b][c] + bf7[o]
__global__ __launch_bounds__(256) void k_gemv7(const float* __restrict__ Wf7, const float* __restrict__ bf7,
                        const unsigned* __restrict__ g, float* __restrict__ bias7){
  int wid = threadIdx.x>>6, lane = threadIdx.x&63;
  int o = blockIdx.x*4 + wid, b = blockIdx.y;
  const float* wr = Wf7 + (size_t)o*1216;
  const unsigned* gb = g + b*1024;
  float acc = 0.f;
  for (int c = lane; c < 1024; c += 64)
    acc = fmaf(wr[c], fdec(gb[c]), acc);
  #pragma unroll
  for (int off=32; off; off>>=1) acc += __shfl_xor(acc, off);
  if (lane==0) bias7[b*512+o] = acc + bf7[o];
}

extern "C" void kernel_launch(void* const* d_in, const int* in_sizes, int n_in,
                              void* d_out, int out_size, void* d_ws, size_t ws_size,
                              hipStream_t stream){
  const float* x  = (const float*)d_in[0];
  const float* W1 = (const float*)d_in[1];
  const float* W2 = (const float*)d_in[2];
  const float* W3 = (const float*)d_in[3];
  const float* W4 = (const float*)d_in[4];
  const float* W5 = (const float*)d_in[5];
  const float* W6 = (const float*)d_in[6];
  const float* W7 = (const float*)d_in[7];
  const float* W8 = (const float*)d_in[8];
  const float* W9 = (const float*)d_in[9];
  const float* bn1 = (const float*)d_in[10];
  const float* bn2 = (const float*)d_in[11];
  const float* bn3 = (const float*)d_in[12];
  const float* bn4 = (const float*)d_in[13];
  const float* bn5 = (const float*)d_in[14];
  const float* bn6 = (const float*)d_in[15];
  const float* bn7 = (const float*)d_in[16];
  const float* bn8 = (const float*)d_in[17];

  float* ws = (float*)d_ws;
  size_t off = 0;
  auto alloc = [&](size_t nf){ float* p = ws + off; off += (nf + 63) & ~(size_t)63; return p; };
  float* Wf7 = alloc((size_t)512*1216); float* bf7 = alloc(512);
  float* bf6 = alloc(1024);
  float* bf8 = alloc(256);
  float* bf2 = alloc(64);
  float* bf4 = alloc(64);
  unsigned* Wb2p = (unsigned*)alloc((size_t)64*64);
  unsigned* Wb4p = (unsigned*)alloc((size_t)64*64);
  unsigned* Wb6p = (unsigned*)alloc((size_t)1024*192);
  unsigned* Wb7p = (unsigned*)alloc((size_t)512*192);
  unsigned* Wb8p = (unsigned*)alloc((size_t)256*512);
  unsigned* Wb9p = (unsigned*)alloc((size_t)128*256);
  float* W3LT4 = alloc(64*64);    float* W3RdT4 = alloc(64*64); float* bf3 = alloc(64);
  float* W5LT4 = alloc(64*64);    float* W5RdT4 = alloc(64*64); float* bf5 = alloc(64);
  float* U1  = alloc(4*KNB*64);
  float* V1  = alloc((size_t)4*N_PTS*64);
  float* x1t = alloc((size_t)4*N_PTS*64);
  float* x2t = alloc((size_t)4*N_PTS*64);
  float* Ut3 = alloc((size_t)4*N_PTS*64);
  float* Vt3 = alloc((size_t)4*N_PTS*64);
  float* Ut5 = alloc((size_t)4*N_PTS*64);
  float* Vt5 = alloc((size_t)4*N_PTS*64);
  unsigned* Xb = (unsigned*)alloc((size_t)4*N_PTS*192);   // packed activations [n][192]
  float* xx1 = alloc(4*N_PTS);
  float* xx2 = alloc(4*N_PTS);
  int* idx1 = (int*)alloc((size_t)4*N_PTS*KNB);
  int* idx2 = (int*)alloc((size_t)4*N_PTS*KNB);
  unsigned* genc = (unsigned*)alloc(4*1024);
  float* bias7 = alloc(4*512);
  unsigned* h8p = (unsigned*)alloc((size_t)4*N_PTS*256);  // packed conv8 out [n][256]
  unsigned* cmaxb = (unsigned*)alloc((size_t)4*N_PTS*64);
  // pdbuf stripe: cap at S=1024 (64 MB) so the gemm->topk round-trip stays L3-resident
  size_t remaining = (ws_size / 4 > off) ? (ws_size / 4 - off) : 0;
  int S = 4096;
  while (S > 512 && (size_t)4*S*N_PTS + 1024 > remaining) S >>= 1;
  if (S > 1024) S = 1024;
  int sshift = 31 - __builtin_clz(S);
  unsigned* pdbuf = (unsigned*)alloc((size_t)4*S*N_PTS);   // encoded u32; reused as h7p (needs 32MB)
  unsigned* h7p = pdbuf;                                    // packed conv7 out [n][512]

  // prep (every call: deterministic)
  k_scale_rows<<<(512*1216+255)/256,256,0,stream>>>(W7, bn7, Wf7, bf7, 512, 1216);
  k_pack_w<<<(64*64+255)/256,256,0,stream>>>(W2, 64, 0, bn2, 64, 64, 64, Wb2p, bf2);
  k_pack_w<<<(64*64+255)/256,256,0,stream>>>(W4, 64, 0, bn4, 64, 64, 64, Wb4p, bf4);
  k_pack_w<<<(1024*192+255)/256,256,0,stream>>>(W6, 192, 0, bn6, 1024, 192, 1024, Wb6p, bf6);
  k_pack_w<<<(512*192+255)/256,256,0,stream>>>(W7, 1216, 1024, bn7, 512, 192, 512, Wb7p, nullptr);
  k_pack_w<<<(256*512+255)/256,256,0,stream>>>(W8, 512, 0, bn8, 256, 512, 256, Wb8p, bf8);
  k_pack_w<<<(128*256+255)/256,256,0,stream>>>(W9, 256, 0, nullptr, 13, 256, 128, Wb9p, nullptr);
  k_build_T4<<<64,64,0,stream>>>(W3, 128, bn3, W3LT4, bf3, 0, 0, 64);
  k_build_T4<<<64,64,0,stream>>>(W3, 128, bn3, W3RdT4, nullptr, 0, 64, 64);  // (W3R-W3L)*s
  k_build_T4<<<64,64,0,stream>>>(W5, 128, bn5, W5LT4, bf5, 0, 0, 64);
  k_build_T4<<<64,64,0,stream>>>(W5, 128, bn5, W5RdT4, nullptr, 0, 64, 64);  // (W5R-W5L)*s
  k_build_U1<<<dim3(KNB,4),64,0,stream>>>(x, W1, bn1, U1);
  k_v1<<<4096,256,0,stream>>>(x, W1, bn1, V1);
  k_init_g<<<16,256,0,stream>>>(genc);

  // edge block 1: MFMA edge-conv (neighbors = points 0..19, U1 indexed by k)
  k_edgemm<0><<<dim3(64,1,4),256,0,stream>>>(U1, V1, nullptr, Wb2p, bf2, x1t, Xb, 0, xx1);

  int nstripe = N_PTS / S;
  // KNN on x1 (packed cols 0..63 of Xb)
  for (int s=0;s<nstripe;s++){
    k_knn_mfma<<<dim3(32,S/128,4),512,0,stream>>>(Xb, 0, xx1, pdbuf, cmaxb, s*S, S);
    k_topk20<<<S,256,0,stream>>>(pdbuf, cmaxb, idx1, s*S, sshift);
  }

  // edge block 2: U3/V3 then MFMA edge-conv with gather
  k_uv<<<4096,256,0,stream>>>(x1t, W3LT4, W3RdT4, bf3, Ut3, Vt3);
  k_edgemm<1><<<dim3(64,1,4),256,0,stream>>>(Ut3, Vt3, idx1, Wb4p, bf4, x2t, Xb, 64, xx2);

  // KNN on x2 (packed cols 64..127 of Xb)
  for (int s=0;s<nstripe;s++){
    k_knn_mfma<<<dim3(32,S/128,4),512,0,stream>>>(Xb, 64, xx2, pdbuf, cmaxb, s*S, S);
    k_topk20<<<S,256,0,stream>>>(pdbuf, cmaxb, idx2, s*S, sshift);
  }

  // edge block 3: U5/V5 then pure gather+max
  k_uv<<<4096,256,0,stream>>>(x2t, W5LT4, W5RdT4, bf5, Ut5, Vt5);
  k_ec3<<<4096,256,0,stream>>>(Ut5, Vt5, idx2, Xb);

  // conv6 (1024x192) -> only column max g (MFMA, gmax atomic)
  k_mgemm<0,1><<<dim3(32,8,4),512,0,stream>>>(Xb, 192, Wb6p, 192, bf6, 0, nullptr, 0, nullptr, genc, 1024, 192);
  // bias7[b][o] = W7[:, :1024] @ g + bf7
  k_gemv7<<<dim3(128,4),256,0,stream>>>(Wf7, bf7, genc, bias7);
  // conv7: W7[:, 1024:1216] @ X + bias7 (per batch) -> packed h7
  k_mgemm<1,1><<<dim3(32,4,4),512,0,stream>>>(Xb, 192, Wb7p, 192, bias7, 1, h7p, 512, nullptr, nullptr, 512, 192);
  // conv8: 256x512 -> packed h8
  k_mgemm<1,1><<<dim3(32,2,4),512,0,stream>>>(h7p, 512, Wb8p, 512, bf8, 0, h8p, 256, nullptr, nullptr, 256, 512);
  // conv9: 13x256 (padded to 128), no bias/relu -> d_out f32
  k_mgemm<2,0><<<dim3(32,1,4),512,0,stream>>>(h8p, 256, Wb9p, 256, nullptr, 0, nullptr, 0, (float*)d_out, nullptr, 13, 256);
}

// Round 13
// 561.328 us; speedup vs baseline: 2.2625x; 1.0000x over previous
//
#include <hip/hip_runtime.h>
#include <math.h>

#define N_PTS 4096
#define BATCH 4
#define KNB 20

typedef __attribute__((ext_vector_type(8))) short short8v;   // 8 bf16
typedef __attribute__((ext_vector_type(4))) float f32x4;

__device__ __forceinline__ float lrelu(float v){ return fmaxf(v, 0.2f*v); }
__device__ __forceinline__ unsigned fenc(float f){ unsigned u=__float_as_uint(f); return (u&0x80000000u)?~u:(u|0x80000000u); }
__device__ __forceinline__ float fdec(unsigned k){ return (k&0x80000000u)?__uint_as_float(k&0x7fffffffu):__uint_as_float(~k); }

// split f32 -> packed (bf16_hi << 16) | bf16_lo,  v ~= hi + lo, err ~2^-18 rel
__device__ __forceinline__ unsigned pack2(float v){
  unsigned u = __float_as_uint(v);
  unsigned hi = (u + 0x7fffu + ((u>>16)&1u)) >> 16;
  float hf = __uint_as_float(hi<<16);
  unsigned u2 = __float_as_uint(v - hf);
  unsigned lo = (u2 + 0x7fffu + ((u2>>16)&1u)) >> 16;
  return (hi<<16) | lo;
}
__device__ __forceinline__ void cvt8(uint4 v0, uint4 v1, short8v& h, short8v& l){
  unsigned a0=v0.x,a1=v0.y,a2=v0.z,a3=v0.w,a4=v1.x,a5=v1.y,a6=v1.z,a7=v1.w;
  h[0]=(short)(a0>>16); l[0]=(short)(a0&0xffffu);
  h[1]=(short)(a1>>16); l[1]=(short)(a1&0xffffu);
  h[2]=(short)(a2>>16); l[2]=(short)(a2&0xffffu);
  h[3]=(short)(a3>>16); l[3]=(short)(a3&0xffffu);
  h[4]=(short)(a4>>16); l[4]=(short)(a4&0xffffu);
  h[5]=(short)(a5>>16); l[5]=(short)(a5&0xffffu);
  h[6]=(short)(a6>>16); l[6]=(short)(a6&0xffffu);
  h[7]=(short)(a7>>16); l[7]=(short)(a7&0xffffu);
}

// ---- prep: fold BN scale into weights (f32, for gemv7) ----
__global__ void k_scale_rows(const float* __restrict__ W, const float* __restrict__ bn,
                             float* __restrict__ Wf, float* __restrict__ bias, int O, int C){
  int i = blockIdx.x*256 + threadIdx.x;
  if (i >= O*C) return;
  int o = i / C;
  float s = bn[o] / sqrtf(bn[3*O+o] + 1e-5f);
  Wf[i] = W[i]*s;
  if (i % C == 0) bias[o] = bn[O+o] - s*bn[2*O+o];
}

// pack scaled weights to (hi|lo) u32 [Opad][C]; rows >= O zero-padded
__global__ void k_pack_w(const float* __restrict__ W, int ldw, int c0,
                         const float* __restrict__ bn, int O, int C, int Opad,
                         unsigned* __restrict__ out, float* __restrict__ bias){
  int i = blockIdx.x*256 + threadIdx.x;
  if (i >= Opad*C) return;
  int o = i / C, c = i - o*C;
  float v = 0.f;
  if (o < O){
    float s = 1.f;
    if (bn != nullptr){
      s = bn[o] / sqrtf(bn[3*O+o] + 1e-5f);
      if (bias != nullptr && c == 0) bias[o] = bn[O+o] - s*bn[2*O+o];
    }
    v = W[o*ldw + c0 + c] * s;
  }
  out[i] = pack2(v);
}

// transposed float4-chunk layout: dst[(c/4)*256 + o*4 + c%4], O=64 fixed
__global__ void k_build_T4(const float* __restrict__ W, int ldw, const float* __restrict__ bn,
                           float* __restrict__ dst, float* __restrict__ bias,
                           int c0, int diffoff, int Csrc){
  int o = threadIdx.x, c = blockIdx.x;
  float s = bn[o] / sqrtf(bn[192+o] + 1e-5f);
  float val = 0.f;
  if (c < Csrc){
    val = W[o*ldw + c0 + c];
    if (diffoff) val = W[o*ldw + c0 + diffoff + c] - val;
    val *= s;
  }
  dst[(c>>2)*256 + o*4 + (c&3)] = val;
  if (bias != nullptr && c==0) bias[o] = bn[64+o] - s*bn[128+o];
}

// U1[b][k][o] = sum_{c<6} s_o*W1[o][c]*x[b][c][k]  (first-KNN neighbors are points 0..19)
__global__ void k_build_U1(const float* __restrict__ x, const float* __restrict__ W1,
                           const float* __restrict__ bn, float* __restrict__ U1){
  int o = threadIdx.x, k = blockIdx.x, b = blockIdx.y;
  float s = bn[o] / sqrtf(bn[192+o] + 1e-5f);
  float acc = 0.f;
  #pragma unroll
  for (int c=0;c<6;c++) acc += W1[o*12+c] * x[(b*6+c)*N_PTS + k];
  U1[(b*KNB+k)*64 + o] = acc*s;
}

// V1[pt][o] = s*((W1R-W1L)@x_pt)[o] + bias1[o]
__global__ __launch_bounds__(256) void k_v1(const float* __restrict__ x, const float* __restrict__ W1,
        const float* __restrict__ bn, float* __restrict__ V1){
  int o = threadIdx.x&63;
  int pt = blockIdx.x*4 + (threadIdx.x>>6);
  int b = pt>>12, n = pt&4095;
  float s = bn[o] / sqrtf(bn[192+o] + 1e-5f);
  float acc = bn[64+o] - s*bn[128+o];
  #pragma unroll
  for (int c=0;c<6;c++)
    acc += s*(W1[o*12+6+c]-W1[o*12+c]) * x[(b*6+c)*N_PTS + n];
  V1[(size_t)pt*64 + o] = acc;
}

__global__ void k_init_g(unsigned* g){ g[blockIdx.x*256+threadIdx.x] = fenc(-INFINITY); }

// ---- U/V precompute ----
__global__ __launch_bounds__(256) void k_uv(const float* __restrict__ xt, const float* __restrict__ WL,
    const float* __restrict__ WRd, const float* __restrict__ bf,
    float* __restrict__ Ut, float* __restrict__ Vt){
  __shared__ float xs[4][64];
  int wid = threadIdx.x>>6, lane = threadIdx.x&63;
  int pt = blockIdx.x*4 + wid;
  xs[wid][lane] = xt[(size_t)pt*64 + lane];
  __syncthreads();
  float U = 0.f, V = bf[lane];
  #pragma unroll
  for (int cb=0;cb<16;cb++){
    float4 wl = ((const float4*)WL)[cb*64+lane];
    float4 wr = ((const float4*)WRd)[cb*64+lane];
    float4 xv = *(const float4*)&xs[wid][cb*4];
    U=fmaf(wl.x,xv.x,U); U=fmaf(wl.y,xv.y,U); U=fmaf(wl.z,xv.z,U); U=fmaf(wl.w,xv.w,U);
    V=fmaf(wr.x,xv.x,V); V=fmaf(wr.y,xv.y,V); V=fmaf(wr.z,xv.z,V); V=fmaf(wr.w,xv.w,V);
  }
  Ut[(size_t)pt*64 + lane] = U;
  Vt[(size_t)pt*64 + lane] = V;
}

// ---- unified MFMA edge-conv: for each point, D[pt][o] = max_k conv(lrelu(U[m_k]+V[pt])) ----
// GATHER=0: U indexed [b][k][64] directly (edge1). GATHER=1: U gathered via idx (ec2).
// 64 points/block, 4 waves; double-buffered hi/lo bf16 h-tile; weights in VGPRs.
template<int GATHER>
__global__ __launch_bounds__(256) void k_edgemm(const float* __restrict__ Ut,
    const float* __restrict__ Vt, const int* __restrict__ idx,
    const unsigned* __restrict__ Wp, const float* __restrict__ bf,
    float* __restrict__ xout, unsigned* __restrict__ Xb, int coff,
    float* __restrict__ xxout){
  __shared__ short Hh[2][64][72];
  __shared__ short Hl[2][64][72];
  int tid = threadIdx.x;
  int b = blockIdx.z, p0 = blockIdx.x*64;
  int w = tid>>6, lane = tid&63, r15 = lane&15, rb = lane>>4;
  int ptl = tid>>2, c0 = (tid&3)*16;
  size_t ptg = ((size_t)b<<12) + p0 + ptl;
  float v[16];
  #pragma unroll
  for (int q=0;q<4;q++){
    float4 t = *(const float4*)&Vt[ptg*64 + c0 + q*4];
    v[q*4+0]=t.x; v[q*4+1]=t.y; v[q*4+2]=t.z; v[q*4+3]=t.w;
  }
  int mr[KNB];
  if (GATHER){
    const int4* ip4 = (const int4*)(idx + ptg*KNB);
    #pragma unroll
    for (int q=0;q<5;q++){ int4 t=ip4[q]; mr[q*4+0]=t.x; mr[q*4+1]=t.y; mr[q*4+2]=t.z; mr[q*4+3]=t.w; }
  }
  short8v wh[4][2], wl[4][2];
  #pragma unroll
  for (int oi=0;oi<4;oi++)
    #pragma unroll
    for (int ks=0;ks<2;ks++){
      const unsigned* pw = Wp + (size_t)(oi*16+r15)*64 + ks*32 + rb*8;
      uint4 w0 = *(const uint4*)pw, w1 = *(const uint4*)(pw+4);
      cvt8(w0,w1,wh[oi][ks],wl[oi][ks]);
    }
  f32x4 rmax[4];
  #pragma unroll
  for (int oi=0;oi<4;oi++) rmax[oi]=(f32x4){-INFINITY,-INFINITY,-INFINITY,-INFINITY};
  float uc[16], un[16];
  {
    const float* ur = GATHER ? (Ut + ((((size_t)b)<<12) + mr[0])*64 + c0)
                             : (Ut + ((size_t)b*KNB + 0)*64 + c0);
    #pragma unroll
    for (int q=0;q<4;q++){
      float4 t = *(const float4*)(ur + q*4);
      uc[q*4+0]=t.x; uc[q*4+1]=t.y; uc[q*4+2]=t.z; uc[q*4+3]=t.w;
    }
  }
  for (int k=0;k<KNB;k++){
    int buf = k&1;
    #pragma unroll
    for (int q=0;q<2;q++){
      short8v hh, hl;
      #pragma unroll
      for (int e=0;e<8;e++){
        unsigned pk = pack2(lrelu(uc[q*8+e] + v[q*8+e]));
        hh[e]=(short)(pk>>16); hl[e]=(short)(pk&0xffffu);
      }
      *(short8v*)&Hh[buf][ptl][c0+q*8] = hh;
      *(short8v*)&Hl[buf][ptl][c0+q*8] = hl;
    }
    if (k+1 < KNB){
      const float* ur = GATHER ? (Ut + ((((size_t)b)<<12) + mr[k+1])*64 + c0)
                               : (Ut + ((size_t)b*KNB + (k+1))*64 + c0);
      #pragma unroll
      for (int q=0;q<4;q++){
        float4 t = *(const float4*)(ur + q*4);
        un[q*4+0]=t.x; un[q*4+1]=t.y; un[q*4+2]=t.z; un[q*4+3]=t.w;
      }
    }
    __syncthreads();
    f32x4 acc[4];
    #pragma unroll
    for (int oi=0;oi<4;oi++) acc[oi]=(f32x4){0.f,0.f,0.f,0.f};
    #pragma unroll
    for (int ks=0;ks<2;ks++){
      short8v ah = *(const short8v*)&Hh[buf][w*16+r15][ks*32+rb*8];
      short8v al = *(const short8v*)&Hl[buf][w*16+r15][ks*32+rb*8];
      #pragma unroll
      for (int oi=0;oi<4;oi++){
        acc[oi] = __builtin_amdgcn_mfma_f32_16x16x32_bf16(ah, wh[oi][ks], acc[oi], 0,0,0);
        acc[oi] = __builtin_amdgcn_mfma_f32_16x16x32_bf16(ah, wl[oi][ks], acc[oi], 0,0,0);
        acc[oi] = __builtin_amdgcn_mfma_f32_16x16x32_bf16(al, wh[oi][ks], acc[oi], 0,0,0);
      }
    }
    #pragma unroll
    for (int oi=0;oi<4;oi++)
      #pragma unroll
      for (int r=0;r<4;r++) rmax[oi][r] = fmaxf(rmax[oi][r], acc[oi][r]);
    if (k+1 < KNB){
      #pragma unroll
      for (int e=0;e<16;e++) uc[e]=un[e];
    }
  }
  float xs[4] = {0.f,0.f,0.f,0.f};
  #pragma unroll
  for (int oi=0;oi<4;oi++){
    int o = oi*16 + r15;
    float bv = bf[o];
    #pragma unroll
    for (int r=0;r<4;r++){
      float y = lrelu(rmax[oi][r] + bv);
      size_t pg = ((size_t)b<<12) + p0 + w*16 + rb*4 + r;
      if (xout) xout[pg*64 + o] = y;
      Xb[pg*192 + coff + o] = pack2(y);
      xs[r] += y*y;
    }
  }
  if (xxout){
    #pragma unroll
    for (int r=0;r<4;r++){
      float s = xs[r];
      s += __shfl_xor(s,1); s += __shfl_xor(s,2); s += __shfl_xor(s,4); s += __shfl_xor(s,8);
      if (r15==0) xxout[((size_t)b<<12) + p0 + w*16 + rb*4 + r] = s;
    }
  }
}

// ---- edge block 3: x3[n] = lrelu(V5[n] + max_k U5[m_k]) -- pure gather+max ----
__global__ __launch_bounds__(256) void k_ec3(const float* __restrict__ Ut, const float* __restrict__ Vt,
    const int* __restrict__ idx, unsigned* __restrict__ Xb){
  int wid = threadIdx.x>>6, lane = threadIdx.x&63;
  int pt = blockIdx.x*4 + wid, b = pt>>12, n = pt&4095;
  const float* Ub = Ut + (((size_t)b)<<12)*64;
  int mr[KNB];
  const int4* ip4 = (const int4*)(idx + (size_t)pt*KNB);
  #pragma unroll
  for (int q=0;q<5;q++){ int4 t = ip4[q]; mr[q*4+0]=t.x; mr[q*4+1]=t.y; mr[q*4+2]=t.z; mr[q*4+3]=t.w; }
  float mx = -INFINITY;
  #pragma unroll
  for (int k=0;k<KNB;k++) mx = fmaxf(mx, Ub[(size_t)mr[k]*64 + lane]);
  mx = lrelu(mx + Vt[(size_t)pt*64 + lane]);
  Xb[((size_t)((b<<12)+n))*192 + 128 + lane] = pack2(mx);
}

// ---- KNN distance via split-bf16 MFMA: pd = fenc(fma(2,dot,-xx_n) - xx_m) ----
// Emits per-(row, 64-col-chunk) max via shfl reduce.
__global__ __launch_bounds__(512) void k_knn_mfma(const unsigned* __restrict__ Xp, int coff,
        const float* __restrict__ xx, unsigned* __restrict__ pd, unsigned* __restrict__ cmax,
        int q0, int S){
  __shared__ short Ah[128][40];
  __shared__ short Al[128][40];
  __shared__ short Bh[128][40];
  __shared__ short Bl[128][40];
  int tid = threadIdx.x;
  int bx = blockIdx.x, by = blockIdx.y, bz = blockIdx.z;
  int w = tid>>6, lane = tid&63;
  int r15 = lane&15, rb = lane>>4;
  int mibase = (w&3)*32, oibase = (w>>2)*64;
  f32x4 acc[2][4];
  #pragma unroll
  for (int mi=0;mi<2;mi++)
    #pragma unroll
    for (int oi=0;oi<4;oi++) acc[mi][oi] = (f32x4){0.f,0.f,0.f,0.f};
  int srow = tid>>2, sc = (tid&3)*8;
  const unsigned* pa = Xp + ((size_t)((bz<<12) + q0 + by*128 + srow))*192 + coff + sc;
  const unsigned* pb = Xp + ((size_t)((bz<<12) + bx*128 + srow))*192 + coff + sc;
  for (int kt=0; kt<64; kt+=32){
    if (kt) __syncthreads();
    uint4 a0 = *(const uint4*)(pa+kt);
    uint4 a1 = *(const uint4*)(pa+kt+4);
    uint4 b0 = *(const uint4*)(pb+kt);
    uint4 b1 = *(const uint4*)(pb+kt+4);
    short8v h, l;
    cvt8(a0,a1,h,l);
    *(short8v*)&Ah[srow][sc] = h; *(short8v*)&Al[srow][sc] = l;
    cvt8(b0,b1,h,l);
    *(short8v*)&Bh[srow][sc] = h; *(short8v*)&Bl[srow][sc] = l;
    __syncthreads();
    short8v ah[2], al[2];
    #pragma unroll
    for (int mi=0;mi<2;mi++){
      ah[mi] = *(const short8v*)&Ah[mibase+mi*16+r15][rb*8];
      al[mi] = *(const short8v*)&Al[mibase+mi*16+r15][rb*8];
    }
    #pragma unroll
    for (int oi=0;oi<4;oi++){
      short8v bh = *(const short8v*)&Bh[oibase+oi*16+r15][rb*8];
      short8v bl = *(const short8v*)&Bl[oibase+oi*16+r15][rb*8];
      #pragma unroll
      for (int mi=0;mi<2;mi++){
        acc[mi][oi] = __builtin_amdgcn_mfma_f32_16x16x32_bf16(ah[mi], bh, acc[mi][oi], 0,0,0);
        acc[mi][oi] = __builtin_amdgcn_mfma_f32_16x16x32_bf16(ah[mi], bl, acc[mi][oi], 0,0,0);
        acc[mi][oi] = __builtin_amdgcn_mfma_f32_16x16x32_bf16(al[mi], bh, acc[mi][oi], 0,0,0);
      }
    }
  }
  float xm[4];
  #pragma unroll
  for (int oi=0;oi<4;oi++) xm[oi] = xx[(bz<<12) + bx*128 + oibase + oi*16 + r15];
  #pragma unroll
  for (int mi=0;mi<2;mi++){
    #pragma unroll
    for (int r=0;r<4;r++){
      int row = by*128 + mibase + mi*16 + rb*4 + r;
      float xn = xx[(bz<<12) + q0 + row];
      float f0 = fmaf(2.f, acc[mi][0][r], -xn) - xm[0];
      float f1 = fmaf(2.f, acc[mi][1][r], -xn) - xm[1];
      float f2 = fmaf(2.f, acc[mi][2][r], -xn) - xm[2];
      float f3 = fmaf(2.f, acc[mi][3][r], -xn) - xm[3];
      unsigned* dst = pd + ((size_t)(bz*S + row))*N_PTS + bx*128 + oibase;
      dst[ 0+r15] = fenc(f0);
      dst[16+r15] = fenc(f1);
      dst[32+r15] = fenc(f2);
      dst[48+r15] = fenc(f3);
      float m = fmaxf(fmaxf(f0,f1), fmaxf(f2,f3));
      m = fmaxf(m, __shfl_xor(m,1));
      m = fmaxf(m, __shfl_xor(m,2));
      m = fmaxf(m, __shfl_xor(m,4));
      m = fmaxf(m, __shfl_xor(m,8));
      if (r15 == 0)
        cmax[((size_t)(bz<<12) + q0 + row)*64 + bx*2 + (oibase>>6)] = fenc(m);
    }
  }
}

__device__ __forceinline__ unsigned bitsort_u32(unsigned v, int lane){
  #pragma unroll
  for (int k=2;k<=64;k<<=1){
    #pragma unroll
    for (int j=k>>1;j>0;j>>=1){
      unsigned o = (unsigned)__shfl_xor((int)v, j);
      bool takeMax = (((lane & j) != 0) == ((lane & k) == 0));
      unsigned mx = v>o?v:o, mn = v<o?v:o;
      v = takeMax ? mx : mn;
    }
  }
  return v;   // ascending by lane
}

// ---- filtered top-20: chunk-max prefilter + streaming candidate selection ----
__global__ __launch_bounds__(256,4) void k_topk20(const unsigned* __restrict__ pdbuf,
        const unsigned* __restrict__ cmax, int* __restrict__ idxout, int q0, int sshift){
  __shared__ unsigned long long cand[4][64];
  int wid = threadIdx.x>>6, lane = threadIdx.x&63;
  int gw = blockIdx.x*4 + wid;
  int S = 1 << sshift;
  int b = gw >> sshift, i = gw & (S-1);
  const unsigned* row = pdbuf + ((size_t)b*S + i)*N_PTS;
  unsigned cm = cmax[((size_t)b*N_PTS + q0 + i)*64 + lane];
  unsigned T = (unsigned)__shfl((int)bitsort_u32(cm, lane), 44);
  unsigned long long qual = __ballot(cm >= T);
  unsigned lmax = 0u;
  for (int c=0;c<64;c++){
    if (!((qual>>c)&1ull)) continue;
    unsigned vv = row[c*64 + lane];
    lmax = lmax > vv ? lmax : vv;
  }
  unsigned T2 = (unsigned)__shfl((int)bitsort_u32(lmax, lane), 44);
  int base = 0;
  unsigned long long below = (1ull<<lane) - 1ull;
  for (int c=0;c<64;c++){
    if (!((qual>>c)&1ull)) continue;
    unsigned vv = row[c*64 + lane];
    bool isc = vv >= T2;
    unsigned long long mb = __ballot(isc);
    int pos = base + __popcll(mb & below);
    if (isc && pos < 64){
      int m = c*64 + lane;
      cand[wid][pos] = (((unsigned long long)vv)<<12) | (unsigned)(4095-m);
    }
    base += __popcll(mb);
  }
  unsigned long long K;
  if (base <= 64){
    unsigned long long kv = (lane < base) ? cand[wid][lane] : 0ull;
    #pragma unroll
    for (int k=2;k<=64;k<<=1){
      #pragma unroll
      for (int j=k>>1;j>0;j>>=1){
        unsigned long long o = __shfl_xor(kv, j);
        bool takeMax = (((lane & j) != 0) == ((lane & k) == 0));
        unsigned long long mx = kv>o?kv:o, mn = kv<o?kv:o;
        kv = takeMax ? mx : mn;
      }
    }
    K = __shfl(kv, 44);
  } else {
    K = 0ull;
    for (int bb2=43; bb2>=0; --bb2){
      unsigned long long cnd = K | (1ull<<bb2);
      int lc = 0;
      for (int c=0;c<64;c++){
        if (!((qual>>c)&1ull)) continue;
        unsigned vv = row[c*64 + lane];
        int m = c*64 + lane;
        unsigned long long key = (((unsigned long long)vv)<<12) | (unsigned)(4095-m);
        if (key >= cnd) lc++;
      }
      #pragma unroll
      for (int off=32; off; off>>=1) lc += __shfl_xor(lc, off);
      if (lc >= KNB) K = cnd;
    }
  }
  int eb = 0;
  int* dst = idxout + ((size_t)b*N_PTS + (q0+i))*KNB;
  for (int c=0;c<64;c++){
    if (!((qual>>c)&1ull)) continue;
    unsigned vv = row[c*64 + lane];
    int m = c*64 + lane;
    unsigned long long key = (((unsigned long long)vv)<<12) | (unsigned)(4095-m);
    bool sel = key >= K;
    unsigned long long mb = __ballot(sel);
    int pos = eb + __popcll(mb & below);
    if (sel) dst[pos] = m;
    eb += __popcll(mb);
  }
}

// ---- split-bf16 MFMA GEMM ----
// STORE: 0 = column-max only (gmax), 1 = packed u32 store [pt][ldo], 2 = f32 store to d_out (O=13)
template<int STORE, int RELU>
__global__ __launch_bounds__(512) void k_mgemm(const unsigned* __restrict__ Ap, int lda,
        const unsigned* __restrict__ Bp, int ldb,
        const float* __restrict__ bias, int perBatch,
        unsigned* __restrict__ Cp, int ldo, float* __restrict__ Cf,
        unsigned* __restrict__ gmax, int O, int K){
  __shared__ short Ah[128][40];
  __shared__ short Al[128][40];
  __shared__ short Bh[128][40];
  __shared__ short Bl[128][40];
  int tid = threadIdx.x;
  int bx = blockIdx.x, by = blockIdx.y, bz = blockIdx.z;
  int w = tid>>6, lane = tid&63;
  int r15 = lane&15, rb = lane>>4;
  int mibase = (w&3)*32, oibase = (w>>2)*64;
  f32x4 acc[2][4];
  #pragma unroll
  for (int mi=0;mi<2;mi++)
    #pragma unroll
    for (int oi=0;oi<4;oi++) acc[mi][oi] = (f32x4){0.f,0.f,0.f,0.f};
  int srow = tid>>2, sc = (tid&3)*8;
  const unsigned* pa = Ap + ((size_t)((bz<<12) + bx*128 + srow))*lda + sc;
  const unsigned* pb = Bp + (size_t)(by*128 + srow)*ldb + sc;
  for (int kt=0; kt<K; kt+=32){
    if (kt) __syncthreads();
    uint4 a0 = *(const uint4*)(pa+kt);
    uint4 a1 = *(const uint4*)(pa+kt+4);
    uint4 b0 = *(const uint4*)(pb+kt);
    uint4 b1 = *(const uint4*)(pb+kt+4);
    short8v h, l;
    cvt8(a0,a1,h,l);
    *(short8v*)&Ah[srow][sc] = h; *(short8v*)&Al[srow][sc] = l;
    cvt8(b0,b1,h,l);
    *(short8v*)&Bh[srow][sc] = h; *(short8v*)&Bl[srow][sc] = l;
    __syncthreads();
    short8v ah[2], al[2];
    #pragma unroll
    for (int mi=0;mi<2;mi++){
      ah[mi] = *(const short8v*)&Ah[mibase+mi*16+r15][rb*8];
      al[mi] = *(const short8v*)&Al[mibase+mi*16+r15][rb*8];
    }
    #pragma unroll
    for (int oi=0;oi<4;oi++){
      short8v bh = *(const short8v*)&Bh[oibase+oi*16+r15][rb*8];
      short8v bl = *(const short8v*)&Bl[oibase+oi*16+r15][rb*8];
      #pragma unroll
      for (int mi=0;mi<2;mi++){
        acc[mi][oi] = __builtin_amdgcn_mfma_f32_16x16x32_bf16(ah[mi], bh, acc[mi][oi], 0,0,0);
        acc[mi][oi] = __builtin_amdgcn_mfma_f32_16x16x32_bf16(ah[mi], bl, acc[mi][oi], 0,0,0);
        acc[mi][oi] = __builtin_amdgcn_mfma_f32_16x16x32_bf16(al[mi], bh, acc[mi][oi], 0,0,0);
      }
    }
  }
  #pragma unroll
  for (int oi=0;oi<4;oi++){
    int o = by*128 + oibase + oi*16 + r15;
    float bv = 0.f;
    if (bias != nullptr) bv = perBatch ? bias[bz*O + o] : bias[o];
    float cmx = -INFINITY;
    #pragma unroll
    for (int mi=0;mi<2;mi++){
      #pragma unroll
      for (int r=0;r<4;r++){
        float y = acc[mi][oi][r] + bv;
        if (RELU) y = lrelu(y);
        if (STORE==1){
          int pt = bx*128 + mibase + mi*16 + rb*4 + r;
          Cp[((size_t)((bz<<12)+pt))*ldo + o] = pack2(y);
        } else if (STORE==2){
          if (o < 13){
            int pt = bx*128 + mibase + mi*16 + rb*4 + r;
            Cf[(((size_t)(bz*13 + o))<<12) + pt] = y;
          }
        } else {
          cmx = fmaxf(cmx, y);
        }
      }
    }
    if (STORE==0){
      cmx = fmaxf(cmx, __shfl_xor(cmx,16));
      cmx = fmaxf(cmx, __shfl_xor(cmx,32));
      if (rb==0) atomicMax(&gmax[bz*1024 + o], fenc(cmx));
    }
  }
}

// bias7[b][o] = sum_{c<1024} Wf7[o][c]*g[b][c] + bf7[o]
__global__ __launch_bounds__(256) void k_gemv7(const float* __restrict__ Wf7, const float* __restrict__ bf7,
                        const unsigned* __restrict__ g, float* __restrict__ bias7){
  int wid = threadIdx.x>>6, lane = threadIdx.x&63;
  int o = blockIdx.x*4 + wid, b = blockIdx.y;
  const float* wr = Wf7 + (size_t)o*1216;
  const unsigned* gb = g + b*1024;
  float acc = 0.f;
  for (int c = lane; c < 1024; c += 64)
    acc = fmaf(wr[c], fdec(gb[c]), acc);
  #pragma unroll
  for (int off=32; off; off>>=1) acc += __shfl_xor(acc, off);
  if (lane==0) bias7[b*512+o] = acc + bf7[o];
}

extern "C" void kernel_launch(void* const* d_in, const int* in_sizes, int n_in,
                              void* d_out, int out_size, void* d_ws, size_t ws_size,
                              hipStream_t stream){
  const float* x  = (const float*)d_in[0];
  const float* W1 = (const float*)d_in[1];
  const float* W2 = (const float*)d_in[2];
  const float* W3 = (const float*)d_in[3];
  const float* W4 = (const float*)d_in[4];
  const float* W5 = (const float*)d_in[5];
  const float* W6 = (const float*)d_in[6];
  const float* W7 = (const float*)d_in[7];
  const float* W8 = (const float*)d_in[8];
  const float* W9 = (const float*)d_in[9];
  const float* bn1 = (const float*)d_in[10];
  const float* bn2 = (const float*)d_in[11];
  const float* bn3 = (const float*)d_in[12];
  const float* bn4 = (const float*)d_in[13];
  const float* bn5 = (const float*)d_in[14];
  const float* bn6 = (const float*)d_in[15];
  const float* bn7 = (const float*)d_in[16];
  const float* bn8 = (const float*)d_in[17];

  float* ws = (float*)d_ws;
  size_t off = 0;
  auto alloc = [&](size_t nf){ float* p = ws + off; off += (nf + 63) & ~(size_t)63; return p; };
  float* Wf7 = alloc((size_t)512*1216); float* bf7 = alloc(512);
  float* bf6 = alloc(1024);
  float* bf8 = alloc(256);
  float* bf2 = alloc(64);
  float* bf4 = alloc(64);
  unsigned* Wb2p = (unsigned*)alloc((size_t)64*64);
  unsigned* Wb4p = (unsigned*)alloc((size_t)64*64);
  unsigned* Wb6p = (unsigned*)alloc((size_t)1024*192);
  unsigned* Wb7p = (unsigned*)alloc((size_t)512*192);
  unsigned* Wb8p = (unsigned*)alloc((size_t)256*512);
  unsigned* Wb9p = (unsigned*)alloc((size_t)128*256);
  float* W3LT4 = alloc(64*64);    float* W3RdT4 = alloc(64*64); float* bf3 = alloc(64);
  float* W5LT4 = alloc(64*64);    float* W5RdT4 = alloc(64*64); float* bf5 = alloc(64);
  float* U1  = alloc(4*KNB*64);
  float* V1  = alloc((size_t)4*N_PTS*64);
  float* x1t = alloc((size_t)4*N_PTS*64);
  float* x2t = alloc((size_t)4*N_PTS*64);
  float* Ut3 = alloc((size_t)4*N_PTS*64);
  float* Vt3 = alloc((size_t)4*N_PTS*64);
  float* Ut5 = alloc((size_t)4*N_PTS*64);
  float* Vt5 = alloc((size_t)4*N_PTS*64);
  unsigned* Xb = (unsigned*)alloc((size_t)4*N_PTS*192);   // packed activations [n][192]
  float* xx1 = alloc(4*N_PTS);
  float* xx2 = alloc(4*N_PTS);
  int* idx1 = (int*)alloc((size_t)4*N_PTS*KNB);
  int* idx2 = (int*)alloc((size_t)4*N_PTS*KNB);
  unsigned* genc = (unsigned*)alloc(4*1024);
  float* bias7 = alloc(4*512);
  unsigned* h8p = (unsigned*)alloc((size_t)4*N_PTS*256);  // packed conv8 out [n][256]
  unsigned* cmaxb = (unsigned*)alloc((size_t)4*N_PTS*64);
  // pdbuf stripe: cap at S=1024 (64 MB, L3-resident sweet spot)
  size_t remaining = (ws_size / 4 > off) ? (ws_size / 4 - off) : 0;
  int S = 4096;
  while (S > 512 && (size_t)4*S*N_PTS + 1024 > remaining) S >>= 1;
  if (S > 1024) S = 1024;
  int sshift = 31 - __builtin_clz(S);
  unsigned* pdbuf = (unsigned*)alloc((size_t)4*S*N_PTS);   // encoded u32; reused as h7p (needs 32MB)
  unsigned* h7p = pdbuf;                                    // packed conv7 out [n][512]

  // prep (every call: deterministic)
  k_scale_rows<<<(512*1216+255)/256,256,0,stream>>>(W7, bn7, Wf7, bf7, 512, 1216);
  k_pack_w<<<(64*64+255)/256,256,0,stream>>>(W2, 64, 0, bn2, 64, 64, 64, Wb2p, bf2);
  k_pack_w<<<(64*64+255)/256,256,0,stream>>>(W4, 64, 0, bn4, 64, 64, 64, Wb4p, bf4);
  k_pack_w<<<(1024*192+255)/256,256,0,stream>>>(W6, 192, 0, bn6, 1024, 192, 1024, Wb6p, bf6);
  k_pack_w<<<(512*192+255)/256,256,0,stream>>>(W7, 1216, 1024, bn7, 512, 192, 512, Wb7p, nullptr);
  k_pack_w<<<(256*512+255)/256,256,0,stream>>>(W8, 512, 0, bn8, 256, 512, 256, Wb8p, bf8);
  k_pack_w<<<(128*256+255)/256,256,0,stream>>>(W9, 256, 0, nullptr, 13, 256, 128, Wb9p, nullptr);
  k_build_T4<<<64,64,0,stream>>>(W3, 128, bn3, W3LT4, bf3, 0, 0, 64);
  k_build_T4<<<64,64,0,stream>>>(W3, 128, bn3, W3RdT4, nullptr, 0, 64, 64);  // (W3R-W3L)*s
  k_build_T4<<<64,64,0,stream>>>(W5, 128, bn5, W5LT4, bf5, 0, 0, 64);
  k_build_T4<<<64,64,0,stream>>>(W5, 128, bn5, W5RdT4, nullptr, 0, 64, 64);  // (W5R-W5L)*s
  k_build_U1<<<dim3(KNB,4),64,0,stream>>>(x, W1, bn1, U1);
  k_v1<<<4096,256,0,stream>>>(x, W1, bn1, V1);
  k_init_g<<<16,256,0,stream>>>(genc);

  // edge block 1: MFMA edge-conv (neighbors = points 0..19, U1 indexed by k)
  k_edgemm<0><<<dim3(64,1,4),256,0,stream>>>(U1, V1, nullptr, Wb2p, bf2, x1t, Xb, 0, xx1);

  int nstripe = N_PTS / S;
  // KNN on x1 (packed cols 0..63 of Xb)
  for (int s=0;s<nstripe;s++){
    k_knn_mfma<<<dim3(32,S/128,4),512,0,stream>>>(Xb, 0, xx1, pdbuf, cmaxb, s*S, S);
    k_topk20<<<S,256,0,stream>>>(pdbuf, cmaxb, idx1, s*S, sshift);
  }

  // edge block 2: U3/V3 then MFMA edge-conv with gather
  k_uv<<<4096,256,0,stream>>>(x1t, W3LT4, W3RdT4, bf3, Ut3, Vt3);
  k_edgemm<1><<<dim3(64,1,4),256,0,stream>>>(Ut3, Vt3, idx1, Wb4p, bf4, x2t, Xb, 64, xx2);

  // KNN on x2 (packed cols 64..127 of Xb)
  for (int s=0;s<nstripe;s++){
    k_knn_mfma<<<dim3(32,S/128,4),512,0,stream>>>(Xb, 64, xx2, pdbuf, cmaxb, s*S, S);
    k_topk20<<<S,256,0,stream>>>(pdbuf, cmaxb, idx2, s*S, sshift);
  }

  // edge block 3: U5/V5 then pure gather+max
  k_uv<<<4096,256,0,stream>>>(x2t, W5LT4, W5RdT4, bf5, Ut5, Vt5);
  k_ec3<<<4096,256,0,stream>>>(Ut5, Vt5, idx2, Xb);

  // conv6 (1024x192) -> only column max g (MFMA, gmax atomic)
  k_mgemm<0,1><<<dim3(32,8,4),512,0,stream>>>(Xb, 192, Wb6p, 192, bf6, 0, nullptr, 0, nullptr, genc, 1024, 192);
  // bias7[b][o] = W7[:, :1024] @ g + bf7
  k_gemv7<<<dim3(128,4),256,0,stream>>>(Wf7, bf7, genc, bias7);
  // conv7: W7[:, 1024:1216] @ X + bias7 (per batch) -> packed h7
  k_mgemm<1,1><<<dim3(32,4,4),512,0,stream>>>(Xb, 192, Wb7p, 192, bias7, 1, h7p, 512, nullptr, nullptr, 512, 192);
  // conv8: 256x512 -> packed h8
  k_mgemm<1,1><<<dim3(32,2,4),512,0,stream>>>(h7p, 512, Wb8p, 512, bf8, 0, h8p, 256, nullptr, nullptr, 256, 512);
  // conv9: 13x256 (padded to 128), no bias/relu -> d_out f32
  k_mgemm<2,0><<<dim3(32,1,4),512,0,stream>>>(h8p, 256, Wb9p, 256, nullptr, 0, nullptr, 0, (float*)d_out, nullptr, 13, 256);
}

// Round 14
// 532.232 us; speedup vs baseline: 2.3862x; 1.0547x over previous
//
#include <hip/hip_runtime.h>
#include <math.h>

#define N_PTS 4096
#define BATCH 4
#define KNB 20

typedef __attribute__((ext_vector_type(8))) short short8v;   // 8 bf16
typedef __attribute__((ext_vector_type(4))) float f32x4;

__device__ __forceinline__ float lrelu(float v){ return fmaxf(v, 0.2f*v); }
__device__ __forceinline__ unsigned fenc(float f){ unsigned u=__float_as_uint(f); return (u&0x80000000u)?~u:(u|0x80000000u); }
__device__ __forceinline__ float fdec(unsigned k){ return (k&0x80000000u)?__uint_as_float(k&0x7fffffffu):__uint_as_float(~k); }

// split f32 -> packed (bf16_hi << 16) | bf16_lo,  v ~= hi + lo, err ~2^-18 rel
__device__ __forceinline__ unsigned pack2(float v){
  unsigned u = __float_as_uint(v);
  unsigned hi = (u + 0x7fffu + ((u>>16)&1u)) >> 16;
  float hf = __uint_as_float(hi<<16);
  unsigned u2 = __float_as_uint(v - hf);
  unsigned lo = (u2 + 0x7fffu + ((u2>>16)&1u)) >> 16;
  return (hi<<16) | lo;
}
__device__ __forceinline__ void cvt8(uint4 v0, uint4 v1, short8v& h, short8v& l){
  unsigned a0=v0.x,a1=v0.y,a2=v0.z,a3=v0.w,a4=v1.x,a5=v1.y,a6=v1.z,a7=v1.w;
  h[0]=(short)(a0>>16); l[0]=(short)(a0&0xffffu);
  h[1]=(short)(a1>>16); l[1]=(short)(a1&0xffffu);
  h[2]=(short)(a2>>16); l[2]=(short)(a2&0xffffu);
  h[3]=(short)(a3>>16); l[3]=(short)(a3&0xffffu);
  h[4]=(short)(a4>>16); l[4]=(short)(a4&0xffffu);
  h[5]=(short)(a5>>16); l[5]=(short)(a5&0xffffu);
  h[6]=(short)(a6>>16); l[6]=(short)(a6&0xffffu);
  h[7]=(short)(a7>>16); l[7]=(short)(a7&0xffffu);
}

// ---- prep device bodies (byte-identical math to the proven standalone kernels) ----
__device__ __forceinline__ void d_scale_rows(int blk, int tid, const float* W, const float* bn,
                                             float* Wf, float* bias, int O, int C){
  int i = blk*256 + tid;
  if (i >= O*C) return;
  int o = i / C;
  float s = bn[o] / sqrtf(bn[3*O+o] + 1e-5f);
  Wf[i] = W[i]*s;
  if (i % C == 0) bias[o] = bn[O+o] - s*bn[2*O+o];
}

__device__ __forceinline__ void d_pack_w(int blk, int tid, const float* W, int ldw, int c0,
                                         const float* bn, int O, int C, int Opad,
                                         unsigned* out, float* bias){
  int i = blk*256 + tid;
  if (i >= Opad*C) return;
  int o = i / C, c = i - o*C;
  float v = 0.f;
  if (o < O){
    float s = 1.f;
    if (bn != nullptr){
      s = bn[o] / sqrtf(bn[3*O+o] + 1e-5f);
      if (bias != nullptr && c == 0) bias[o] = bn[O+o] - s*bn[2*O+o];
    }
    v = W[o*ldw + c0 + c] * s;
  }
  out[i] = pack2(v);
}

// transposed float4-chunk layout: dst[(c/4)*256 + o*4 + c%4], O=64 fixed; 16 blocks x 256 thr
__device__ __forceinline__ void d_build_T4(int blk, int tid, const float* W, int ldw,
                                           const float* bn, float* dst, float* bias,
                                           int c0, int diffoff, int Csrc){
  int o = tid & 63, c = blk*4 + (tid>>6);
  float s = bn[o] / sqrtf(bn[192+o] + 1e-5f);
  float val = 0.f;
  if (c < Csrc){
    val = W[o*ldw + c0 + c];
    if (diffoff) val = W[o*ldw + c0 + diffoff + c] - val;
    val *= s;
  }
  dst[(c>>2)*256 + o*4 + (c&3)] = val;
  if (bias != nullptr && c==0) bias[o] = bn[64+o] - s*bn[128+o];
}

// U1[b][k][o]; 20 blocks x 256 thr (4 waves = 4 flat (k,b) slots each)
__device__ __forceinline__ void d_build_U1(int blk, int tid, const float* x, const float* W1,
                                           const float* bn, float* U1){
  int w = tid>>6, o = tid&63;
  int flat = blk*4 + w;           // 0..79
  int k = flat >> 2, b = flat & 3;
  float s = bn[o] / sqrtf(bn[192+o] + 1e-5f);
  float acc = 0.f;
  #pragma unroll
  for (int c=0;c<6;c++) acc += W1[o*12+c] * x[(b*6+c)*N_PTS + k];
  U1[(b*KNB+k)*64 + o] = acc*s;
}

// V1[pt][o]; 4096 blocks x 256 thr
__device__ __forceinline__ void d_v1(int blk, int tid, const float* x, const float* W1,
                                     const float* bn, float* V1){
  int o = tid&63;
  int pt = blk*4 + (tid>>6);
  int b = pt>>12, n = pt&4095;
  float s = bn[o] / sqrtf(bn[192+o] + 1e-5f);
  float acc = bn[64+o] - s*bn[128+o];
  #pragma unroll
  for (int c=0;c<6;c++)
    acc += s*(W1[o*12+6+c]-W1[o*12+c]) * x[(b*6+c)*N_PTS + n];
  V1[(size_t)pt*64 + o] = acc;
}

// ---- single merged prep kernel: block-range dispatch over 14 independent sub-tasks ----
// segs: 2432 scale7 | 16 pk2 | 16 pk4 | 768 pk6 | 384 pk7 | 512 pk8 | 128 pk9 |
//       16 T4(3L) | 16 T4(3Rd) | 16 T4(5L) | 16 T4(5Rd) | 20 U1 | 4096 V1 | 16 initg = 8452
__global__ __launch_bounds__(256) void k_prep(
    const float* __restrict__ x,  const float* __restrict__ W1,
    const float* __restrict__ W2, const float* __restrict__ W3,
    const float* __restrict__ W4, const float* __restrict__ W5,
    const float* __restrict__ W6, const float* __restrict__ W7,
    const float* __restrict__ W8, const float* __restrict__ W9,
    const float* __restrict__ bn1, const float* __restrict__ bn2,
    const float* __restrict__ bn3, const float* __restrict__ bn4,
    const float* __restrict__ bn5, const float* __restrict__ bn6,
    const float* __restrict__ bn7, const float* __restrict__ bn8,
    float* Wf7, float* bf7,
    unsigned* Wb2p, float* bf2, unsigned* Wb4p, float* bf4,
    unsigned* Wb6p, float* bf6, unsigned* Wb7p,
    unsigned* Wb8p, float* bf8, unsigned* Wb9p,
    float* W3LT4, float* bf3, float* W3RdT4,
    float* W5LT4, float* bf5, float* W5RdT4,
    float* U1, float* V1, unsigned* genc){
  int blk = blockIdx.x, tid = threadIdx.x;
  if (blk < 2432){ d_scale_rows(blk, tid, W7, bn7, Wf7, bf7, 512, 1216); return; }
  blk -= 2432;
  if (blk < 16){ d_pack_w(blk, tid, W2, 64, 0, bn2, 64, 64, 64, Wb2p, bf2); return; }
  blk -= 16;
  if (blk < 16){ d_pack_w(blk, tid, W4, 64, 0, bn4, 64, 64, 64, Wb4p, bf4); return; }
  blk -= 16;
  if (blk < 768){ d_pack_w(blk, tid, W6, 192, 0, bn6, 1024, 192, 1024, Wb6p, bf6); return; }
  blk -= 768;
  if (blk < 384){ d_pack_w(blk, tid, W7, 1216, 1024, bn7, 512, 192, 512, Wb7p, nullptr); return; }
  blk -= 384;
  if (blk < 512){ d_pack_w(blk, tid, W8, 512, 0, bn8, 256, 512, 256, Wb8p, bf8); return; }
  blk -= 512;
  if (blk < 128){ d_pack_w(blk, tid, W9, 256, 0, nullptr, 13, 256, 128, Wb9p, nullptr); return; }
  blk -= 128;
  if (blk < 16){ d_build_T4(blk, tid, W3, 128, bn3, W3LT4, bf3, 0, 0, 64); return; }
  blk -= 16;
  if (blk < 16){ d_build_T4(blk, tid, W3, 128, bn3, W3RdT4, nullptr, 0, 64, 64); return; }
  blk -= 16;
  if (blk < 16){ d_build_T4(blk, tid, W5, 128, bn5, W5LT4, bf5, 0, 0, 64); return; }
  blk -= 16;
  if (blk < 16){ d_build_T4(blk, tid, W5, 128, bn5, W5RdT4, nullptr, 0, 64, 64); return; }
  blk -= 16;
  if (blk < 20){ d_build_U1(blk, tid, x, W1, bn1, U1); return; }
  blk -= 20;
  if (blk < 4096){ d_v1(blk, tid, x, W1, bn1, V1); return; }
  blk -= 4096;
  genc[blk*256 + tid] = fenc(-INFINITY);
}

// ---- U/V precompute ----
__global__ __launch_bounds__(256) void k_uv(const float* __restrict__ xt, const float* __restrict__ WL,
    const float* __restrict__ WRd, const float* __restrict__ bf,
    float* __restrict__ Ut, float* __restrict__ Vt){
  __shared__ float xs[4][64];
  int wid = threadIdx.x>>6, lane = threadIdx.x&63;
  int pt = blockIdx.x*4 + wid;
  xs[wid][lane] = xt[(size_t)pt*64 + lane];
  __syncthreads();
  float U = 0.f, V = bf[lane];
  #pragma unroll
  for (int cb=0;cb<16;cb++){
    float4 wl = ((const float4*)WL)[cb*64+lane];
    float4 wr = ((const float4*)WRd)[cb*64+lane];
    float4 xv = *(const float4*)&xs[wid][cb*4];
    U=fmaf(wl.x,xv.x,U); U=fmaf(wl.y,xv.y,U); U=fmaf(wl.z,xv.z,U); U=fmaf(wl.w,xv.w,U);
    V=fmaf(wr.x,xv.x,V); V=fmaf(wr.y,xv.y,V); V=fmaf(wr.z,xv.z,V); V=fmaf(wr.w,xv.w,V);
  }
  Ut[(size_t)pt*64 + lane] = U;
  Vt[(size_t)pt*64 + lane] = V;
}

// ---- unified MFMA edge-conv: for each point, D[pt][o] = max_k conv(lrelu(U[m_k]+V[pt])) ----
template<int GATHER>
__global__ __launch_bounds__(256) void k_edgemm(const float* __restrict__ Ut,
    const float* __restrict__ Vt, const int* __restrict__ idx,
    const unsigned* __restrict__ Wp, const float* __restrict__ bf,
    float* __restrict__ xout, unsigned* __restrict__ Xb, int coff,
    float* __restrict__ xxout){
  __shared__ short Hh[2][64][72];
  __shared__ short Hl[2][64][72];
  int tid = threadIdx.x;
  int b = blockIdx.z, p0 = blockIdx.x*64;
  int w = tid>>6, lane = tid&63, r15 = lane&15, rb = lane>>4;
  int ptl = tid>>2, c0 = (tid&3)*16;
  size_t ptg = ((size_t)b<<12) + p0 + ptl;
  float v[16];
  #pragma unroll
  for (int q=0;q<4;q++){
    float4 t = *(const float4*)&Vt[ptg*64 + c0 + q*4];
    v[q*4+0]=t.x; v[q*4+1]=t.y; v[q*4+2]=t.z; v[q*4+3]=t.w;
  }
  int mr[KNB];
  if (GATHER){
    const int4* ip4 = (const int4*)(idx + ptg*KNB);
    #pragma unroll
    for (int q=0;q<5;q++){ int4 t=ip4[q]; mr[q*4+0]=t.x; mr[q*4+1]=t.y; mr[q*4+2]=t.z; mr[q*4+3]=t.w; }
  }
  short8v wh[4][2], wl[4][2];
  #pragma unroll
  for (int oi=0;oi<4;oi++)
    #pragma unroll
    for (int ks=0;ks<2;ks++){
      const unsigned* pw = Wp + (size_t)(oi*16+r15)*64 + ks*32 + rb*8;
      uint4 w0 = *(const uint4*)pw, w1 = *(const uint4*)(pw+4);
      cvt8(w0,w1,wh[oi][ks],wl[oi][ks]);
    }
  f32x4 rmax[4];
  #pragma unroll
  for (int oi=0;oi<4;oi++) rmax[oi]=(f32x4){-INFINITY,-INFINITY,-INFINITY,-INFINITY};
  float uc[16], un[16];
  {
    const float* ur = GATHER ? (Ut + ((((size_t)b)<<12) + mr[0])*64 + c0)
                             : (Ut + ((size_t)b*KNB + 0)*64 + c0);
    #pragma unroll
    for (int q=0;q<4;q++){
      float4 t = *(const float4*)(ur + q*4);
      uc[q*4+0]=t.x; uc[q*4+1]=t.y; uc[q*4+2]=t.z; uc[q*4+3]=t.w;
    }
  }
  for (int k=0;k<KNB;k++){
    int buf = k&1;
    #pragma unroll
    for (int q=0;q<2;q++){
      short8v hh, hl;
      #pragma unroll
      for (int e=0;e<8;e++){
        unsigned pk = pack2(lrelu(uc[q*8+e] + v[q*8+e]));
        hh[e]=(short)(pk>>16); hl[e]=(short)(pk&0xffffu);
      }
      *(short8v*)&Hh[buf][ptl][c0+q*8] = hh;
      *(short8v*)&Hl[buf][ptl][c0+q*8] = hl;
    }
    if (k+1 < KNB){
      const float* ur = GATHER ? (Ut + ((((size_t)b)<<12) + mr[k+1])*64 + c0)
                               : (Ut + ((size_t)b*KNB + (k+1))*64 + c0);
      #pragma unroll
      for (int q=0;q<4;q++){
        float4 t = *(const float4*)(ur + q*4);
        un[q*4+0]=t.x; un[q*4+1]=t.y; un[q*4+2]=t.z; un[q*4+3]=t.w;
      }
    }
    __syncthreads();
    f32x4 acc[4];
    #pragma unroll
    for (int oi=0;oi<4;oi++) acc[oi]=(f32x4){0.f,0.f,0.f,0.f};
    #pragma unroll
    for (int ks=0;ks<2;ks++){
      short8v ah = *(const short8v*)&Hh[buf][w*16+r15][ks*32+rb*8];
      short8v al = *(const short8v*)&Hl[buf][w*16+r15][ks*32+rb*8];
      #pragma unroll
      for (int oi=0;oi<4;oi++){
        acc[oi] = __builtin_amdgcn_mfma_f32_16x16x32_bf16(ah, wh[oi][ks], acc[oi], 0,0,0);
        acc[oi] = __builtin_amdgcn_mfma_f32_16x16x32_bf16(ah, wl[oi][ks], acc[oi], 0,0,0);
        acc[oi] = __builtin_amdgcn_mfma_f32_16x16x32_bf16(al, wh[oi][ks], acc[oi], 0,0,0);
      }
    }
    #pragma unroll
    for (int oi=0;oi<4;oi++)
      #pragma unroll
      for (int r=0;r<4;r++) rmax[oi][r] = fmaxf(rmax[oi][r], acc[oi][r]);
    if (k+1 < KNB){
      #pragma unroll
      for (int e=0;e<16;e++) uc[e]=un[e];
    }
  }
  float xs[4] = {0.f,0.f,0.f,0.f};
  #pragma unroll
  for (int oi=0;oi<4;oi++){
    int o = oi*16 + r15;
    float bv = bf[o];
    #pragma unroll
    for (int r=0;r<4;r++){
      float y = lrelu(rmax[oi][r] + bv);
      size_t pg = ((size_t)b<<12) + p0 + w*16 + rb*4 + r;
      if (xout) xout[pg*64 + o] = y;
      Xb[pg*192 + coff + o] = pack2(y);
      xs[r] += y*y;
    }
  }
  if (xxout){
    #pragma unroll
    for (int r=0;r<4;r++){
      float s = xs[r];
      s += __shfl_xor(s,1); s += __shfl_xor(s,2); s += __shfl_xor(s,4); s += __shfl_xor(s,8);
      if (r15==0) xxout[((size_t)b<<12) + p0 + w*16 + rb*4 + r] = s;
    }
  }
}

// ---- edge block 3: x3[n] = lrelu(V5[n] + max_k U5[m_k]) -- pure gather+max ----
__global__ __launch_bounds__(256) void k_ec3(const float* __restrict__ Ut, const float* __restrict__ Vt,
    const int* __restrict__ idx, unsigned* __restrict__ Xb){
  int wid = threadIdx.x>>6, lane = threadIdx.x&63;
  int pt = blockIdx.x*4 + wid, b = pt>>12, n = pt&4095;
  const float* Ub = Ut + (((size_t)b)<<12)*64;
  int mr[KNB];
  const int4* ip4 = (const int4*)(idx + (size_t)pt*KNB);
  #pragma unroll
  for (int q=0;q<5;q++){ int4 t = ip4[q]; mr[q*4+0]=t.x; mr[q*4+1]=t.y; mr[q*4+2]=t.z; mr[q*4+3]=t.w; }
  float mx = -INFINITY;
  #pragma unroll
  for (int k=0;k<KNB;k++) mx = fmaxf(mx, Ub[(size_t)mr[k]*64 + lane]);
  mx = lrelu(mx + Vt[(size_t)pt*64 + lane]);
  Xb[((size_t)((b<<12)+n))*192 + 128 + lane] = pack2(mx);
}

// ---- KNN distance via split-bf16 MFMA: pd = fenc(fma(2,dot,-xx_n) - xx_m) ----
// Emits per-(row, 64-col-chunk) max via shfl reduce.
__global__ __launch_bounds__(512) void k_knn_mfma(const unsigned* __restrict__ Xp, int coff,
        const float* __restrict__ xx, unsigned* __restrict__ pd, unsigned* __restrict__ cmax,
        int q0, int S){
  __shared__ short Ah[128][40];
  __shared__ short Al[128][40];
  __shared__ short Bh[128][40];
  __shared__ short Bl[128][40];
  int tid = threadIdx.x;
  int bx = blockIdx.x, by = blockIdx.y, bz = blockIdx.z;
  int w = tid>>6, lane = tid&63;
  int r15 = lane&15, rb = lane>>4;
  int mibase = (w&3)*32, oibase = (w>>2)*64;
  f32x4 acc[2][4];
  #pragma unroll
  for (int mi=0;mi<2;mi++)
    #pragma unroll
    for (int oi=0;oi<4;oi++) acc[mi][oi] = (f32x4){0.f,0.f,0.f,0.f};
  int srow = tid>>2, sc = (tid&3)*8;
  const unsigned* pa = Xp + ((size_t)((bz<<12) + q0 + by*128 + srow))*192 + coff + sc;
  const unsigned* pb = Xp + ((size_t)((bz<<12) + bx*128 + srow))*192 + coff + sc;
  for (int kt=0; kt<64; kt+=32){
    if (kt) __syncthreads();
    uint4 a0 = *(const uint4*)(pa+kt);
    uint4 a1 = *(const uint4*)(pa+kt+4);
    uint4 b0 = *(const uint4*)(pb+kt);
    uint4 b1 = *(const uint4*)(pb+kt+4);
    short8v h, l;
    cvt8(a0,a1,h,l);
    *(short8v*)&Ah[srow][sc] = h; *(short8v*)&Al[srow][sc] = l;
    cvt8(b0,b1,h,l);
    *(short8v*)&Bh[srow][sc] = h; *(short8v*)&Bl[srow][sc] = l;
    __syncthreads();
    short8v ah[2], al[2];
    #pragma unroll
    for (int mi=0;mi<2;mi++){
      ah[mi] = *(const short8v*)&Ah[mibase+mi*16+r15][rb*8];
      al[mi] = *(const short8v*)&Al[mibase+mi*16+r15][rb*8];
    }
    #pragma unroll
    for (int oi=0;oi<4;oi++){
      short8v bh = *(const short8v*)&Bh[oibase+oi*16+r15][rb*8];
      short8v bl = *(const short8v*)&Bl[oibase+oi*16+r15][rb*8];
      #pragma unroll
      for (int mi=0;mi<2;mi++){
        acc[mi][oi] = __builtin_amdgcn_mfma_f32_16x16x32_bf16(ah[mi], bh, acc[mi][oi], 0,0,0);
        acc[mi][oi] = __builtin_amdgcn_mfma_f32_16x16x32_bf16(ah[mi], bl, acc[mi][oi], 0,0,0);
        acc[mi][oi] = __builtin_amdgcn_mfma_f32_16x16x32_bf16(al[mi], bh, acc[mi][oi], 0,0,0);
      }
    }
  }
  float xm[4];
  #pragma unroll
  for (int oi=0;oi<4;oi++) xm[oi] = xx[(bz<<12) + bx*128 + oibase + oi*16 + r15];
  #pragma unroll
  for (int mi=0;mi<2;mi++){
    #pragma unroll
    for (int r=0;r<4;r++){
      int row = by*128 + mibase + mi*16 + rb*4 + r;
      float xn = xx[(bz<<12) + q0 + row];
      float f0 = fmaf(2.f, acc[mi][0][r], -xn) - xm[0];
      float f1 = fmaf(2.f, acc[mi][1][r], -xn) - xm[1];
      float f2 = fmaf(2.f, acc[mi][2][r], -xn) - xm[2];
      float f3 = fmaf(2.f, acc[mi][3][r], -xn) - xm[3];
      unsigned* dst = pd + ((size_t)(bz*S + row))*N_PTS + bx*128 + oibase;
      dst[ 0+r15] = fenc(f0);
      dst[16+r15] = fenc(f1);
      dst[32+r15] = fenc(f2);
      dst[48+r15] = fenc(f3);
      float m = fmaxf(fmaxf(f0,f1), fmaxf(f2,f3));
      m = fmaxf(m, __shfl_xor(m,1));
      m = fmaxf(m, __shfl_xor(m,2));
      m = fmaxf(m, __shfl_xor(m,4));
      m = fmaxf(m, __shfl_xor(m,8));
      if (r15 == 0)
        cmax[((size_t)(bz<<12) + q0 + row)*64 + bx*2 + (oibase>>6)] = fenc(m);
    }
  }
}

__device__ __forceinline__ unsigned bitsort_u32(unsigned v, int lane){
  #pragma unroll
  for (int k=2;k<=64;k<<=1){
    #pragma unroll
    for (int j=k>>1;j>0;j>>=1){
      unsigned o = (unsigned)__shfl_xor((int)v, j);
      bool takeMax = (((lane & j) != 0) == ((lane & k) == 0));
      unsigned mx = v>o?v:o, mn = v<o?v:o;
      v = takeMax ? mx : mn;
    }
  }
  return v;   // ascending by lane
}

// ---- filtered top-20: chunk-max prefilter + streaming candidate selection ----
__global__ __launch_bounds__(256,4) void k_topk20(const unsigned* __restrict__ pdbuf,
        const unsigned* __restrict__ cmax, int* __restrict__ idxout, int q0, int sshift){
  __shared__ unsigned long long cand[4][64];
  int wid = threadIdx.x>>6, lane = threadIdx.x&63;
  int gw = blockIdx.x*4 + wid;
  int S = 1 << sshift;
  int b = gw >> sshift, i = gw & (S-1);
  const unsigned* row = pdbuf + ((size_t)b*S + i)*N_PTS;
  unsigned cm = cmax[((size_t)b*N_PTS + q0 + i)*64 + lane];
  unsigned T = (unsigned)__shfl((int)bitsort_u32(cm, lane), 44);
  unsigned long long qual = __ballot(cm >= T);
  unsigned lmax = 0u;
  for (int c=0;c<64;c++){
    if (!((qual>>c)&1ull)) continue;
    unsigned vv = row[c*64 + lane];
    lmax = lmax > vv ? lmax : vv;
  }
  unsigned T2 = (unsigned)__shfl((int)bitsort_u32(lmax, lane), 44);
  int base = 0;
  unsigned long long below = (1ull<<lane) - 1ull;
  for (int c=0;c<64;c++){
    if (!((qual>>c)&1ull)) continue;
    unsigned vv = row[c*64 + lane];
    bool isc = vv >= T2;
    unsigned long long mb = __ballot(isc);
    int pos = base + __popcll(mb & below);
    if (isc && pos < 64){
      int m = c*64 + lane;
      cand[wid][pos] = (((unsigned long long)vv)<<12) | (unsigned)(4095-m);
    }
    base += __popcll(mb);
  }
  unsigned long long K;
  if (base <= 64){
    unsigned long long kv = (lane < base) ? cand[wid][lane] : 0ull;
    #pragma unroll
    for (int k=2;k<=64;k<<=1){
      #pragma unroll
      for (int j=k>>1;j>0;j>>=1){
        unsigned long long o = __shfl_xor(kv, j);
        bool takeMax = (((lane & j) != 0) == ((lane & k) == 0));
        unsigned long long mx = kv>o?kv:o, mn = kv<o?kv:o;
        kv = takeMax ? mx : mn;
      }
    }
    K = __shfl(kv, 44);
  } else {
    K = 0ull;
    for (int bb2=43; bb2>=0; --bb2){
      unsigned long long cnd = K | (1ull<<bb2);
      int lc = 0;
      for (int c=0;c<64;c++){
        if (!((qual>>c)&1ull)) continue;
        unsigned vv = row[c*64 + lane];
        int m = c*64 + lane;
        unsigned long long key = (((unsigned long long)vv)<<12) | (unsigned)(4095-m);
        if (key >= cnd) lc++;
      }
      #pragma unroll
      for (int off=32; off; off>>=1) lc += __shfl_xor(lc, off);
      if (lc >= KNB) K = cnd;
    }
  }
  int eb = 0;
  int* dst = idxout + ((size_t)b*N_PTS + (q0+i))*KNB;
  for (int c=0;c<64;c++){
    if (!((qual>>c)&1ull)) continue;
    unsigned vv = row[c*64 + lane];
    int m = c*64 + lane;
    unsigned long long key = (((unsigned long long)vv)<<12) | (unsigned)(4095-m);
    bool sel = key >= K;
    unsigned long long mb = __ballot(sel);
    int pos = eb + __popcll(mb & below);
    if (sel) dst[pos] = m;
    eb += __popcll(mb);
  }
}

// ---- split-bf16 MFMA GEMM ----
// STORE: 0 = column-max only (gmax), 1 = packed u32 store [pt][ldo], 2 = f32 store to d_out (O=13)
template<int STORE, int RELU>
__global__ __launch_bounds__(512) void k_mgemm(const unsigned* __restrict__ Ap, int lda,
        const unsigned* __restrict__ Bp, int ldb,
        const float* __restrict__ bias, int perBatch,
        unsigned* __restrict__ Cp, int ldo, float* __restrict__ Cf,
        unsigned* __restrict__ gmax, int O, int K){
  __shared__ short Ah[128][40];
  __shared__ short Al[128][40];
  __shared__ short Bh[128][40];
  __shared__ short Bl[128][40];
  int tid = threadIdx.x;
  int bx = blockIdx.x, by = blockIdx.y, bz = blockIdx.z;
  int w = tid>>6, lane = tid&63;
  int r15 = lane&15, rb = lane>>4;
  int mibase = (w&3)*32, oibase = (w>>2)*64;
  f32x4 acc[2][4];
  #pragma unroll
  for (int mi=0;mi<2;mi++)
    #pragma unroll
    for (int oi=0;oi<4;oi++) acc[mi][oi] = (f32x4){0.f,0.f,0.f,0.f};
  int srow = tid>>2, sc = (tid&3)*8;
  const unsigned* pa = Ap + ((size_t)((bz<<12) + bx*128 + srow))*lda + sc;
  const unsigned* pb = Bp + (size_t)(by*128 + srow)*ldb + sc;
  for (int kt=0; kt<K; kt+=32){
    if (kt) __syncthreads();
    uint4 a0 = *(const uint4*)(pa+kt);
    uint4 a1 = *(const uint4*)(pa+kt+4);
    uint4 b0 = *(const uint4*)(pb+kt);
    uint4 b1 = *(const uint4*)(pb+kt+4);
    short8v h, l;
    cvt8(a0,a1,h,l);
    *(short8v*)&Ah[srow][sc] = h; *(short8v*)&Al[srow][sc] = l;
    cvt8(b0,b1,h,l);
    *(short8v*)&Bh[srow][sc] = h; *(short8v*)&Bl[srow][sc] = l;
    __syncthreads();
    short8v ah[2], al[2];
    #pragma unroll
    for (int mi=0;mi<2;mi++){
      ah[mi] = *(const short8v*)&Ah[mibase+mi*16+r15][rb*8];
      al[mi] = *(const short8v*)&Al[mibase+mi*16+r15][rb*8];
    }
    #pragma unroll
    for (int oi=0;oi<4;oi++){
      short8v bh = *(const short8v*)&Bh[oibase+oi*16+r15][rb*8];
      short8v bl = *(const short8v*)&Bl[oibase+oi*16+r15][rb*8];
      #pragma unroll
      for (int mi=0;mi<2;mi++){
        acc[mi][oi] = __builtin_amdgcn_mfma_f32_16x16x32_bf16(ah[mi], bh, acc[mi][oi], 0,0,0);
        acc[mi][oi] = __builtin_amdgcn_mfma_f32_16x16x32_bf16(ah[mi], bl, acc[mi][oi], 0,0,0);
        acc[mi][oi] = __builtin_amdgcn_mfma_f32_16x16x32_bf16(al[mi], bh, acc[mi][oi], 0,0,0);
      }
    }
  }
  #pragma unroll
  for (int oi=0;oi<4;oi++){
    int o = by*128 + oibase + oi*16 + r15;
    float bv = 0.f;
    if (bias != nullptr) bv = perBatch ? bias[bz*O + o] : bias[o];
    float cmx = -INFINITY;
    #pragma unroll
    for (int mi=0;mi<2;mi++){
      #pragma unroll
      for (int r=0;r<4;r++){
        float y = acc[mi][oi][r] + bv;
        if (RELU) y = lrelu(y);
        if (STORE==1){
          int pt = bx*128 + mibase + mi*16 + rb*4 + r;
          Cp[((size_t)((bz<<12)+pt))*ldo + o] = pack2(y);
        } else if (STORE==2){
          if (o < 13){
            int pt = bx*128 + mibase + mi*16 + rb*4 + r;
            Cf[(((size_t)(bz*13 + o))<<12) + pt] = y;
          }
        } else {
          cmx = fmaxf(cmx, y);
        }
      }
    }
    if (STORE==0){
      cmx = fmaxf(cmx, __shfl_xor(cmx,16));
      cmx = fmaxf(cmx, __shfl_xor(cmx,32));
      if (rb==0) atomicMax(&gmax[bz*1024 + o], fenc(cmx));
    }
  }
}

// bias7[b][o] = sum_{c<1024} Wf7[o][c]*g[b][c] + bf7[o]
__global__ __launch_bounds__(256) void k_gemv7(const float* __restrict__ Wf7, const float* __restrict__ bf7,
                        const unsigned* __restrict__ g, float* __restrict__ bias7){
  int wid = threadIdx.x>>6, lane = threadIdx.x&63;
  int o = blockIdx.x*4 + wid, b = blockIdx.y;
  const float* wr = Wf7 + (size_t)o*1216;
  const unsigned* gb = g + b*1024;
  float acc = 0.f;
  for (int c = lane; c < 1024; c += 64)
    acc = fmaf(wr[c], fdec(gb[c]), acc);
  #pragma unroll
  for (int off=32; off; off>>=1) acc += __shfl_xor(acc, off);
  if (lane==0) bias7[b*512+o] = acc + bf7[o];
}

extern "C" void kernel_launch(void* const* d_in, const int* in_sizes, int n_in,
                              void* d_out, int out_size, void* d_ws, size_t ws_size,
                              hipStream_t stream){
  const float* x  = (const float*)d_in[0];
  const float* W1 = (const float*)d_in[1];
  const float* W2 = (const float*)d_in[2];
  const float* W3 = (const float*)d_in[3];
  const float* W4 = (const float*)d_in[4];
  const float* W5 = (const float*)d_in[5];
  const float* W6 = (const float*)d_in[6];
  const float* W7 = (const float*)d_in[7];
  const float* W8 = (const float*)d_in[8];
  const float* W9 = (const float*)d_in[9];
  const float* bn1 = (const float*)d_in[10];
  const float* bn2 = (const float*)d_in[11];
  const float* bn3 = (const float*)d_in[12];
  const float* bn4 = (const float*)d_in[13];
  const float* bn5 = (const float*)d_in[14];
  const float* bn6 = (const float*)d_in[15];
  const float* bn7 = (const float*)d_in[16];
  const float* bn8 = (const float*)d_in[17];

  float* ws = (float*)d_ws;
  size_t off = 0;
  auto alloc = [&](size_t nf){ float* p = ws + off; off += (nf + 63) & ~(size_t)63; return p; };
  float* Wf7 = alloc((size_t)512*1216); float* bf7 = alloc(512);
  float* bf6 = alloc(1024);
  float* bf8 = alloc(256);
  float* bf2 = alloc(64);
  float* bf4 = alloc(64);
  unsigned* Wb2p = (unsigned*)alloc((size_t)64*64);
  unsigned* Wb4p = (unsigned*)alloc((size_t)64*64);
  unsigned* Wb6p = (unsigned*)alloc((size_t)1024*192);
  unsigned* Wb7p = (unsigned*)alloc((size_t)512*192);
  unsigned* Wb8p = (unsigned*)alloc((size_t)256*512);
  unsigned* Wb9p = (unsigned*)alloc((size_t)128*256);
  float* W3LT4 = alloc(64*64);    float* W3RdT4 = alloc(64*64); float* bf3 = alloc(64);
  float* W5LT4 = alloc(64*64);    float* W5RdT4 = alloc(64*64); float* bf5 = alloc(64);
  float* U1  = alloc(4*KNB*64);
  float* V1  = alloc((size_t)4*N_PTS*64);
  float* x1t = alloc((size_t)4*N_PTS*64);
  float* x2t = alloc((size_t)4*N_PTS*64);
  float* Ut3 = alloc((size_t)4*N_PTS*64);
  float* Vt3 = alloc((size_t)4*N_PTS*64);
  float* Ut5 = alloc((size_t)4*N_PTS*64);
  float* Vt5 = alloc((size_t)4*N_PTS*64);
  unsigned* Xb = (unsigned*)alloc((size_t)4*N_PTS*192);   // packed activations [n][192]
  float* xx1 = alloc(4*N_PTS);
  float* xx2 = alloc(4*N_PTS);
  int* idx1 = (int*)alloc((size_t)4*N_PTS*KNB);
  int* idx2 = (int*)alloc((size_t)4*N_PTS*KNB);
  unsigned* genc = (unsigned*)alloc(4*1024);
  float* bias7 = alloc(4*512);
  unsigned* h8p = (unsigned*)alloc((size_t)4*N_PTS*256);  // packed conv8 out [n][256]
  unsigned* cmaxb = (unsigned*)alloc((size_t)4*N_PTS*64);
  // pdbuf stripe: cap at S=1024 (64 MB, L3-resident sweet spot)
  size_t remaining = (ws_size / 4 > off) ? (ws_size / 4 - off) : 0;
  int S = 4096;
  while (S > 512 && (size_t)4*S*N_PTS + 1024 > remaining) S >>= 1;
  if (S > 1024) S = 1024;
  int sshift = 31 - __builtin_clz(S);
  unsigned* pdbuf = (unsigned*)alloc((size_t)4*S*N_PTS);   // encoded u32; reused as h7p (needs 32MB)
  unsigned* h7p = pdbuf;                                    // packed conv7 out [n][512]

  // single merged prep kernel (14 independent sub-tasks, block-range dispatch)
  k_prep<<<8452,256,0,stream>>>(x, W1, W2, W3, W4, W5, W6, W7, W8, W9,
                                bn1, bn2, bn3, bn4, bn5, bn6, bn7, bn8,
                                Wf7, bf7, Wb2p, bf2, Wb4p, bf4, Wb6p, bf6, Wb7p,
                                Wb8p, bf8, Wb9p, W3LT4, bf3, W3RdT4, W5LT4, bf5, W5RdT4,
                                U1, V1, genc);

  // edge block 1: MFMA edge-conv (neighbors = points 0..19, U1 indexed by k)
  k_edgemm<0><<<dim3(64,1,4),256,0,stream>>>(U1, V1, nullptr, Wb2p, bf2, x1t, Xb, 0, xx1);

  int nstripe = N_PTS / S;
  // KNN on x1 (packed cols 0..63 of Xb)
  for (int s=0;s<nstripe;s++){
    k_knn_mfma<<<dim3(32,S/128,4),512,0,stream>>>(Xb, 0, xx1, pdbuf, cmaxb, s*S, S);
    k_topk20<<<S,256,0,stream>>>(pdbuf, cmaxb, idx1, s*S, sshift);
  }

  // edge block 2: U3/V3 then MFMA edge-conv with gather
  k_uv<<<4096,256,0,stream>>>(x1t, W3LT4, W3RdT4, bf3, Ut3, Vt3);
  k_edgemm<1><<<dim3(64,1,4),256,0,stream>>>(Ut3, Vt3, idx1, Wb4p, bf4, x2t, Xb, 64, xx2);

  // KNN on x2 (packed cols 64..127 of Xb)
  for (int s=0;s<nstripe;s++){
    k_knn_mfma<<<dim3(32,S/128,4),512,0,stream>>>(Xb, 64, xx2, pdbuf, cmaxb, s*S, S);
    k_topk20<<<S,256,0,stream>>>(pdbuf, cmaxb, idx2, s*S, sshift);
  }

  // edge block 3: U5/V5 then pure gather+max
  k_uv<<<4096,256,0,stream>>>(x2t, W5LT4, W5RdT4, bf5, Ut5, Vt5);
  k_ec3<<<4096,256,0,stream>>>(Ut5, Vt5, idx2, Xb);

  // conv6 (1024x192) -> only column max g (MFMA, gmax atomic)
  k_mgemm<0,1><<<dim3(32,8,4),512,0,stream>>>(Xb, 192, Wb6p, 192, bf6, 0, nullptr, 0, nullptr, genc, 1024, 192);
  // bias7[b][o] = W7[:, :1024] @ g + bf7
  k_gemv7<<<dim3(128,4),256,0,stream>>>(Wf7, bf7, genc, bias7);
  // conv7: W7[:, 1024:1216] @ X + bias7 (per batch) -> packed h7
  k_mgemm<1,1><<<dim3(32,4,4),512,0,stream>>>(Xb, 192, Wb7p, 192, bias7, 1, h7p, 512, nullptr, nullptr, 512, 192);
  // conv8: 256x512 -> packed h8
  k_mgemm<1,1><<<dim3(32,2,4),512,0,stream>>>(h7p, 512, Wb8p, 512, bf8, 0, h8p, 256, nullptr, nullptr, 256, 512);
  // conv9: 13x256 (padded to 128), no bias/relu -> d_out f32
  k_mgemm<2,0><<<dim3(32,1,4),512,0,stream>>>(h8p, 256, Wb9p, 256, nullptr, 0, nullptr, 0, (float*)d_out, nullptr, 13, 256);
}